// Round 6
// baseline (582.243 us; speedup 1.0000x reference)
//
#include <hip/hip_runtime.h>
#include <cmath>

constexpr int B = 16, P = 2048, KNN = 5;
constexpr int BP = B * P;           // 32768
constexpr int E = BP * KNN;         // 163840
constexpr float EPS = 1e-5f;
constexpr int QC2 = 8;              // q-chunks for knn2 (grid was the wave cap at 4)
constexpr int QC2_SHIFT = 3;
static_assert(QC2 == (1 << QC2_SHIFT), "QC2 pow2");

// stats layout (floats): per stage [sum[C] | sumsq[C]]
constexpr int ST0 = 0;        // 64ch -> 128
constexpr int ST1 = 128;      // 64ch
constexpr int ST2 = 256;      // 64ch
constexpr int ST3 = 384;      // 128ch -> 256
constexpr int ST4 = 640;      // 1024ch -> 2048
constexpr int ST5 = 2688;     // 512ch -> 1024
constexpr int ST6 = 3712;     // 256ch -> 512
constexpr int ST_TOTAL = 4224;

typedef __attribute__((ext_vector_type(8))) short bf16x8;
typedef __attribute__((ext_vector_type(4))) float f32x4;

__device__ inline unsigned short f2bf(float x) {
    unsigned u = __float_as_uint(x);
    unsigned r = (u + 0x7FFFu + ((u >> 16) & 1u)) >> 16;
    return (unsigned short)r;
}
__device__ inline float bf2f(unsigned short h) {
    return __uint_as_float(((unsigned)h) << 16);
}
// split x into hi (bf16) and lo (bf16 of residual): x ~= hi + lo, err ~2^-18 rel
__device__ inline void split2bf(float x, unsigned short& h, unsigned short& l) {
    unsigned short hh = f2bf(x);
    h = hh;
    l = f2bf(x - bf2f(hh));
}

// branch-free sorted-5 insertion (ascending); constant indices -> stays in VGPRs.
__device__ inline void ins5(float d, int qi, float bd[KNN], int bi[KNN]) {
    bool c0 = d < bd[0], c1 = d < bd[1], c2 = d < bd[2], c3 = d < bd[3], c4 = d < bd[4];
    bd[4] = c3 ? bd[3] : (c4 ? d : bd[4]);  bi[4] = c3 ? bi[3] : (c4 ? qi : bi[4]);
    bd[3] = c2 ? bd[2] : (c3 ? d : bd[3]);  bi[3] = c2 ? bi[2] : (c3 ? qi : bi[3]);
    bd[2] = c1 ? bd[1] : (c2 ? d : bd[2]);  bi[2] = c1 ? bi[1] : (c2 ? qi : bi[2]);
    bd[1] = c0 ? bd[0] : (c1 ? d : bd[1]);  bi[1] = c0 ? bi[0] : (c1 ? qi : bi[1]);
    bd[0] = c0 ? d : bd[0];                 bi[0] = c0 ? qi : bi[0];
}
// insertion with lexicographic (d, qi) tie-break: keep lower q on exact fp tie
__device__ inline void ins5t(float d, int qi, float bd[KNN], int bi[KNN]) {
    bool c0 = (d < bd[0]) || (d == bd[0] && qi < bi[0]);
    bool c1 = (d < bd[1]) || (d == bd[1] && qi < bi[1]);
    bool c2 = (d < bd[2]) || (d == bd[2] && qi < bi[2]);
    bool c3 = (d < bd[3]) || (d == bd[3] && qi < bi[3]);
    bool c4 = (d < bd[4]) || (d == bd[4] && qi < bi[4]);
    bd[4] = c3 ? bd[3] : (c4 ? d : bd[4]);  bi[4] = c3 ? bi[3] : (c4 ? qi : bi[4]);
    bd[3] = c2 ? bd[2] : (c3 ? d : bd[3]);  bi[3] = c2 ? bi[2] : (c3 ? qi : bi[3]);
    bd[2] = c1 ? bd[1] : (c2 ? d : bd[2]);  bi[2] = c1 ? bi[1] : (c2 ? qi : bi[2]);
    bd[1] = c0 ? bd[0] : (c1 ? d : bd[1]);  bi[1] = c0 ? bi[0] : (c1 ? qi : bi[1]);
    bd[0] = c0 ? d : bd[0];                 bi[0] = c0 ? qi : bi[0];
}
// butterfly-merge helper: pull partner's sorted-5 and insert with tie-break
__device__ inline void merge_xor(int w, float bd[KNN], int bi[KNN]) {
    float od[KNN]; int oi[KNN];
#pragma unroll
    for (int k = 0; k < KNN; ++k) {
        od[k] = __shfl_xor(bd[k], w, 64);
        oi[k] = __shfl_xor(bi[k], w, 64);
    }
#pragma unroll
    for (int k = 0; k < KNN; ++k) ins5t(od[k], oi[k], bd, bi);
}

// ---------------------------------------------------------------- init
__global__ void k_init(float* __restrict__ stats, float* __restrict__ pmax,
                       float* __restrict__ pmin) {
    int i = blockIdx.x * 256 + threadIdx.x;   // grid covers 16384
    if (i < ST_TOTAL) stats[i] = 0.f;
    if (i < B * 1024) { pmax[i] = 0.f; pmin[i] = INFINITY; }
}

// ---------------------------------------------------------------- deterministic partial reducer
__global__ __launch_bounds__(256) void k_redstat(const float* __restrict__ part,
        float* __restrict__ stats, int nblk) {
    __shared__ float r[256];
    int slot = blockIdx.x;
    float s = 0.f;
    for (int i = threadIdx.x; i < nblk; i += 256)
        s += part[(size_t)i * 128 + slot];
    r[threadIdx.x] = s; __syncthreads();
    for (int o = 128; o; o >>= 1) {
        if (threadIdx.x < o) r[threadIdx.x] += r[threadIdx.x + o];
        __syncthreads();
    }
    if (threadIdx.x == 0) stats[slot] = r[0];
}

// ---------------------------------------------------------------- weight pre-split: w[K][N] fp32 -> wt{h,l}[N][K] bf16
__global__ void k_wsplit(const float* __restrict__ w, unsigned short* __restrict__ th,
                         unsigned short* __restrict__ tl, int K, int N) {
    int i = blockIdx.x * 256 + threadIdx.x;
    if (i >= K * N) return;
    int k = i / N, n = i - k * N;          // read coalesced over n
    float f = w[i];
    unsigned short h = f2bf(f);
    th[(size_t)n * K + k] = h;
    tl[(size_t)n * K + k] = f2bf(f - bf2f(h));
}

// ---------------------------------------------------------------- BN-fold: wf[n][k] = scl[k]*w[k][n]; bias2 = bias + shf.w
__global__ __launch_bounds__(64) void k_wfold(const float* __restrict__ stats,
        const float* __restrict__ g, const float* __restrict__ be,
        const float* __restrict__ w, const float* __restrict__ bias,
        unsigned short* __restrict__ wfh, unsigned short* __restrict__ wfl,
        float* __restrict__ bias2, float invN) {
    __shared__ float red[64];
    int n = blockIdx.x, k = threadIdx.x;
    float mu = stats[k] * invN;
    float var = stats[64 + k] * invN - mu * mu;
    float sc = g[k] * rsqrtf(var + EPS);
    float sh = be[k] - mu * sc;
    float wv = w[k * 64 + n];
    float wf = sc * wv;
    unsigned short h, l;
    split2bf(wf, h, l);
    wfh[n * 64 + k] = h; wfl[n * 64 + k] = l;
    red[k] = sh * wv; __syncthreads();
    for (int o = 32; o; o >>= 1) {
        if (k < o) red[k] += red[k + o];
        __syncthreads();
    }
    if (k == 0) bias2[n] = bias[n] + red[0];
}

// ---------------------------------------------------------------- ec2 weight prep: W0-W1 and W1, transposed bf16 hi/lo
__global__ void k_wprep2(const float* __restrict__ w,   // c2w [128][128]
        unsigned short* __restrict__ wdh, unsigned short* __restrict__ wdl,
        unsigned short* __restrict__ w1h, unsigned short* __restrict__ w1l) {
    int i = blockIdx.x * 256 + threadIdx.x;  // 64*128
    if (i >= 64 * 128) return;
    int k = i >> 7, n = i & 127;
    float w0 = w[k * 128 + n];
    float w1 = w[(64 + k) * 128 + n];
    float wd = w0 - w1;
    unsigned short h, l;
    split2bf(wd, h, l); wdh[n * 64 + k] = h; wdl[n * 64 + k] = l;
    split2bf(w1, h, l); w1h[n * 64 + k] = h; w1l[n * 64 + k] = l;
}

// ---------------------------------------------------------------- kNN on pos (D=3)
__global__ __launch_bounds__(256) void k_knn1(const float* __restrict__ pos,
                                              int* __restrict__ idx1) {
    __shared__ float4 qt[2048];   // all q staged once (32 KB)
    int b = blockIdx.x >> 5;
    int p0 = (blockIdx.x & 31) << 6;
    const float* posb = pos + (size_t)b * P * 3;
#pragma unroll
    for (int t = 0; t < 8; ++t) {
        int q = (t << 8) + threadIdx.x;
        float qx = posb[q * 3 + 0], qy = posb[q * 3 + 1], qz = posb[q * 3 + 2];
        qt[q] = make_float4(qx, qy, qz, qx * qx + qy * qy + qz * qz);
    }
    __syncthreads();
    int pl = threadIdx.x >> 2, sub = threadIdx.x & 3;
    int p = p0 + pl;
    float4 me = qt[p];
    float x = me.x, y = me.y, z = me.z, sqp = me.w;
    float bd[KNN]; int bi[KNN];
#pragma unroll
    for (int i = 0; i < KNN; ++i) { bd[i] = INFINITY; bi[i] = 0; }
    for (int j0 = 0; j0 < 512; j0 += 8) {
        float4 v[8];
#pragma unroll
        for (int u = 0; u < 8; ++u) v[u] = qt[((j0 + u) << 2) | sub];
#pragma unroll
        for (int u = 0; u < 8; ++u) {
            float dot = x * v[u].x + y * v[u].y + z * v[u].z;
            float d2 = sqp + v[u].w - 2.f * dot;
            if (d2 < bd[KNN - 1]) ins5(d2, ((j0 + u) << 2) | sub, bd, bi);
        }
    }
    // butterfly merge across the 4 subs; snapshot-then-insert
#pragma unroll
    for (int w = 1; w <= 2; w <<= 1) {
        float od[KNN]; int oi[KNN];
#pragma unroll
        for (int i = 0; i < KNN; ++i) {
            od[i] = __shfl_xor(bd[i], w, 64);
            oi[i] = __shfl_xor(bi[i], w, 64);
        }
#pragma unroll
        for (int i = 0; i < KNN; ++i) ins5t(od[i], oi[i], bd, bi);
    }
    if (sub == 0) {
        size_t o = ((size_t)b * P + p) * KNN;
#pragma unroll
        for (int i = 0; i < KNN; ++i) idx1[o + i] = bi[i];
    }
}

// ---------------------------------------------------------------- edgeconv1 layer0: e[6] @ w[6,64]; bf16 hi/lo out + partials
__global__ __launch_bounds__(256) void k_ec1_l0(const float* __restrict__ pos,
        const int* __restrict__ idx1, const float* __restrict__ w,
        const float* __restrict__ bias, unsigned short* __restrict__ zh,
        unsigned short* __restrict__ zl, float* __restrict__ part) {
    __shared__ float elds[256][6];
    __shared__ float red[256];
    int tid = threadIdx.x;
    int base = blockIdx.x * 256;
    {
        int e = base + tid;
        int bp = e / KNN;
        int bb = bp >> 11;
        int q = idx1[e];
        const float* pi = pos + (size_t)bp * 3;
        const float* pj = pos + ((size_t)(bb << 11) + q) * 3;
        float x0 = pi[0], x1v = pi[1], x2v = pi[2];
        elds[tid][0] = x0; elds[tid][1] = x1v; elds[tid][2] = x2v;
        elds[tid][3] = pj[0] - x0; elds[tid][4] = pj[1] - x1v; elds[tid][5] = pj[2] - x2v;
    }
    int c = tid & 63, lane = tid >> 6;
    float wr[6];
#pragma unroll
    for (int d = 0; d < 6; ++d) wr[d] = w[d * 64 + c];
    float bc = bias[c];
    __syncthreads();
    float s1 = 0.f, s2 = 0.f;
    for (int i = 0; i < 64; ++i) {
        int e = lane + (i << 2);
        float acc = bc;
#pragma unroll
        for (int d = 0; d < 6; ++d) acc = fmaf(elds[e][d], wr[d], acc);
        acc = fmaxf(acc, 0.f);
        unsigned short h, l;
        split2bf(acc, h, l);
        zh[(size_t)(base + e) * 64 + c] = h;
        zl[(size_t)(base + e) * 64 + c] = l;
        s1 += acc; s2 = fmaf(acc, acc, s2);
    }
    red[tid] = s1; __syncthreads();
    if (tid < 64) part[(size_t)blockIdx.x * 128 + tid] =
        red[tid] + red[tid + 64] + red[tid + 128] + red[tid + 192];
    __syncthreads();
    red[tid] = s2; __syncthreads();
    if (tid < 64) part[(size_t)blockIdx.x * 128 + 64 + tid] =
        red[tid] + red[tid + 64] + red[tid + 128] + red[tid + 192];
}

// ---------------------------------------------------------------- 64->64 layer (BN folded into weights; direct-frag MFMA)
__global__ __launch_bounds__(128) void k_lin64m(
        const unsigned short* __restrict__ zinh, const unsigned short* __restrict__ zinl,
        const unsigned short* __restrict__ wfh, const unsigned short* __restrict__ wfl,
        const float* __restrict__ bias2, unsigned short* __restrict__ zouth,
        unsigned short* __restrict__ zoutl, float* __restrict__ part) {
    __shared__ float red[2 * 64 * 2];
    int tid = threadIdx.x;
    int wv = tid >> 6, lane = tid & 63;
    int l15 = lane & 15, quad = lane >> 4;
    int row0 = blockIdx.x * 128 + wv * 64;
    f32x4 acc[4][4];
#pragma unroll
    for (int i = 0; i < 4; ++i)
#pragma unroll
        for (int j = 0; j < 4; ++j) acc[i][j] = (f32x4)0.f;

#pragma unroll
    for (int kc = 0; kc < 2; ++kc) {
        bf16x8 afh[4], afl[4], bfh[4], bfl[4];
#pragma unroll
        for (int i = 0; i < 4; ++i) {
            size_t o = (size_t)(row0 + i * 16 + l15) * 64 + kc * 32 + quad * 8;
            afh[i] = *(const bf16x8*)&zinh[o];
            afl[i] = *(const bf16x8*)&zinl[o];
        }
#pragma unroll
        for (int j = 0; j < 4; ++j) {
            size_t wo = (size_t)(j * 16 + l15) * 64 + kc * 32 + quad * 8;
            bfh[j] = *(const bf16x8*)&wfh[wo];
            bfl[j] = *(const bf16x8*)&wfl[wo];
        }
#pragma unroll
        for (int i = 0; i < 4; ++i)
#pragma unroll
            for (int j = 0; j < 4; ++j) {
                acc[i][j] = __builtin_amdgcn_mfma_f32_16x16x32_bf16(afh[i], bfh[j], acc[i][j], 0, 0, 0);
                acc[i][j] = __builtin_amdgcn_mfma_f32_16x16x32_bf16(afh[i], bfl[j], acc[i][j], 0, 0, 0);
                acc[i][j] = __builtin_amdgcn_mfma_f32_16x16x32_bf16(afl[i], bfh[j], acc[i][j], 0, 0, 0);
            }
    }
    // epilogue: bias + ReLU, bf16 split store, per-col stats
#pragma unroll
    for (int j = 0; j < 4; ++j) {
        int colL = j * 16 + l15;
        float bl = bias2[colL];
        float s1 = 0.f, s2 = 0.f;
#pragma unroll
        for (int i = 0; i < 4; ++i) {
            int row = row0 + i * 16 + quad * 4;
#pragma unroll
            for (int r = 0; r < 4; ++r) {
                float v = fmaxf(acc[i][j][r] + bl, 0.f);
                unsigned short h, l;
                split2bf(v, h, l);
                zouth[(size_t)(row + r) * 64 + colL] = h;
                zoutl[(size_t)(row + r) * 64 + colL] = l;
                s1 += v; s2 = fmaf(v, v, s2);
            }
        }
        s1 += __shfl_xor(s1, 16, 64); s1 += __shfl_xor(s1, 32, 64);
        s2 += __shfl_xor(s2, 16, 64); s2 += __shfl_xor(s2, 32, 64);
        if (quad == 0) {
            red[(wv * 64 + colL) * 2 + 0] = s1;
            red[(wv * 64 + colL) * 2 + 1] = s2;
        }
    }
    __syncthreads();
    if (tid < 64) {
        part[(size_t)blockIdx.x * 128 + tid] =
            red[tid * 2] + red[(64 + tid) * 2];
        part[(size_t)blockIdx.x * 128 + 64 + tid] =
            red[tid * 2 + 1] + red[(64 + tid) * 2 + 1];
    }
}

// ---------------------------------------------------------------- ec1 finalize: BN + max over k -> x1 bf16 hi/lo (fused xsplit), sq norms
// NOTE: x1h/x1l MUST NOT alias z2h/z2l (R5 bug: in-place overwrite raced
// with other blocks' reads of z2 rows). x1 pair has a dedicated allocation.
__global__ __launch_bounds__(256) void k_ec1_fin(const unsigned short* __restrict__ z2h,
        const unsigned short* __restrict__ z2l,
        const float* __restrict__ statsIn, const float* __restrict__ g,
        const float* __restrict__ be, unsigned short* __restrict__ x1h,
        unsigned short* __restrict__ x1l, float* __restrict__ sq2) {
    int tid = threadIdx.x;
    int o = blockIdx.x * 256 + tid;
    int c = o & 63; int bp = o >> 6;
    float mu = statsIn[c] * (1.f / E);
    float var = statsIn[64 + c] * (1.f / E) - mu * mu;
    float sc = g[c] * rsqrtf(var + EPS);
    float sh = be[c] - mu * sc;
    float m = -INFINITY;
#pragma unroll
    for (int j = 0; j < KNN; ++j) {
        size_t zo = ((size_t)bp * KNN + j) * 64 + c;
        float v = bf2f(z2h[zo]) + bf2f(z2l[zo]);
        m = fmaxf(m, fmaf(v, sc, sh));
    }
    unsigned short h, l;
    split2bf(m, h, l);
    x1h[o] = h; x1l[o] = l;
    float ss = m * m;
#pragma unroll
    for (int off = 32; off; off >>= 1) ss += __shfl_down(ss, off, 64);
    if (c == 0) sq2[bp] = ss;
}

// ---------------------------------------------------------------- kNN2 partial
// R19: swapped-operand Gram -> C[q][p] with p=lane&15: lane owns full p-rows,
// top-5 scan on MFMA accumulator registers; no LDS key tile.
// R20: spill disaster. R21: 2 sequential p-passes -> doubled loads, 175us.
// R22: q-frags shared across both p-tiles -> 91us, VGPR 56, but grid-capped
// at 4 waves/SIMD (Occ 39%) and shfl-based sqq on the DS pipe.
// R23/R24: QC2 8 (4096 blocks -> 8 waves/SIMD ceiling); sqq via contiguous
// float4 load (lane's 4 candidates = sq2[qb..qb+3]) kills 32 ds_bpermute/t.
__global__ __launch_bounds__(128) void k_knn2(const unsigned short* __restrict__ x1h,
        const unsigned short* __restrict__ x1l, const float* __restrict__ sq2,
        float* __restrict__ cd, int* __restrict__ ci) {
    int tid = threadIdx.x;
    int wv = tid >> 6, lane = tid & 63;
    int l15 = lane & 15, quad = lane >> 4;
    int qc = blockIdx.x & (QC2 - 1);
    int pt = blockIdx.x >> QC2_SHIFT;         // 16*32 ptiles of 64 rows
    int b = pt >> 5;
    int pw = ((pt & 31) << 6) + wv * 32;      // wave p base within batch
    const size_t xbase = (size_t)b * P * 64;
    int qlo = qc * (P / QC2);                 // 256-q chunk

    // B operand: p-row fragments for both 16-row tiles (held whole kernel)
    bf16x8 ph[2][2], pl_[2][2];               // [i][kc]
#pragma unroll
    for (int i = 0; i < 2; ++i)
#pragma unroll
        for (int kc = 0; kc < 2; ++kc) {
            size_t o = xbase + (size_t)(pw + i * 16 + l15) * 64 + kc * 32 + quad * 8;
            ph[i][kc] = *(const bf16x8*)&x1h[o];
            pl_[i][kc] = *(const bf16x8*)&x1l[o];
        }
    // per-lane top-5 for p-rows l15 (0) and 16+l15 (1)
    float bd0[KNN], bd1[KNN]; int bi0[KNN], bi1[KNN];
#pragma unroll
    for (int i = 0; i < KNN; ++i) {
        bd0[i] = INFINITY; bi0[i] = 0;
        bd1[i] = INFINITY; bi1[i] = 0;
    }

#pragma unroll 1
    for (int t = 0; t < (P / QC2) / 128; ++t) {
        int q0 = qlo + (t << 7);
#pragma unroll 1
        for (int j = 0; j < 8; ++j) {
            f32x4 a0 = (f32x4)0.f, a1 = (f32x4)0.f;
#pragma unroll
            for (int kc = 0; kc < 2; ++kc) {
                size_t o = xbase + (size_t)(q0 + j * 16 + l15) * 64 + kc * 32 + quad * 8;
                bf16x8 qh = *(const bf16x8*)&x1h[o];
                bf16x8 ql = *(const bf16x8*)&x1l[o];
                a0 = __builtin_amdgcn_mfma_f32_16x16x32_bf16(qh, ph[0][kc], a0, 0, 0, 0);
                a0 = __builtin_amdgcn_mfma_f32_16x16x32_bf16(qh, pl_[0][kc], a0, 0, 0, 0);
                a0 = __builtin_amdgcn_mfma_f32_16x16x32_bf16(ql, ph[0][kc], a0, 0, 0, 0);
                a1 = __builtin_amdgcn_mfma_f32_16x16x32_bf16(qh, ph[1][kc], a1, 0, 0, 0);
                a1 = __builtin_amdgcn_mfma_f32_16x16x32_bf16(qh, pl_[1][kc], a1, 0, 0, 0);
                a1 = __builtin_amdgcn_mfma_f32_16x16x32_bf16(ql, ph[1][kc], a1, 0, 0, 0);
            }
            // scan: this lane's 4 candidates are contiguous -> one float4 sq load
            int qb = q0 + j * 16 + (quad << 2);
            f32x4 sq4 = *(const f32x4*)&sq2[b * P + qb];
#pragma unroll
            for (int r = 0; r < 4; ++r) {
                float d0 = fmaf(a0[r], -2.f, sq4[r]);
                if (d0 < bd0[KNN - 1]) ins5(d0, qb + r, bd0, bi0);
                float d1 = fmaf(a1[r], -2.f, sq4[r]);
                if (d1 < bd1[KNN - 1]) ins5(d1, qb + r, bd1, bi1);
            }
        }
    }
    // merge across the 4 quads sharing l15 (disjoint q mod 16 -> clean ties)
    merge_xor(16, bd0, bi0); merge_xor(16, bd1, bi1);
    merge_xor(32, bd0, bi0); merge_xor(32, bd1, bi1);
    if (quad == 0) {
        size_t o0 = (((size_t)b * P + pw + l15) * QC2 + qc) * KNN;
        size_t o1 = (((size_t)b * P + pw + 16 + l15) * QC2 + qc) * KNN;
#pragma unroll
        for (int k = 0; k < KNN; ++k) {
            cd[o0 + k] = bd0[k]; ci[o0 + k] = bi0[k];
            cd[o1 + k] = bd1[k]; ci[o1 + k] = bi1[k];
        }
    }
}

// ---------------------------------------------------------------- kNN2 merge (QC2 sorted chunks of 5 -> 5)
__global__ __launch_bounds__(256) void k_knn2m(const float* __restrict__ cd,
        const int* __restrict__ ci, int* __restrict__ idx2) {
    int bp = blockIdx.x * 256 + threadIdx.x;
    float bd[KNN]; int bi[KNN];
#pragma unroll
    for (int i = 0; i < KNN; ++i) { bd[i] = INFINITY; bi[i] = 0; }
    size_t o = (size_t)bp * QC2 * KNN;
    for (int t = 0; t < QC2 * KNN; ++t) {
        float d2 = cd[o + t]; int qi = ci[o + t];
        if (d2 < bd[KNN - 1]) ins5(d2, qi, bd, bi);
    }
#pragma unroll
    for (int i = 0; i < KNN; ++i) idx2[bp * KNN + i] = bi[i];
}

// ---------------------------------------------------------------- edgeconv2 (direct-fragment split-bf16 MFMA)
__global__ __launch_bounds__(256) void k_ec2m(
        const unsigned short* __restrict__ x1h, const unsigned short* __restrict__ x1l,
        const int* __restrict__ idx2,
        const unsigned short* __restrict__ wdh, const unsigned short* __restrict__ wdl,
        const unsigned short* __restrict__ w1h, const unsigned short* __restrict__ w1l,
        const float* __restrict__ bias, float* __restrict__ zout,
        float* __restrict__ stats) {
    __shared__ float red[2 * 128 * 2];
    int tid = threadIdx.x;
    int base = blockIdx.x * 128;            // first edge
    int bb = base / (P * KNN);              // batch (blocks never straddle: 10240%128==0)
    int wv = tid >> 6, lane = tid & 63;
    int wm = wv >> 1, wn = wv & 1;
    int l15 = lane & 15, quad = lane >> 4;
    // per-lane A rows for this wave's 4 row-tiles
    int rI[4], rJ[4];
#pragma unroll
    for (int i = 0; i < 4; ++i) {
        int e = base + wm * 64 + i * 16 + l15;
        rI[i] = e / KNN;
        rJ[i] = (bb << 11) + idx2[e];
    }
    f32x4 acc[4][4];
#pragma unroll
    for (int i = 0; i < 4; ++i)
#pragma unroll
        for (int j = 0; j < 4; ++j) acc[i][j] = (f32x4)0.f;

#pragma unroll
    for (int s = 0; s < 2; ++s) {
        const unsigned short* bh_ = s ? w1h : wdh;
        const unsigned short* bl_ = s ? w1l : wdl;
#pragma unroll
        for (int kc = 0; kc < 2; ++kc) {
            bf16x8 afh[4], afl[4], bfh[4], bfl[4];
#pragma unroll
            for (int i = 0; i < 4; ++i) {
                int row = s ? rJ[i] : rI[i];
                size_t o = (size_t)row * 64 + kc * 32 + quad * 8;
                afh[i] = *(const bf16x8*)&x1h[o];
                afl[i] = *(const bf16x8*)&x1l[o];
            }
#pragma unroll
            for (int j = 0; j < 4; ++j) {
                size_t wo = (size_t)(wn * 64 + j * 16 + l15) * 64 + kc * 32 + quad * 8;
                bfh[j] = *(const bf16x8*)&bh_[wo];
                bfl[j] = *(const bf16x8*)&bl_[wo];
            }
#pragma unroll
            for (int i = 0; i < 4; ++i)
#pragma unroll
                for (int j = 0; j < 4; ++j) {
                    acc[i][j] = __builtin_amdgcn_mfma_f32_16x16x32_bf16(afh[i], bfh[j], acc[i][j], 0, 0, 0);
                    acc[i][j] = __builtin_amdgcn_mfma_f32_16x16x32_bf16(afh[i], bfl[j], acc[i][j], 0, 0, 0);
                    acc[i][j] = __builtin_amdgcn_mfma_f32_16x16x32_bf16(afl[i], bfh[j], acc[i][j], 0, 0, 0);
                }
        }
    }
    // epilogue: bias + ReLU, write z, per-col stats
#pragma unroll
    for (int j = 0; j < 4; ++j) {
        int colL = wn * 64 + j * 16 + l15;
        float bl = bias[colL];
        float s1 = 0.f, s2 = 0.f;
#pragma unroll
        for (int i = 0; i < 4; ++i) {
            int row = wm * 64 + i * 16 + quad * 4;
#pragma unroll
            for (int r = 0; r < 4; ++r) {
                float v = fmaxf(acc[i][j][r] + bl, 0.f);
                zout[(size_t)(base + row + r) * 128 + colL] = v;
                s1 += v; s2 = fmaf(v, v, s2);
            }
        }
        s1 += __shfl_xor(s1, 16, 64); s1 += __shfl_xor(s1, 32, 64);
        s2 += __shfl_xor(s2, 16, 64); s2 += __shfl_xor(s2, 32, 64);
        if (quad == 0) {
            red[(wm * 128 + colL) * 2 + 0] = s1;
            red[(wm * 128 + colL) * 2 + 1] = s2;
        }
    }
    __syncthreads();
    if (tid < 128) {
        atomicAdd(&stats[tid], red[tid * 2] + red[(128 + tid) * 2]);
        atomicAdd(&stats[128 + tid], red[tid * 2 + 1] + red[(128 + tid) * 2 + 1]);
    }
}

// ---------------------------------------------------------------- ec2 finalize: BN + max over k -> x2 bf16 hi/lo (fused xsplit)
// safe: z3 lives in zA, x2 pair lives in zB — disjoint buffers.
__global__ __launch_bounds__(256) void k_ec2_fin(const float* __restrict__ z3,
        const float* __restrict__ stats, const float* __restrict__ g,
        const float* __restrict__ be, unsigned short* __restrict__ x2h,
        unsigned short* __restrict__ x2l) {
    int o = blockIdx.x * 256 + threadIdx.x;
    int c = o & 127; int bp = o >> 7;
    float mu = stats[c] * (1.f / E);
    float var = stats[128 + c] * (1.f / E) - mu * mu;
    float sc = g[c] * rsqrtf(var + EPS);
    float sh = be[c] - mu * sc;
    float m = -INFINITY;
#pragma unroll
    for (int j = 0; j < KNN; ++j)
        m = fmaxf(m, fmaf(z3[((size_t)bp * KNN + j) * 128 + c], sc, sh));
    unsigned short h, l;
    split2bf(m, h, l);
    x2h[o] = h; x2l[o] = l;
}

// ---------------------------------------------------------------- l1 (LDS-staged split-bf16 MFMA, m97-style 2-phase)
// R18: coalesced global_load_lds staging + ds_read_b128 frags fixed the
// latency-bound direct-gather version (108 -> out of top-5).
__device__ __forceinline__ void gl16(unsigned short* lds, const unsigned short* g) {
    __builtin_amdgcn_global_load_lds(
        (const __attribute__((address_space(1))) unsigned int*)g,
        (__attribute__((address_space(3))) unsigned int*)lds, 16, 0, 0);
}

__global__ __launch_bounds__(256) void k_l1m(
        const unsigned short* __restrict__ x1h, const unsigned short* __restrict__ x1l,
        const unsigned short* __restrict__ x2h, const unsigned short* __restrict__ x2l,
        const unsigned short* __restrict__ wth, const unsigned short* __restrict__ wtl,
        const float* __restrict__ bias, float* __restrict__ stats,
        float* __restrict__ pmax, float* __restrict__ pmin) {
    __shared__ unsigned short Ah[128 * 32], Al[128 * 32];   // [row][k] bf16, 8 KB each
    __shared__ unsigned short Bh[128 * 32], Bl[128 * 32];   // [col][k] bf16
    __shared__ float red[2 * 128 * 4];
    int tid = threadIdx.x;
    int brow = blockIdx.x & 255;
    int bcol = blockIdx.x >> 8;
    int row0 = brow << 7, col0 = bcol << 7;
    int wv = tid >> 6, lane = tid & 63;
    int wm = wv >> 1, wn = wv & 1;
    int l15 = lane & 15, quad = lane >> 4;
    int rloc = wv * 16 + (lane >> 2);      // staging row for call 0 (+64 for call 1)
    int ch8 = (lane & 3) * 8;              // staging k-chunk (ushorts, 16 B)
    f32x4 acc[4][4];
#pragma unroll
    for (int i = 0; i < 4; ++i)
#pragma unroll
        for (int j = 0; j < 4; ++j) acc[i][j] = (f32x4)0.f;

#pragma unroll
    for (int t = 0; t < 6; ++t) {
        int k0 = t * 32;
        const unsigned short* ah = (k0 < 64) ? x1h : x2h;
        const unsigned short* al = (k0 < 64) ? x1l : x2l;
        int astr = (k0 < 64) ? 64 : 128;
        int aoff = (k0 < 64) ? k0 : (k0 - 64);
        // stage: 32 KB/step, 8 x 16B global_load_lds per thread, 1 KB/wave/call
#pragma unroll
        for (int c = 0; c < 2; ++c) {
            int rl = c * 64 + rloc;
            size_t ao = (size_t)(row0 + rl) * astr + aoff + ch8;
            size_t bo = (size_t)(col0 + rl) * 192 + k0 + ch8;
            int lb = (c * 64 + wv * 16) * 32;   // wave-uniform LDS base (ushorts)
            gl16(&Ah[lb], &ah[ao]);
            gl16(&Al[lb], &al[ao]);
            gl16(&Bh[lb], &wth[bo]);
            gl16(&Bl[lb], &wtl[bo]);
        }
        __syncthreads();    // compiler drains vmcnt before s_barrier
        bf16x8 afh[4], afl[4], bfh[4], bfl[4];
#pragma unroll
        for (int i = 0; i < 4; ++i) {
            int o = (wm * 64 + i * 16 + l15) * 32 + quad * 8;
            afh[i] = *(const bf16x8*)&Ah[o];
            afl[i] = *(const bf16x8*)&Al[o];
        }
#pragma unroll
        for (int j = 0; j < 4; ++j) {
            int o = (wn * 64 + j * 16 + l15) * 32 + quad * 8;
            bfh[j] = *(const bf16x8*)&Bh[o];
            bfl[j] = *(const bf16x8*)&Bl[o];
        }
#pragma unroll
        for (int i = 0; i < 4; ++i)
#pragma unroll
            for (int j = 0; j < 4; ++j) {
                acc[i][j] = __builtin_amdgcn_mfma_f32_16x16x32_bf16(afh[i], bfh[j], acc[i][j], 0, 0, 0);
                acc[i][j] = __builtin_amdgcn_mfma_f32_16x16x32_bf16(afh[i], bfl[j], acc[i][j], 0, 0, 0);
                acc[i][j] = __builtin_amdgcn_mfma_f32_16x16x32_bf16(afl[i], bfh[j], acc[i][j], 0, 0, 0);
            }
        __syncthreads();    // protect LDS re-stage of step t+1
    }
    // epilogue: bias + ReLU, per-col sum/sumsq/max/min (h never materialized)
#pragma unroll
    for (int j = 0; j < 4; ++j) {
        int colL = wn * 64 + j * 16 + l15;
        float bl = bias[col0 + colL];
        float s1 = 0.f, s2 = 0.f, mx = 0.f, mn = INFINITY;
#pragma unroll
        for (int i = 0; i < 4; ++i)
#pragma unroll
            for (int r = 0; r < 4; ++r) {
                float v = fmaxf(acc[i][j][r] + bl, 0.f);
                s1 += v; s2 = fmaf(v, v, s2);
                mx = fmaxf(mx, v); mn = fminf(mn, v);
            }
        s1 += __shfl_xor(s1, 16, 64); s1 += __shfl_xor(s1, 32, 64);
        s2 += __shfl_xor(s2, 16, 64); s2 += __shfl_xor(s2, 32, 64);
        mx = fmaxf(mx, __shfl_xor(mx, 16, 64)); mx = fmaxf(mx, __shfl_xor(mx, 32, 64));
        mn = fminf(mn, __shfl_xor(mn, 16, 64)); mn = fminf(mn, __shfl_xor(mn, 32, 64));
        if (quad == 0) {
            float* rp = &red[(wm * 128 + colL) * 4];
            rp[0] = s1; rp[1] = s2; rp[2] = mx; rp[3] = mn;
        }
    }
    __syncthreads();
    if (tid < 128) {
        const float* r0 = &red[tid * 4];
        const float* r1 = &red[(128 + tid) * 4];
        int bb = row0 >> 11;
        atomicAdd(&stats[col0 + tid], r0[0] + r1[0]);
        atomicAdd(&stats[1024 + col0 + tid], r0[1] + r1[1]);
        atomicMax((unsigned int*)&pmax[bb * 1024 + col0 + tid],
                  __float_as_uint(fmaxf(r0[2], r1[2])));
        atomicMin((unsigned int*)&pmin[bb * 1024 + col0 + tid],
                  __float_as_uint(fminf(r0[3], r1[3])));
    }
}

// ---------------------------------------------------------------- pooled p = BN(max or min)
__global__ void k_pool(const float* __restrict__ stats, const float* __restrict__ g,
                       const float* __restrict__ be, const float* __restrict__ pmax,
                       const float* __restrict__ pmin, float* __restrict__ p) {
    int o = blockIdx.x * 256 + threadIdx.x;   // 16384
    int c = o & 1023;
    float mu = stats[c] * (1.f / BP);
    float var = stats[1024 + c] * (1.f / BP) - mu * mu;
    float sc = g[c] * rsqrtf(var + EPS);
    float sh = be[c] - mu * sc;
    float v = (sc >= 0.f) ? pmax[o] : pmin[o];
    p[o] = fmaf(v, sc, sh);
}

// ---------------------------------------------------------------- head
__global__ __launch_bounds__(256) void k_m1(const float* __restrict__ p,
        const float* __restrict__ w, const float* __restrict__ bias,
        float* __restrict__ t1, float* __restrict__ stats) {
    int o = blockIdx.x * 256 + threadIdx.x;   // 8192
    int c = o & 511, b = o >> 9;
    const float* pr = p + (b << 10);
    float acc = bias[c];
    for (int k = 0; k < 1024; ++k) acc = fmaf(pr[k], w[k * 512 + c], acc);
    acc = fmaxf(acc, 0.f);
    t1[o] = acc;
    atomicAdd(&stats[c], acc);
    atomicAdd(&stats[512 + c], acc * acc);
}

__global__ __launch_bounds__(256) void k_m2(const float* __restrict__ t1,
        const float* __restrict__ stats5, const float* __restrict__ g,
        const float* __restrict__ be, const float* __restrict__ w,
        const float* __restrict__ bias, float* __restrict__ t2,
        float* __restrict__ stats6) {
    __shared__ float scl[512], shf[512];
    int tid = threadIdx.x;
    for (int t = tid; t < 512; t += 256) {
        float mu = stats5[t] * (1.f / 16.f);
        float var = stats5[512 + t] * (1.f / 16.f) - mu * mu;
        float sc = g[t] * rsqrtf(var + EPS);
        scl[t] = sc; shf[t] = be[t] - mu * sc;
    }
    __syncthreads();
    int o = blockIdx.x * 256 + tid;   // 4096
    int c = o & 255, b = o >> 8;
    const float* tr = t1 + (b << 9);
    float acc = bias[c];
    for (int k = 0; k < 512; ++k) {
        float u = fmaf(tr[k], scl[k], shf[k]);
        acc = fmaf(u, w[k * 256 + c], acc);
    }
    acc = fmaxf(acc, 0.f);
    t2[o] = acc;
    atomicAdd(&stats6[c], acc);
    atomicAdd(&stats6[256 + c], acc * acc);
}

__global__ __launch_bounds__(256) void k_m3(const float* __restrict__ t2,
        const float* __restrict__ stats6, const float* __restrict__ g,
        const float* __restrict__ be, const float* __restrict__ w,
        const float* __restrict__ bias, float* __restrict__ out) {
    __shared__ float scl[256], shf[256];
    int tid = threadIdx.x;
    {
        float mu = stats6[tid] * (1.f / 16.f);
        float var = stats6[256 + tid] * (1.f / 16.f) - mu * mu;
        float sc = g[tid] * rsqrtf(var + EPS);
        scl[tid] = sc; shf[tid] = be[tid] - mu * sc;
    }
    __syncthreads();
    if (tid < 32) {
        int c = tid & 1, b = tid >> 1;
        const float* tr = t2 + (b << 8);
        float acc = bias[c];
        for (int k = 0; k < 256; ++k) {
            float u = fmaf(tr[k], scl[k], shf[k]);
            acc = fmaf(u, w[k * 2 + c], acc);
        }
        out[tid] = acc;
    }
}

// ================================================================ launch
extern "C" void kernel_launch(void* const* d_in, const int* in_sizes, int n_in,
                              void* d_out, int out_size, void* d_ws, size_t ws_size,
                              hipStream_t stream) {
    const float* pos  = (const float*)d_in[0];
    const float* c1w0 = (const float*)d_in[1];
    const float* c1b0 = (const float*)d_in[2];
    const float* c1g0 = (const float*)d_in[3];
    const float* c1e0 = (const float*)d_in[4];
    const float* c1w1 = (const float*)d_in[5];
    const float* c1b1 = (const float*)d_in[6];
    const float* c1g1 = (const float*)d_in[7];
    const float* c1e1 = (const float*)d_in[8];
    const float* c1w2 = (const float*)d_in[9];
    const float* c1b2 = (const float*)d_in[10];
    const float* c1g2 = (const float*)d_in[11];
    const float* c1e2 = (const float*)d_in[12];
    const float* c2w  = (const float*)d_in[13];
    const float* c2b  = (const float*)d_in[14];
    const float* c2g  = (const float*)d_in[15];
    const float* c2e  = (const float*)d_in[16];
    const float* l1w  = (const float*)d_in[17];
    const float* l1b  = (const float*)d_in[18];
    const float* l1g  = (const float*)d_in[19];
    const float* l1e  = (const float*)d_in[20];
    const float* m1w  = (const float*)d_in[21];
    const float* m1b  = (const float*)d_in[22];
    const float* m1g  = (const float*)d_in[23];
    const float* m1e  = (const float*)d_in[24];
    const float* m2w  = (const float*)d_in[25];
    const float* m2b  = (const float*)d_in[26];
    const float* m2g  = (const float*)d_in[27];
    const float* m2e  = (const float*)d_in[28];
    const float* m3w  = (const float*)d_in[29];
    const float* m3b  = (const float*)d_in[30];
    float* out = (float*)d_out;

    char* ws = (char*)d_ws;
    size_t off = 0;
    auto alloc = [&](size_t bytes) {
        size_t r = off; off = (off + bytes + 255) & ~(size_t)255; return r;
    };
    float* stats = (float*)(ws + alloc(ST_TOTAL * 4));
    float* pmax  = (float*)(ws + alloc(16 * 1024 * 4));
    float* pmin  = (float*)(ws + alloc(16 * 1024 * 4));
    float* pbuf  = (float*)(ws + alloc(16 * 1024 * 4));
    float* t1    = (float*)(ws + alloc(16 * 512 * 4));
    float* t2    = (float*)(ws + alloc(16 * 256 * 4));
    float* sq2   = (float*)(ws + alloc((size_t)BP * 4));
    float* part  = (float*)(ws + alloc((size_t)(E / 64) * 128 * 4));  // up to 2560 blocks x 128
    unsigned short* wthL = (unsigned short*)(ws + alloc((size_t)192 * 1024 * 2));
    unsigned short* wtlL = (unsigned short*)(ws + alloc((size_t)192 * 1024 * 2));
    unsigned short* wdh  = (unsigned short*)(ws + alloc((size_t)128 * 64 * 2));
    unsigned short* wdl  = (unsigned short*)(ws + alloc((size_t)128 * 64 * 2));
    unsigned short* w1h  = (unsigned short*)(ws + alloc((size_t)128 * 64 * 2));
    unsigned short* w1l  = (unsigned short*)(ws + alloc((size_t)128 * 64 * 2));
    unsigned short* wf1h = (unsigned short*)(ws + alloc((size_t)64 * 64 * 2));
    unsigned short* wf1l = (unsigned short*)(ws + alloc((size_t)64 * 64 * 2));
    unsigned short* wf2h = (unsigned short*)(ws + alloc((size_t)64 * 64 * 2));
    unsigned short* wf2l = (unsigned short*)(ws + alloc((size_t)64 * 64 * 2));
    float* bias2a = (float*)(ws + alloc(64 * 4));
    float* bias2b = (float*)(ws + alloc(64 * 4));
    int*   idx1  = (int*)  (ws + alloc((size_t)E * 4));
    int*   idx2  = (int*)  (ws + alloc((size_t)E * 4));
    // dedicated x1 bf16 pair (R6 fix: must NOT alias z2 — ec1_fin reads z2
    // and writes x1 in the same kernel; aliasing raced across blocks)
    unsigned short* x1h = (unsigned short*)(ws + alloc((size_t)BP * 64 * 2));
    unsigned short* x1l = (unsigned short*)(ws + alloc((size_t)BP * 64 * 2));
    float* zA    = (float*)(ws + alloc((size_t)E * 128 * 4)); // hosts z0/z1 bf16 pairs, later z3 fp32
    float* zB    = (float*)(ws + alloc((size_t)E * 64 * 4));  // hosts z2 bf16 pair, later knn2 scratch
    // zA aliases: z0h/z0l (21MB each) then z1h/z1l; all dead before z3 (ec2 out) overwrites
    unsigned short* z0h = (unsigned short*)zA;
    unsigned short* z0l = z0h + (size_t)E * 64;
    unsigned short* z1h = z0l + (size_t)E * 64;
    unsigned short* z1l = z1h + (size_t)E * 64;
    // zB aliases: z2h/z2l (dead after ec1_fin completes), then knn2 scratch:
    // cand 10.5MB + x2 pair 16.8MB = 27.3 < 41.9MB
    unsigned short* z2h = (unsigned short*)zB;
    unsigned short* z2l = z2h + (size_t)E * 64;
    float* cand_d = (float*)zB;
    int*   cand_i = (int*)(cand_d + (size_t)BP * QC2 * KNN);
    unsigned short* x2h = (unsigned short*)(cand_i + (size_t)BP * QC2 * KNN);
    unsigned short* x2l = x2h + (size_t)BP * 128;

    (void)in_sizes; (void)n_in; (void)out_size; (void)ws_size;

    k_init<<<64, 256, 0, stream>>>(stats, pmax, pmin);
    k_wsplit<<<(192 * 1024 + 255) / 256, 256, 0, stream>>>(l1w, wthL, wtlL, 192, 1024);
    k_wprep2<<<(64 * 128 + 255) / 256, 256, 0, stream>>>(c2w, wdh, wdl, w1h, w1l);
    k_knn1<<<B * 32, 256, 0, stream>>>(pos, idx1);
    k_ec1_l0<<<E / 256, 256, 0, stream>>>(pos, idx1, c1w0, c1b0, z0h, z0l, part);
    k_redstat<<<128, 256, 0, stream>>>(part, stats + ST0, E / 256);
    k_wfold<<<64, 64, 0, stream>>>(stats + ST0, c1g0, c1e0, c1w1, c1b1,
                                   wf1h, wf1l, bias2a, 1.f / E);
    k_lin64m<<<E / 128, 128, 0, stream>>>(z0h, z0l, wf1h, wf1l, bias2a,
                                          z1h, z1l, part);
    k_redstat<<<128, 256, 0, stream>>>(part, stats + ST1, E / 128);
    k_wfold<<<64, 64, 0, stream>>>(stats + ST1, c1g1, c1e1, c1w2, c1b2,
                                   wf2h, wf2l, bias2b, 1.f / E);
    k_lin64m<<<E / 128, 128, 0, stream>>>(z1h, z1l, wf2h, wf2l, bias2b,
                                          z2h, z2l, part);
    k_redstat<<<128, 256, 0, stream>>>(part, stats + ST2, E / 128);
    k_ec1_fin<<<BP * 64 / 256, 256, 0, stream>>>(z2h, z2l, stats + ST2, c1g2, c1e2,
                                                 x1h, x1l, sq2);
    k_knn2<<<B * 32 * QC2, 128, 0, stream>>>(x1h, x1l, sq2, cand_d, cand_i);
    k_knn2m<<<BP / 256, 256, 0, stream>>>(cand_d, cand_i, idx2);
    k_ec2m<<<E / 128, 256, 0, stream>>>(x1h, x1l, idx2, wdh, wdl, w1h, w1l,
                                        c2b, zA, stats + ST3);
    k_ec2_fin<<<BP * 128 / 256, 256, 0, stream>>>(zA, stats + ST3, c2g, c2e,
                                                  x2h, x2l);
    k_l1m<<<256 * 8, 256, 0, stream>>>(x1h, x1l, x2h, x2l, wthL, wtlL, l1b,
                                       stats + ST4, pmax, pmin);
    k_pool<<<64, 256, 0, stream>>>(stats + ST4, l1g, l1e, pmax, pmin, pbuf);
    k_m1<<<32, 256, 0, stream>>>(pbuf, m1w, m1b, t1, stats + ST5);
    k_m2<<<16, 256, 0, stream>>>(t1, stats + ST5, m1g, m1e, m2w, m2b, t2, stats + ST6);
    k_m3<<<1, 256, 0, stream>>>(t2, stats + ST6, m2g, m2e, m3w, m3b, out);
}

// Round 8
// 572.134 us; speedup vs baseline: 1.0177x; 1.0177x over previous
//
#include <hip/hip_runtime.h>
#include <cmath>

constexpr int B = 16, P = 2048, KNN = 5;
constexpr int BP = B * P;           // 32768
constexpr int E = BP * KNN;         // 163840
constexpr float EPS = 1e-5f;
constexpr int QC2 = 4;              // q-chunks for knn2 (R7: 8->4 revert; 8 doubled
                                    // p-frag refetch + cand traffic, net -10%)
constexpr int QC2_SHIFT = 2;
static_assert(QC2 == (1 << QC2_SHIFT), "QC2 pow2");

// stats layout (floats): per stage [sum[C] | sumsq[C]]
constexpr int ST0 = 0;        // 64ch -> 128
constexpr int ST1 = 128;      // 64ch
constexpr int ST2 = 256;      // 64ch
constexpr int ST3 = 384;      // 128ch -> 256
constexpr int ST4 = 640;      // 1024ch -> 2048
constexpr int ST5 = 2688;     // 512ch -> 1024
constexpr int ST6 = 3712;     // 256ch -> 512
constexpr int ST_TOTAL = 4224;

typedef __attribute__((ext_vector_type(8))) short bf16x8;
typedef __attribute__((ext_vector_type(4))) float f32x4;

__device__ inline unsigned short f2bf(float x) {
    unsigned u = __float_as_uint(x);
    unsigned r = (u + 0x7FFFu + ((u >> 16) & 1u)) >> 16;
    return (unsigned short)r;
}
__device__ inline float bf2f(unsigned short h) {
    return __uint_as_float(((unsigned)h) << 16);
}
// split x into hi (bf16) and lo (bf16 of residual): x ~= hi + lo, err ~2^-18 rel
__device__ inline void split2bf(float x, unsigned short& h, unsigned short& l) {
    unsigned short hh = f2bf(x);
    h = hh;
    l = f2bf(x - bf2f(hh));
}

// branch-free sorted-5 insertion (ascending); constant indices -> stays in VGPRs.
__device__ inline void ins5(float d, int qi, float bd[KNN], int bi[KNN]) {
    bool c0 = d < bd[0], c1 = d < bd[1], c2 = d < bd[2], c3 = d < bd[3], c4 = d < bd[4];
    bd[4] = c3 ? bd[3] : (c4 ? d : bd[4]);  bi[4] = c3 ? bi[3] : (c4 ? qi : bi[4]);
    bd[3] = c2 ? bd[2] : (c3 ? d : bd[3]);  bi[3] = c2 ? bi[2] : (c3 ? qi : bi[3]);
    bd[2] = c1 ? bd[1] : (c2 ? d : bd[2]);  bi[2] = c1 ? bi[1] : (c2 ? qi : bi[2]);
    bd[1] = c0 ? bd[0] : (c1 ? d : bd[1]);  bi[1] = c0 ? bi[0] : (c1 ? qi : bi[1]);
    bd[0] = c0 ? d : bd[0];                 bi[0] = c0 ? qi : bi[0];
}
// insertion with lexicographic (d, qi) tie-break: keep lower q on exact fp tie
__device__ inline void ins5t(float d, int qi, float bd[KNN], int bi[KNN]) {
    bool c0 = (d < bd[0]) || (d == bd[0] && qi < bi[0]);
    bool c1 = (d < bd[1]) || (d == bd[1] && qi < bi[1]);
    bool c2 = (d < bd[2]) || (d == bd[2] && qi < bi[2]);
    bool c3 = (d < bd[3]) || (d == bd[3] && qi < bi[3]);
    bool c4 = (d < bd[4]) || (d == bd[4] && qi < bi[4]);
    bd[4] = c3 ? bd[3] : (c4 ? d : bd[4]);  bi[4] = c3 ? bi[3] : (c4 ? qi : bi[4]);
    bd[3] = c2 ? bd[2] : (c3 ? d : bd[3]);  bi[3] = c2 ? bi[2] : (c3 ? qi : bi[3]);
    bd[2] = c1 ? bd[1] : (c2 ? d : bd[2]);  bi[2] = c1 ? bi[1] : (c2 ? qi : bi[2]);
    bd[1] = c0 ? bd[0] : (c1 ? d : bd[1]);  bi[1] = c0 ? bi[0] : (c1 ? qi : bi[1]);
    bd[0] = c0 ? d : bd[0];                 bi[0] = c0 ? qi : bi[0];
}
// butterfly-merge helper: pull partner's sorted-5 and insert with tie-break
__device__ inline void merge_xor(int w, float bd[KNN], int bi[KNN]) {
    float od[KNN]; int oi[KNN];
#pragma unroll
    for (int k = 0; k < KNN; ++k) {
        od[k] = __shfl_xor(bd[k], w, 64);
        oi[k] = __shfl_xor(bi[k], w, 64);
    }
#pragma unroll
    for (int k = 0; k < KNN; ++k) ins5t(od[k], oi[k], bd, bi);
}

// ---------------------------------------------------------------- init
__global__ void k_init(float* __restrict__ stats, float* __restrict__ pmax,
                       float* __restrict__ pmin) {
    int i = blockIdx.x * 256 + threadIdx.x;   // grid covers 16384
    if (i < ST_TOTAL) stats[i] = 0.f;
    if (i < B * 1024) { pmax[i] = 0.f; pmin[i] = INFINITY; }
}

// ---------------------------------------------------------------- deterministic partial reducer
__global__ __launch_bounds__(256) void k_redstat(const float* __restrict__ part,
        float* __restrict__ stats, int nblk) {
    __shared__ float r[256];
    int slot = blockIdx.x;
    float s = 0.f;
    for (int i = threadIdx.x; i < nblk; i += 256)
        s += part[(size_t)i * 128 + slot];
    r[threadIdx.x] = s; __syncthreads();
    for (int o = 128; o; o >>= 1) {
        if (threadIdx.x < o) r[threadIdx.x] += r[threadIdx.x + o];
        __syncthreads();
    }
    if (threadIdx.x == 0) stats[slot] = r[0];
}

// ---------------------------------------------------------------- weight pre-split: w[K][N] fp32 -> wt{h,l}[N][K] bf16
__global__ void k_wsplit(const float* __restrict__ w, unsigned short* __restrict__ th,
                         unsigned short* __restrict__ tl, int K, int N) {
    int i = blockIdx.x * 256 + threadIdx.x;
    if (i >= K * N) return;
    int k = i / N, n = i - k * N;          // read coalesced over n
    float f = w[i];
    unsigned short h = f2bf(f);
    th[(size_t)n * K + k] = h;
    tl[(size_t)n * K + k] = f2bf(f - bf2f(h));
}

// ---------------------------------------------------------------- BN-fold: wf[n][k] = scl[k]*w[k][n]; bias2 = bias + shf.w
__global__ __launch_bounds__(64) void k_wfold(const float* __restrict__ stats,
        const float* __restrict__ g, const float* __restrict__ be,
        const float* __restrict__ w, const float* __restrict__ bias,
        unsigned short* __restrict__ wfh, unsigned short* __restrict__ wfl,
        float* __restrict__ bias2, float invN) {
    __shared__ float red[64];
    int n = blockIdx.x, k = threadIdx.x;
    float mu = stats[k] * invN;
    float var = stats[64 + k] * invN - mu * mu;
    float sc = g[k] * rsqrtf(var + EPS);
    float sh = be[k] - mu * sc;
    float wv = w[k * 64 + n];
    float wf = sc * wv;
    unsigned short h, l;
    split2bf(wf, h, l);
    wfh[n * 64 + k] = h; wfl[n * 64 + k] = l;
    red[k] = sh * wv; __syncthreads();
    for (int o = 32; o; o >>= 1) {
        if (k < o) red[k] += red[k + o];
        __syncthreads();
    }
    if (k == 0) bias2[n] = bias[n] + red[0];
}

// ---------------------------------------------------------------- ec2 weight prep: W0-W1 and W1, transposed bf16 hi/lo
__global__ void k_wprep2(const float* __restrict__ w,   // c2w [128][128]
        unsigned short* __restrict__ wdh, unsigned short* __restrict__ wdl,
        unsigned short* __restrict__ w1h, unsigned short* __restrict__ w1l) {
    int i = blockIdx.x * 256 + threadIdx.x;  // 64*128
    if (i >= 64 * 128) return;
    int k = i >> 7, n = i & 127;
    float w0 = w[k * 128 + n];
    float w1 = w[(64 + k) * 128 + n];
    float wd = w0 - w1;
    unsigned short h, l;
    split2bf(wd, h, l); wdh[n * 64 + k] = h; wdl[n * 64 + k] = l;
    split2bf(w1, h, l); w1h[n * 64 + k] = h; w1l[n * 64 + k] = l;
}

// ---------------------------------------------------------------- kNN on pos (D=3)
__global__ __launch_bounds__(256) void k_knn1(const float* __restrict__ pos,
                                              int* __restrict__ idx1) {
    __shared__ float4 qt[2048];   // all q staged once (32 KB)
    int b = blockIdx.x >> 5;
    int p0 = (blockIdx.x & 31) << 6;
    const float* posb = pos + (size_t)b * P * 3;
#pragma unroll
    for (int t = 0; t < 8; ++t) {
        int q = (t << 8) + threadIdx.x;
        float qx = posb[q * 3 + 0], qy = posb[q * 3 + 1], qz = posb[q * 3 + 2];
        qt[q] = make_float4(qx, qy, qz, qx * qx + qy * qy + qz * qz);
    }
    __syncthreads();
    int pl = threadIdx.x >> 2, sub = threadIdx.x & 3;
    int p = p0 + pl;
    float4 me = qt[p];
    float x = me.x, y = me.y, z = me.z, sqp = me.w;
    float bd[KNN]; int bi[KNN];
#pragma unroll
    for (int i = 0; i < KNN; ++i) { bd[i] = INFINITY; bi[i] = 0; }
    for (int j0 = 0; j0 < 512; j0 += 8) {
        float4 v[8];
#pragma unroll
        for (int u = 0; u < 8; ++u) v[u] = qt[((j0 + u) << 2) | sub];
#pragma unroll
        for (int u = 0; u < 8; ++u) {
            float dot = x * v[u].x + y * v[u].y + z * v[u].z;
            float d2 = sqp + v[u].w - 2.f * dot;
            if (d2 < bd[KNN - 1]) ins5(d2, ((j0 + u) << 2) | sub, bd, bi);
        }
    }
    // butterfly merge across the 4 subs; snapshot-then-insert
#pragma unroll
    for (int w = 1; w <= 2; w <<= 1) {
        float od[KNN]; int oi[KNN];
#pragma unroll
        for (int i = 0; i < KNN; ++i) {
            od[i] = __shfl_xor(bd[i], w, 64);
            oi[i] = __shfl_xor(bi[i], w, 64);
        }
#pragma unroll
        for (int i = 0; i < KNN; ++i) ins5t(od[i], oi[i], bd, bi);
    }
    if (sub == 0) {
        size_t o = ((size_t)b * P + p) * KNN;
#pragma unroll
        for (int i = 0; i < KNN; ++i) idx1[o + i] = bi[i];
    }
}

// ---------------------------------------------------------------- edgeconv1 layer0: e[6] @ w[6,64]; bf16 hi/lo out + partials
__global__ __launch_bounds__(256) void k_ec1_l0(const float* __restrict__ pos,
        const int* __restrict__ idx1, const float* __restrict__ w,
        const float* __restrict__ bias, unsigned short* __restrict__ zh,
        unsigned short* __restrict__ zl, float* __restrict__ part) {
    __shared__ float elds[256][6];
    __shared__ float red[256];
    int tid = threadIdx.x;
    int base = blockIdx.x * 256;
    {
        int e = base + tid;
        int bp = e / KNN;
        int bb = bp >> 11;
        int q = idx1[e];
        const float* pi = pos + (size_t)bp * 3;
        const float* pj = pos + ((size_t)(bb << 11) + q) * 3;
        float x0 = pi[0], x1v = pi[1], x2v = pi[2];
        elds[tid][0] = x0; elds[tid][1] = x1v; elds[tid][2] = x2v;
        elds[tid][3] = pj[0] - x0; elds[tid][4] = pj[1] - x1v; elds[tid][5] = pj[2] - x2v;
    }
    int c = tid & 63, lane = tid >> 6;
    float wr[6];
#pragma unroll
    for (int d = 0; d < 6; ++d) wr[d] = w[d * 64 + c];
    float bc = bias[c];
    __syncthreads();
    float s1 = 0.f, s2 = 0.f;
    for (int i = 0; i < 64; ++i) {
        int e = lane + (i << 2);
        float acc = bc;
#pragma unroll
        for (int d = 0; d < 6; ++d) acc = fmaf(elds[e][d], wr[d], acc);
        acc = fmaxf(acc, 0.f);
        unsigned short h, l;
        split2bf(acc, h, l);
        zh[(size_t)(base + e) * 64 + c] = h;
        zl[(size_t)(base + e) * 64 + c] = l;
        s1 += acc; s2 = fmaf(acc, acc, s2);
    }
    red[tid] = s1; __syncthreads();
    if (tid < 64) part[(size_t)blockIdx.x * 128 + tid] =
        red[tid] + red[tid + 64] + red[tid + 128] + red[tid + 192];
    __syncthreads();
    red[tid] = s2; __syncthreads();
    if (tid < 64) part[(size_t)blockIdx.x * 128 + 64 + tid] =
        red[tid] + red[tid + 64] + red[tid + 128] + red[tid + 192];
}

// ---------------------------------------------------------------- 64->64 layer (BN folded into weights; direct-frag MFMA)
__global__ __launch_bounds__(128) void k_lin64m(
        const unsigned short* __restrict__ zinh, const unsigned short* __restrict__ zinl,
        const unsigned short* __restrict__ wfh, const unsigned short* __restrict__ wfl,
        const float* __restrict__ bias2, unsigned short* __restrict__ zouth,
        unsigned short* __restrict__ zoutl, float* __restrict__ part) {
    __shared__ float red[2 * 64 * 2];
    int tid = threadIdx.x;
    int wv = tid >> 6, lane = tid & 63;
    int l15 = lane & 15, quad = lane >> 4;
    int row0 = blockIdx.x * 128 + wv * 64;
    f32x4 acc[4][4];
#pragma unroll
    for (int i = 0; i < 4; ++i)
#pragma unroll
        for (int j = 0; j < 4; ++j) acc[i][j] = (f32x4)0.f;

#pragma unroll
    for (int kc = 0; kc < 2; ++kc) {
        bf16x8 afh[4], afl[4], bfh[4], bfl[4];
#pragma unroll
        for (int i = 0; i < 4; ++i) {
            size_t o = (size_t)(row0 + i * 16 + l15) * 64 + kc * 32 + quad * 8;
            afh[i] = *(const bf16x8*)&zinh[o];
            afl[i] = *(const bf16x8*)&zinl[o];
        }
#pragma unroll
        for (int j = 0; j < 4; ++j) {
            size_t wo = (size_t)(j * 16 + l15) * 64 + kc * 32 + quad * 8;
            bfh[j] = *(const bf16x8*)&wfh[wo];
            bfl[j] = *(const bf16x8*)&wfl[wo];
        }
#pragma unroll
        for (int i = 0; i < 4; ++i)
#pragma unroll
            for (int j = 0; j < 4; ++j) {
                acc[i][j] = __builtin_amdgcn_mfma_f32_16x16x32_bf16(afh[i], bfh[j], acc[i][j], 0, 0, 0);
                acc[i][j] = __builtin_amdgcn_mfma_f32_16x16x32_bf16(afh[i], bfl[j], acc[i][j], 0, 0, 0);
                acc[i][j] = __builtin_amdgcn_mfma_f32_16x16x32_bf16(afl[i], bfh[j], acc[i][j], 0, 0, 0);
            }
    }
    // epilogue: bias + ReLU, bf16 split store, per-col stats
#pragma unroll
    for (int j = 0; j < 4; ++j) {
        int colL = j * 16 + l15;
        float bl = bias2[colL];
        float s1 = 0.f, s2 = 0.f;
#pragma unroll
        for (int i = 0; i < 4; ++i) {
            int row = row0 + i * 16 + quad * 4;
#pragma unroll
            for (int r = 0; r < 4; ++r) {
                float v = fmaxf(acc[i][j][r] + bl, 0.f);
                unsigned short h, l;
                split2bf(v, h, l);
                zouth[(size_t)(row + r) * 64 + colL] = h;
                zoutl[(size_t)(row + r) * 64 + colL] = l;
                s1 += v; s2 = fmaf(v, v, s2);
            }
        }
        s1 += __shfl_xor(s1, 16, 64); s1 += __shfl_xor(s1, 32, 64);
        s2 += __shfl_xor(s2, 16, 64); s2 += __shfl_xor(s2, 32, 64);
        if (quad == 0) {
            red[(wv * 64 + colL) * 2 + 0] = s1;
            red[(wv * 64 + colL) * 2 + 1] = s2;
        }
    }
    __syncthreads();
    if (tid < 64) {
        part[(size_t)blockIdx.x * 128 + tid] =
            red[tid * 2] + red[(64 + tid) * 2];
        part[(size_t)blockIdx.x * 128 + 64 + tid] =
            red[tid * 2 + 1] + red[(64 + tid) * 2 + 1];
    }
}

// ---------------------------------------------------------------- ec1 finalize: BN + max over k -> x1 bf16 hi/lo (fused xsplit), sq norms
// NOTE: x1h/x1l MUST NOT alias z2h/z2l (R5 bug: in-place overwrite raced
// with other blocks' reads of z2 rows). x1 pair has a dedicated allocation.
__global__ __launch_bounds__(256) void k_ec1_fin(const unsigned short* __restrict__ z2h,
        const unsigned short* __restrict__ z2l,
        const float* __restrict__ statsIn, const float* __restrict__ g,
        const float* __restrict__ be, unsigned short* __restrict__ x1h,
        unsigned short* __restrict__ x1l, float* __restrict__ sq2) {
    int tid = threadIdx.x;
    int o = blockIdx.x * 256 + tid;
    int c = o & 63; int bp = o >> 6;
    float mu = statsIn[c] * (1.f / E);
    float var = statsIn[64 + c] * (1.f / E) - mu * mu;
    float sc = g[c] * rsqrtf(var + EPS);
    float sh = be[c] - mu * sc;
    float m = -INFINITY;
#pragma unroll
    for (int j = 0; j < KNN; ++j) {
        size_t zo = ((size_t)bp * KNN + j) * 64 + c;
        float v = bf2f(z2h[zo]) + bf2f(z2l[zo]);
        m = fmaxf(m, fmaf(v, sc, sh));
    }
    unsigned short h, l;
    split2bf(m, h, l);
    x1h[o] = h; x1l[o] = l;
    float ss = m * m;
#pragma unroll
    for (int off = 32; off; off >>= 1) ss += __shfl_down(ss, off, 64);
    if (c == 0) sq2[bp] = ss;
}

// ---------------------------------------------------------------- kNN2 partial
// R19: swapped-operand Gram -> C[q][p] with p=lane&15: lane owns full p-rows,
// top-5 scan on MFMA accumulator registers; no LDS key tile.
// R20: spill disaster. R21: 2 sequential p-passes -> doubled loads, 175us.
// R22: q-frags shared across both p-tiles -> 91us, VGPR 56.
// R23: float4 sq2 loads (kills 32 ds_bpermute/t-iter). R24: QC2 8 regressed
// (p-frag refetch + cand traffic doubled; occupancy gain never materialized)
// -> back to QC2=4.
__global__ __launch_bounds__(128) void k_knn2(const unsigned short* __restrict__ x1h,
        const unsigned short* __restrict__ x1l, const float* __restrict__ sq2,
        float* __restrict__ cd, int* __restrict__ ci) {
    int tid = threadIdx.x;
    int wv = tid >> 6, lane = tid & 63;
    int l15 = lane & 15, quad = lane >> 4;
    int qc = blockIdx.x & (QC2 - 1);
    int pt = blockIdx.x >> QC2_SHIFT;         // 16*32 ptiles of 64 rows
    int b = pt >> 5;
    int pw = ((pt & 31) << 6) + wv * 32;      // wave p base within batch
    const size_t xbase = (size_t)b * P * 64;
    int qlo = qc * (P / QC2);                 // 512-q chunk

    // B operand: p-row fragments for both 16-row tiles (held whole kernel)
    bf16x8 ph[2][2], pl_[2][2];               // [i][kc]
#pragma unroll
    for (int i = 0; i < 2; ++i)
#pragma unroll
        for (int kc = 0; kc < 2; ++kc) {
            size_t o = xbase + (size_t)(pw + i * 16 + l15) * 64 + kc * 32 + quad * 8;
            ph[i][kc] = *(const bf16x8*)&x1h[o];
            pl_[i][kc] = *(const bf16x8*)&x1l[o];
        }
    // per-lane top-5 for p-rows l15 (0) and 16+l15 (1)
    float bd0[KNN], bd1[KNN]; int bi0[KNN], bi1[KNN];
#pragma unroll
    for (int i = 0; i < KNN; ++i) {
        bd0[i] = INFINITY; bi0[i] = 0;
        bd1[i] = INFINITY; bi1[i] = 0;
    }

#pragma unroll 1
    for (int t = 0; t < (P / QC2) / 128; ++t) {
        int q0 = qlo + (t << 7);
#pragma unroll 1
        for (int j = 0; j < 8; ++j) {
            f32x4 a0 = (f32x4)0.f, a1 = (f32x4)0.f;
#pragma unroll
            for (int kc = 0; kc < 2; ++kc) {
                size_t o = xbase + (size_t)(q0 + j * 16 + l15) * 64 + kc * 32 + quad * 8;
                bf16x8 qh = *(const bf16x8*)&x1h[o];
                bf16x8 ql = *(const bf16x8*)&x1l[o];
                a0 = __builtin_amdgcn_mfma_f32_16x16x32_bf16(qh, ph[0][kc], a0, 0, 0, 0);
                a0 = __builtin_amdgcn_mfma_f32_16x16x32_bf16(qh, pl_[0][kc], a0, 0, 0, 0);
                a0 = __builtin_amdgcn_mfma_f32_16x16x32_bf16(ql, ph[0][kc], a0, 0, 0, 0);
                a1 = __builtin_amdgcn_mfma_f32_16x16x32_bf16(qh, ph[1][kc], a1, 0, 0, 0);
                a1 = __builtin_amdgcn_mfma_f32_16x16x32_bf16(qh, pl_[1][kc], a1, 0, 0, 0);
                a1 = __builtin_amdgcn_mfma_f32_16x16x32_bf16(ql, ph[1][kc], a1, 0, 0, 0);
            }
            // scan: this lane's 4 candidates are contiguous -> one float4 sq load
            int qb = q0 + j * 16 + (quad << 2);
            f32x4 sq4 = *(const f32x4*)&sq2[b * P + qb];
#pragma unroll
            for (int r = 0; r < 4; ++r) {
                float d0 = fmaf(a0[r], -2.f, sq4[r]);
                if (d0 < bd0[KNN - 1]) ins5(d0, qb + r, bd0, bi0);
                float d1 = fmaf(a1[r], -2.f, sq4[r]);
                if (d1 < bd1[KNN - 1]) ins5(d1, qb + r, bd1, bi1);
            }
        }
    }
    // merge across the 4 quads sharing l15 (disjoint q mod 16 -> clean ties)
    merge_xor(16, bd0, bi0); merge_xor(16, bd1, bi1);
    merge_xor(32, bd0, bi0); merge_xor(32, bd1, bi1);
    if (quad == 0) {
        size_t o0 = (((size_t)b * P + pw + l15) * QC2 + qc) * KNN;
        size_t o1 = (((size_t)b * P + pw + 16 + l15) * QC2 + qc) * KNN;
#pragma unroll
        for (int k = 0; k < KNN; ++k) {
            cd[o0 + k] = bd0[k]; ci[o0 + k] = bi0[k];
            cd[o1 + k] = bd1[k]; ci[o1 + k] = bi1[k];
        }
    }
}

// ---------------------------------------------------------------- kNN2 merge (QC2 sorted chunks of 5 -> 5)
__global__ __launch_bounds__(256) void k_knn2m(const float* __restrict__ cd,
        const int* __restrict__ ci, int* __restrict__ idx2) {
    int bp = blockIdx.x * 256 + threadIdx.x;
    float bd[KNN]; int bi[KNN];
#pragma unroll
    for (int i = 0; i < KNN; ++i) { bd[i] = INFINITY; bi[i] = 0; }
    size_t o = (size_t)bp * QC2 * KNN;
    for (int t = 0; t < QC2 * KNN; ++t) {
        float d2 = cd[o + t]; int qi = ci[o + t];
        if (d2 < bd[KNN - 1]) ins5(d2, qi, bd, bi);
    }
#pragma unroll
    for (int i = 0; i < KNN; ++i) idx2[bp * KNN + i] = bi[i];
}

// ---------------------------------------------------------------- edgeconv2 (direct-fragment split-bf16 MFMA)
__global__ __launch_bounds__(256) void k_ec2m(
        const unsigned short* __restrict__ x1h, const unsigned short* __restrict__ x1l,
        const int* __restrict__ idx2,
        const unsigned short* __restrict__ wdh, const unsigned short* __restrict__ wdl,
        const unsigned short* __restrict__ w1h, const unsigned short* __restrict__ w1l,
        const float* __restrict__ bias, float* __restrict__ zout,
        float* __restrict__ stats) {
    __shared__ float red[2 * 128 * 2];
    int tid = threadIdx.x;
    int base = blockIdx.x * 128;            // first edge
    int bb = base / (P * KNN);              // batch (blocks never straddle: 10240%128==0)
    int wv = tid >> 6, lane = tid & 63;
    int wm = wv >> 1, wn = wv & 1;
    int l15 = lane & 15, quad = lane >> 4;
    // per-lane A rows for this wave's 4 row-tiles
    int rI[4], rJ[4];
#pragma unroll
    for (int i = 0; i < 4; ++i) {
        int e = base + wm * 64 + i * 16 + l15;
        rI[i] = e / KNN;
        rJ[i] = (bb << 11) + idx2[e];
    }
    f32x4 acc[4][4];
#pragma unroll
    for (int i = 0; i < 4; ++i)
#pragma unroll
        for (int j = 0; j < 4; ++j) acc[i][j] = (f32x4)0.f;

#pragma unroll
    for (int s = 0; s < 2; ++s) {
        const unsigned short* bh_ = s ? w1h : wdh;
        const unsigned short* bl_ = s ? w1l : wdl;
#pragma unroll
        for (int kc = 0; kc < 2; ++kc) {
            bf16x8 afh[4], afl[4], bfh[4], bfl[4];
#pragma unroll
            for (int i = 0; i < 4; ++i) {
                int row = s ? rJ[i] : rI[i];
                size_t o = (size_t)row * 64 + kc * 32 + quad * 8;
                afh[i] = *(const bf16x8*)&x1h[o];
                afl[i] = *(const bf16x8*)&x1l[o];
            }
#pragma unroll
            for (int j = 0; j < 4; ++j) {
                size_t wo = (size_t)(wn * 64 + j * 16 + l15) * 64 + kc * 32 + quad * 8;
                bfh[j] = *(const bf16x8*)&bh_[wo];
                bfl[j] = *(const bf16x8*)&bl_[wo];
            }
#pragma unroll
            for (int i = 0; i < 4; ++i)
#pragma unroll
                for (int j = 0; j < 4; ++j) {
                    acc[i][j] = __builtin_amdgcn_mfma_f32_16x16x32_bf16(afh[i], bfh[j], acc[i][j], 0, 0, 0);
                    acc[i][j] = __builtin_amdgcn_mfma_f32_16x16x32_bf16(afh[i], bfl[j], acc[i][j], 0, 0, 0);
                    acc[i][j] = __builtin_amdgcn_mfma_f32_16x16x32_bf16(afl[i], bfh[j], acc[i][j], 0, 0, 0);
                }
        }
    }
    // epilogue: bias + ReLU, write z, per-col stats
#pragma unroll
    for (int j = 0; j < 4; ++j) {
        int colL = wn * 64 + j * 16 + l15;
        float bl = bias[colL];
        float s1 = 0.f, s2 = 0.f;
#pragma unroll
        for (int i = 0; i < 4; ++i) {
            int row = wm * 64 + i * 16 + quad * 4;
#pragma unroll
            for (int r = 0; r < 4; ++r) {
                float v = fmaxf(acc[i][j][r] + bl, 0.f);
                zout[(size_t)(base + row + r) * 128 + colL] = v;
                s1 += v; s2 = fmaf(v, v, s2);
            }
        }
        s1 += __shfl_xor(s1, 16, 64); s1 += __shfl_xor(s1, 32, 64);
        s2 += __shfl_xor(s2, 16, 64); s2 += __shfl_xor(s2, 32, 64);
        if (quad == 0) {
            red[(wm * 128 + colL) * 2 + 0] = s1;
            red[(wm * 128 + colL) * 2 + 1] = s2;
        }
    }
    __syncthreads();
    if (tid < 128) {
        atomicAdd(&stats[tid], red[tid * 2] + red[(128 + tid) * 2]);
        atomicAdd(&stats[128 + tid], red[tid * 2 + 1] + red[(128 + tid) * 2 + 1]);
    }
}

// ---------------------------------------------------------------- ec2 finalize: BN + max over k -> x2 bf16 hi/lo (fused xsplit)
// safe: z3 lives in zA, x2 pair lives in zB — disjoint buffers.
__global__ __launch_bounds__(256) void k_ec2_fin(const float* __restrict__ z3,
        const float* __restrict__ stats, const float* __restrict__ g,
        const float* __restrict__ be, unsigned short* __restrict__ x2h,
        unsigned short* __restrict__ x2l) {
    int o = blockIdx.x * 256 + threadIdx.x;
    int c = o & 127; int bp = o >> 7;
    float mu = stats[c] * (1.f / E);
    float var = stats[128 + c] * (1.f / E) - mu * mu;
    float sc = g[c] * rsqrtf(var + EPS);
    float sh = be[c] - mu * sc;
    float m = -INFINITY;
#pragma unroll
    for (int j = 0; j < KNN; ++j)
        m = fmaxf(m, fmaf(z3[((size_t)bp * KNN + j) * 128 + c], sc, sh));
    unsigned short h, l;
    split2bf(m, h, l);
    x2h[o] = h; x2l[o] = l;
}

// ---------------------------------------------------------------- l1 (LDS-staged split-bf16 MFMA, m97-style 2-phase)
// R18: coalesced global_load_lds staging + ds_read_b128 frags fixed the
// latency-bound direct-gather version (108 -> out of top-5).
__device__ __forceinline__ void gl16(unsigned short* lds, const unsigned short* g) {
    __builtin_amdgcn_global_load_lds(
        (const __attribute__((address_space(1))) unsigned int*)g,
        (__attribute__((address_space(3))) unsigned int*)lds, 16, 0, 0);
}

__global__ __launch_bounds__(256) void k_l1m(
        const unsigned short* __restrict__ x1h, const unsigned short* __restrict__ x1l,
        const unsigned short* __restrict__ x2h, const unsigned short* __restrict__ x2l,
        const unsigned short* __restrict__ wth, const unsigned short* __restrict__ wtl,
        const float* __restrict__ bias, float* __restrict__ stats,
        float* __restrict__ pmax, float* __restrict__ pmin) {
    __shared__ unsigned short Ah[128 * 32], Al[128 * 32];   // [row][k] bf16, 8 KB each
    __shared__ unsigned short Bh[128 * 32], Bl[128 * 32];   // [col][k] bf16
    __shared__ float red[2 * 128 * 4];
    int tid = threadIdx.x;
    int brow = blockIdx.x & 255;
    int bcol = blockIdx.x >> 8;
    int row0 = brow << 7, col0 = bcol << 7;
    int wv = tid >> 6, lane = tid & 63;
    int wm = wv >> 1, wn = wv & 1;
    int l15 = lane & 15, quad = lane >> 4;
    int rloc = wv * 16 + (lane >> 2);      // staging row for call 0 (+64 for call 1)
    int ch8 = (lane & 3) * 8;              // staging k-chunk (ushorts, 16 B)
    f32x4 acc[4][4];
#pragma unroll
    for (int i = 0; i < 4; ++i)
#pragma unroll
        for (int j = 0; j < 4; ++j) acc[i][j] = (f32x4)0.f;

#pragma unroll
    for (int t = 0; t < 6; ++t) {
        int k0 = t * 32;
        const unsigned short* ah = (k0 < 64) ? x1h : x2h;
        const unsigned short* al = (k0 < 64) ? x1l : x2l;
        int astr = (k0 < 64) ? 64 : 128;
        int aoff = (k0 < 64) ? k0 : (k0 - 64);
        // stage: 32 KB/step, 8 x 16B global_load_lds per thread, 1 KB/wave/call
#pragma unroll
        for (int c = 0; c < 2; ++c) {
            int rl = c * 64 + rloc;
            size_t ao = (size_t)(row0 + rl) * astr + aoff + ch8;
            size_t bo = (size_t)(col0 + rl) * 192 + k0 + ch8;
            int lb = (c * 64 + wv * 16) * 32;   // wave-uniform LDS base (ushorts)
            gl16(&Ah[lb], &ah[ao]);
            gl16(&Al[lb], &al[ao]);
            gl16(&Bh[lb], &wth[bo]);
            gl16(&Bl[lb], &wtl[bo]);
        }
        __syncthreads();    // compiler drains vmcnt before s_barrier
        bf16x8 afh[4], afl[4], bfh[4], bfl[4];
#pragma unroll
        for (int i = 0; i < 4; ++i) {
            int o = (wm * 64 + i * 16 + l15) * 32 + quad * 8;
            afh[i] = *(const bf16x8*)&Ah[o];
            afl[i] = *(const bf16x8*)&Al[o];
        }
#pragma unroll
        for (int j = 0; j < 4; ++j) {
            int o = (wn * 64 + j * 16 + l15) * 32 + quad * 8;
            bfh[j] = *(const bf16x8*)&Bh[o];
            bfl[j] = *(const bf16x8*)&Bl[o];
        }
#pragma unroll
        for (int i = 0; i < 4; ++i)
#pragma unroll
            for (int j = 0; j < 4; ++j) {
                acc[i][j] = __builtin_amdgcn_mfma_f32_16x16x32_bf16(afh[i], bfh[j], acc[i][j], 0, 0, 0);
                acc[i][j] = __builtin_amdgcn_mfma_f32_16x16x32_bf16(afh[i], bfl[j], acc[i][j], 0, 0, 0);
                acc[i][j] = __builtin_amdgcn_mfma_f32_16x16x32_bf16(afl[i], bfh[j], acc[i][j], 0, 0, 0);
            }
        __syncthreads();    // protect LDS re-stage of step t+1
    }
    // epilogue: bias + ReLU, per-col sum/sumsq/max/min (h never materialized)
#pragma unroll
    for (int j = 0; j < 4; ++j) {
        int colL = wn * 64 + j * 16 + l15;
        float bl = bias[col0 + colL];
        float s1 = 0.f, s2 = 0.f, mx = 0.f, mn = INFINITY;
#pragma unroll
        for (int i = 0; i < 4; ++i)
#pragma unroll
            for (int r = 0; r < 4; ++r) {
                float v = fmaxf(acc[i][j][r] + bl, 0.f);
                s1 += v; s2 = fmaf(v, v, s2);
                mx = fmaxf(mx, v); mn = fminf(mn, v);
            }
        s1 += __shfl_xor(s1, 16, 64); s1 += __shfl_xor(s1, 32, 64);
        s2 += __shfl_xor(s2, 16, 64); s2 += __shfl_xor(s2, 32, 64);
        mx = fmaxf(mx, __shfl_xor(mx, 16, 64)); mx = fmaxf(mx, __shfl_xor(mx, 32, 64));
        mn = fminf(mn, __shfl_xor(mn, 16, 64)); mn = fminf(mn, __shfl_xor(mn, 32, 64));
        if (quad == 0) {
            float* rp = &red[(wm * 128 + colL) * 4];
            rp[0] = s1; rp[1] = s2; rp[2] = mx; rp[3] = mn;
        }
    }
    __syncthreads();
    if (tid < 128) {
        const float* r0 = &red[tid * 4];
        const float* r1 = &red[(128 + tid) * 4];
        int bb = row0 >> 11;
        atomicAdd(&stats[col0 + tid], r0[0] + r1[0]);
        atomicAdd(&stats[1024 + col0 + tid], r0[1] + r1[1]);
        atomicMax((unsigned int*)&pmax[bb * 1024 + col0 + tid],
                  __float_as_uint(fmaxf(r0[2], r1[2])));
        atomicMin((unsigned int*)&pmin[bb * 1024 + col0 + tid],
                  __float_as_uint(fminf(r0[3], r1[3])));
    }
}

// ---------------------------------------------------------------- pooled p = BN(max or min)
__global__ void k_pool(const float* __restrict__ stats, const float* __restrict__ g,
                       const float* __restrict__ be, const float* __restrict__ pmax,
                       const float* __restrict__ pmin, float* __restrict__ p) {
    int o = blockIdx.x * 256 + threadIdx.x;   // 16384
    int c = o & 1023;
    float mu = stats[c] * (1.f / BP);
    float var = stats[1024 + c] * (1.f / BP) - mu * mu;
    float sc = g[c] * rsqrtf(var + EPS);
    float sh = be[c] - mu * sc;
    float v = (sc >= 0.f) ? pmax[o] : pmin[o];
    p[o] = fmaf(v, sc, sh);
}

// ---------------------------------------------------------------- head
__global__ __launch_bounds__(256) void k_m1(const float* __restrict__ p,
        const float* __restrict__ w, const float* __restrict__ bias,
        float* __restrict__ t1, float* __restrict__ stats) {
    int o = blockIdx.x * 256 + threadIdx.x;   // 8192
    int c = o & 511, b = o >> 9;
    const float* pr = p + (b << 10);
    float acc = bias[c];
    for (int k = 0; k < 1024; ++k) acc = fmaf(pr[k], w[k * 512 + c], acc);
    acc = fmaxf(acc, 0.f);
    t1[o] = acc;
    atomicAdd(&stats[c], acc);
    atomicAdd(&stats[512 + c], acc * acc);
}

__global__ __launch_bounds__(256) void k_m2(const float* __restrict__ t1,
        const float* __restrict__ stats5, const float* __restrict__ g,
        const float* __restrict__ be, const float* __restrict__ w,
        const float* __restrict__ bias, float* __restrict__ t2,
        float* __restrict__ stats6) {
    __shared__ float scl[512], shf[512];
    int tid = threadIdx.x;
    for (int t = tid; t < 512; t += 256) {
        float mu = stats5[t] * (1.f / 16.f);
        float var = stats5[512 + t] * (1.f / 16.f) - mu * mu;
        float sc = g[t] * rsqrtf(var + EPS);
        scl[t] = sc; shf[t] = be[t] - mu * sc;
    }
    __syncthreads();
    int o = blockIdx.x * 256 + tid;   // 4096
    int c = o & 255, b = o >> 8;
    const float* tr = t1 + (b << 9);
    float acc = bias[c];
    for (int k = 0; k < 512; ++k) {
        float u = fmaf(tr[k], scl[k], shf[k]);
        acc = fmaf(u, w[k * 256 + c], acc);
    }
    acc = fmaxf(acc, 0.f);
    t2[o] = acc;
    atomicAdd(&stats6[c], acc);
    atomicAdd(&stats6[256 + c], acc * acc);
}

__global__ __launch_bounds__(256) void k_m3(const float* __restrict__ t2,
        const float* __restrict__ stats6, const float* __restrict__ g,
        const float* __restrict__ be, const float* __restrict__ w,
        const float* __restrict__ bias, float* __restrict__ out) {
    __shared__ float scl[256], shf[256];
    int tid = threadIdx.x;
    {
        float mu = stats6[tid] * (1.f / 16.f);
        float var = stats6[256 + tid] * (1.f / 16.f) - mu * mu;
        float sc = g[tid] * rsqrtf(var + EPS);
        scl[tid] = sc; shf[tid] = be[tid] - mu * sc;
    }
    __syncthreads();
    if (tid < 32) {
        int c = tid & 1, b = tid >> 1;
        const float* tr = t2 + (b << 8);
        float acc = bias[c];
        for (int k = 0; k < 256; ++k) {
            float u = fmaf(tr[k], scl[k], shf[k]);
            acc = fmaf(u, w[k * 2 + c], acc);
        }
        out[tid] = acc;
    }
}

// ================================================================ launch
extern "C" void kernel_launch(void* const* d_in, const int* in_sizes, int n_in,
                              void* d_out, int out_size, void* d_ws, size_t ws_size,
                              hipStream_t stream) {
    const float* pos  = (const float*)d_in[0];
    const float* c1w0 = (const float*)d_in[1];
    const float* c1b0 = (const float*)d_in[2];
    const float* c1g0 = (const float*)d_in[3];
    const float* c1e0 = (const float*)d_in[4];
    const float* c1w1 = (const float*)d_in[5];
    const float* c1b1 = (const float*)d_in[6];
    const float* c1g1 = (const float*)d_in[7];
    const float* c1e1 = (const float*)d_in[8];
    const float* c1w2 = (const float*)d_in[9];
    const float* c1b2 = (const float*)d_in[10];
    const float* c1g2 = (const float*)d_in[11];
    const float* c1e2 = (const float*)d_in[12];
    const float* c2w  = (const float*)d_in[13];
    const float* c2b  = (const float*)d_in[14];
    const float* c2g  = (const float*)d_in[15];
    const float* c2e  = (const float*)d_in[16];
    const float* l1w  = (const float*)d_in[17];
    const float* l1b  = (const float*)d_in[18];
    const float* l1g  = (const float*)d_in[19];
    const float* l1e  = (const float*)d_in[20];
    const float* m1w  = (const float*)d_in[21];
    const float* m1b  = (const float*)d_in[22];
    const float* m1g  = (const float*)d_in[23];
    const float* m1e  = (const float*)d_in[24];
    const float* m2w  = (const float*)d_in[25];
    const float* m2b  = (const float*)d_in[26];
    const float* m2g  = (const float*)d_in[27];
    const float* m2e  = (const float*)d_in[28];
    const float* m3w  = (const float*)d_in[29];
    const float* m3b  = (const float*)d_in[30];
    float* out = (float*)d_out;

    char* ws = (char*)d_ws;
    size_t off = 0;
    auto alloc = [&](size_t bytes) {
        size_t r = off; off = (off + bytes + 255) & ~(size_t)255; return r;
    };
    float* stats = (float*)(ws + alloc(ST_TOTAL * 4));
    float* pmax  = (float*)(ws + alloc(16 * 1024 * 4));
    float* pmin  = (float*)(ws + alloc(16 * 1024 * 4));
    float* pbuf  = (float*)(ws + alloc(16 * 1024 * 4));
    float* t1    = (float*)(ws + alloc(16 * 512 * 4));
    float* t2    = (float*)(ws + alloc(16 * 256 * 4));
    float* sq2   = (float*)(ws + alloc((size_t)BP * 4));
    float* part  = (float*)(ws + alloc((size_t)(E / 64) * 128 * 4));  // up to 2560 blocks x 128
    unsigned short* wthL = (unsigned short*)(ws + alloc((size_t)192 * 1024 * 2));
    unsigned short* wtlL = (unsigned short*)(ws + alloc((size_t)192 * 1024 * 2));
    unsigned short* wdh  = (unsigned short*)(ws + alloc((size_t)128 * 64 * 2));
    unsigned short* wdl  = (unsigned short*)(ws + alloc((size_t)128 * 64 * 2));
    unsigned short* w1h  = (unsigned short*)(ws + alloc((size_t)128 * 64 * 2));
    unsigned short* w1l  = (unsigned short*)(ws + alloc((size_t)128 * 64 * 2));
    unsigned short* wf1h = (unsigned short*)(ws + alloc((size_t)64 * 64 * 2));
    unsigned short* wf1l = (unsigned short*)(ws + alloc((size_t)64 * 64 * 2));
    unsigned short* wf2h = (unsigned short*)(ws + alloc((size_t)64 * 64 * 2));
    unsigned short* wf2l = (unsigned short*)(ws + alloc((size_t)64 * 64 * 2));
    float* bias2a = (float*)(ws + alloc(64 * 4));
    float* bias2b = (float*)(ws + alloc(64 * 4));
    int*   idx1  = (int*)  (ws + alloc((size_t)E * 4));
    int*   idx2  = (int*)  (ws + alloc((size_t)E * 4));
    // dedicated x1 bf16 pair (R6 fix: must NOT alias z2 — ec1_fin reads z2
    // and writes x1 in the same kernel; aliasing raced across blocks)
    unsigned short* x1h = (unsigned short*)(ws + alloc((size_t)BP * 64 * 2));
    unsigned short* x1l = (unsigned short*)(ws + alloc((size_t)BP * 64 * 2));
    float* zA    = (float*)(ws + alloc((size_t)E * 128 * 4)); // hosts z0/z1 bf16 pairs, later z3 fp32
    float* zB    = (float*)(ws + alloc((size_t)E * 64 * 4));  // hosts z2 bf16 pair, later knn2 scratch
    // zA aliases: z0h/z0l (21MB each) then z1h/z1l; all dead before z3 (ec2 out) overwrites
    unsigned short* z0h = (unsigned short*)zA;
    unsigned short* z0l = z0h + (size_t)E * 64;
    unsigned short* z1h = z0l + (size_t)E * 64;
    unsigned short* z1l = z1h + (size_t)E * 64;
    // zB aliases: z2h/z2l (dead after ec1_fin completes), then knn2 scratch:
    // cand 5.2MB + x2 pair 16.8MB = 22 < 41.9MB
    unsigned short* z2h = (unsigned short*)zB;
    unsigned short* z2l = z2h + (size_t)E * 64;
    float* cand_d = (float*)zB;
    int*   cand_i = (int*)(cand_d + (size_t)BP * QC2 * KNN);
    unsigned short* x2h = (unsigned short*)(cand_i + (size_t)BP * QC2 * KNN);
    unsigned short* x2l = x2h + (size_t)BP * 128;

    (void)in_sizes; (void)n_in; (void)out_size; (void)ws_size;

    k_init<<<64, 256, 0, stream>>>(stats, pmax, pmin);
    k_wsplit<<<(192 * 1024 + 255) / 256, 256, 0, stream>>>(l1w, wthL, wtlL, 192, 1024);
    k_wprep2<<<(64 * 128 + 255) / 256, 256, 0, stream>>>(c2w, wdh, wdl, w1h, w1l);
    k_knn1<<<B * 32, 256, 0, stream>>>(pos, idx1);
    k_ec1_l0<<<E / 256, 256, 0, stream>>>(pos, idx1, c1w0, c1b0, z0h, z0l, part);
    k_redstat<<<128, 256, 0, stream>>>(part, stats + ST0, E / 256);
    k_wfold<<<64, 64, 0, stream>>>(stats + ST0, c1g0, c1e0, c1w1, c1b1,
                                   wf1h, wf1l, bias2a, 1.f / E);
    k_lin64m<<<E / 128, 128, 0, stream>>>(z0h, z0l, wf1h, wf1l, bias2a,
                                          z1h, z1l, part);
    k_redstat<<<128, 256, 0, stream>>>(part, stats + ST1, E / 128);
    k_wfold<<<64, 64, 0, stream>>>(stats + ST1, c1g1, c1e1, c1w2, c1b2,
                                   wf2h, wf2l, bias2b, 1.f / E);
    k_lin64m<<<E / 128, 128, 0, stream>>>(z1h, z1l, wf2h, wf2l, bias2b,
                                          z2h, z2l, part);
    k_redstat<<<128, 256, 0, stream>>>(part, stats + ST2, E / 128);
    k_ec1_fin<<<BP * 64 / 256, 256, 0, stream>>>(z2h, z2l, stats + ST2, c1g2, c1e2,
                                                 x1h, x1l, sq2);
    k_knn2<<<B * 32 * QC2, 128, 0, stream>>>(x1h, x1l, sq2, cand_d, cand_i);
    k_knn2m<<<BP / 256, 256, 0, stream>>>(cand_d, cand_i, idx2);
    k_ec2m<<<E / 128, 256, 0, stream>>>(x1h, x1l, idx2, wdh, wdl, w1h, w1l,
                                        c2b, zA, stats + ST3);
    k_ec2_fin<<<BP * 128 / 256, 256, 0, stream>>>(zA, stats + ST3, c2g, c2e,
                                                  x2h, x2l);
    k_l1m<<<256 * 8, 256, 0, stream>>>(x1h, x1l, x2h, x2l, wthL, wtlL, l1b,
                                       stats + ST4, pmax, pmin);
    k_pool<<<64, 256, 0, stream>>>(stats + ST4, l1g, l1e, pmax, pmin, pbuf);
    k_m1<<<32, 256, 0, stream>>>(pbuf, m1w, m1b, t1, stats + ST5);
    k_m2<<<16, 256, 0, stream>>>(t1, stats + ST5, m1g, m1e, m2w, m2b, t2, stats + ST6);
    k_m3<<<1, 256, 0, stream>>>(t2, stats + ST6, m2g, m2e, m3w, m3b, out);
}

// Round 9
// 555.281 us; speedup vs baseline: 1.0486x; 1.0303x over previous
//
#include <hip/hip_runtime.h>
#include <cmath>

constexpr int B = 16, P = 2048, KNN = 5;
constexpr int BP = B * P;           // 32768
constexpr int E = BP * KNN;         // 163840
constexpr float EPS = 1e-5f;
constexpr int QC2 = 4;              // q-chunks for knn2 (8 doubled p-frag refetch + cand traffic)
constexpr int QC2_SHIFT = 2;
static_assert(QC2 == (1 << QC2_SHIFT), "QC2 pow2");

// stats layout (floats): per stage [sum[C] | sumsq[C]]
constexpr int ST0 = 0;        // 64ch -> 128
constexpr int ST1 = 128;      // 64ch
constexpr int ST2 = 256;      // 64ch
constexpr int ST3 = 384;      // 128ch -> 256
constexpr int ST4 = 640;      // 1024ch -> 2048
constexpr int ST5 = 2688;     // 512ch -> 1024
constexpr int ST6 = 3712;     // 256ch -> 512
constexpr int ST_TOTAL = 4224;

typedef __attribute__((ext_vector_type(8))) short bf16x8;
typedef __attribute__((ext_vector_type(4))) float f32x4;

__device__ inline unsigned short f2bf(float x) {
    unsigned u = __float_as_uint(x);
    unsigned r = (u + 0x7FFFu + ((u >> 16) & 1u)) >> 16;
    return (unsigned short)r;
}
__device__ inline float bf2f(unsigned short h) {
    return __uint_as_float(((unsigned)h) << 16);
}
// split x into hi (bf16) and lo (bf16 of residual): x ~= hi + lo, err ~2^-18 rel
__device__ inline void split2bf(float x, unsigned short& h, unsigned short& l) {
    unsigned short hh = f2bf(x);
    h = hh;
    l = f2bf(x - bf2f(hh));
}

// branch-free sorted-5 insertion (ascending); constant indices -> stays in VGPRs.
__device__ inline void ins5(float d, int qi, float bd[KNN], int bi[KNN]) {
    bool c0 = d < bd[0], c1 = d < bd[1], c2 = d < bd[2], c3 = d < bd[3], c4 = d < bd[4];
    bd[4] = c3 ? bd[3] : (c4 ? d : bd[4]);  bi[4] = c3 ? bi[3] : (c4 ? qi : bi[4]);
    bd[3] = c2 ? bd[2] : (c3 ? d : bd[3]);  bi[3] = c2 ? bi[2] : (c3 ? qi : bi[3]);
    bd[2] = c1 ? bd[1] : (c2 ? d : bd[2]);  bi[2] = c1 ? bi[1] : (c2 ? qi : bi[2]);
    bd[1] = c0 ? bd[0] : (c1 ? d : bd[1]);  bi[1] = c0 ? bi[0] : (c1 ? qi : bi[1]);
    bd[0] = c0 ? d : bd[0];                 bi[0] = c0 ? qi : bi[0];
}
// insertion with lexicographic (d, qi) tie-break: keep lower q on exact fp tie
__device__ inline void ins5t(float d, int qi, float bd[KNN], int bi[KNN]) {
    bool c0 = (d < bd[0]) || (d == bd[0] && qi < bi[0]);
    bool c1 = (d < bd[1]) || (d == bd[1] && qi < bi[1]);
    bool c2 = (d < bd[2]) || (d == bd[2] && qi < bi[2]);
    bool c3 = (d < bd[3]) || (d == bd[3] && qi < bi[3]);
    bool c4 = (d < bd[4]) || (d == bd[4] && qi < bi[4]);
    bd[4] = c3 ? bd[3] : (c4 ? d : bd[4]);  bi[4] = c3 ? bi[3] : (c4 ? qi : bi[4]);
    bd[3] = c2 ? bd[2] : (c3 ? d : bd[3]);  bi[3] = c2 ? bi[2] : (c3 ? qi : bi[3]);
    bd[2] = c1 ? bd[1] : (c2 ? d : bd[2]);  bi[2] = c1 ? bi[1] : (c2 ? qi : bi[2]);
    bd[1] = c0 ? bd[0] : (c1 ? d : bd[1]);  bi[1] = c0 ? bi[0] : (c1 ? qi : bi[1]);
    bd[0] = c0 ? d : bd[0];                 bi[0] = c0 ? qi : bi[0];
}
// butterfly-merge helper: pull partner's sorted-5 and insert with tie-break
__device__ inline void merge_xor(int w, float bd[KNN], int bi[KNN]) {
    float od[KNN]; int oi[KNN];
#pragma unroll
    for (int k = 0; k < KNN; ++k) {
        od[k] = __shfl_xor(bd[k], w, 64);
        oi[k] = __shfl_xor(bi[k], w, 64);
    }
#pragma unroll
    for (int k = 0; k < KNN; ++k) ins5t(od[k], oi[k], bd, bi);
}

// ---------------------------------------------------------------- init
__global__ void k_init(float* __restrict__ stats, float* __restrict__ pmax,
                       float* __restrict__ pmin) {
    int i = blockIdx.x * 256 + threadIdx.x;   // grid covers 16384
    if (i < ST_TOTAL) stats[i] = 0.f;
    if (i < B * 1024) { pmax[i] = 0.f; pmin[i] = INFINITY; }
}

// ---------------------------------------------------------------- deterministic partial reducer
__global__ __launch_bounds__(256) void k_redstat(const float* __restrict__ part,
        float* __restrict__ stats, int nblk) {
    __shared__ float r[256];
    int slot = blockIdx.x;
    float s = 0.f;
    for (int i = threadIdx.x; i < nblk; i += 256)
        s += part[(size_t)i * 128 + slot];
    r[threadIdx.x] = s; __syncthreads();
    for (int o = 128; o; o >>= 1) {
        if (threadIdx.x < o) r[threadIdx.x] += r[threadIdx.x + o];
        __syncthreads();
    }
    if (threadIdx.x == 0) stats[slot] = r[0];
}

// ---------------------------------------------------------------- weight pre-split: w[K][N] fp32 -> wt{h,l}[N][K] bf16
__global__ void k_wsplit(const float* __restrict__ w, unsigned short* __restrict__ th,
                         unsigned short* __restrict__ tl, int K, int N) {
    int i = blockIdx.x * 256 + threadIdx.x;
    if (i >= K * N) return;
    int k = i / N, n = i - k * N;          // read coalesced over n
    float f = w[i];
    unsigned short h = f2bf(f);
    th[(size_t)n * K + k] = h;
    tl[(size_t)n * K + k] = f2bf(f - bf2f(h));
}

// ---------------------------------------------------------------- BN-fold: wf[n][k] = scl[k]*w[k][n]; bias2 = bias + shf.w
__global__ __launch_bounds__(64) void k_wfold(const float* __restrict__ stats,
        const float* __restrict__ g, const float* __restrict__ be,
        const float* __restrict__ w, const float* __restrict__ bias,
        unsigned short* __restrict__ wfh, unsigned short* __restrict__ wfl,
        float* __restrict__ bias2, float invN) {
    __shared__ float red[64];
    int n = blockIdx.x, k = threadIdx.x;
    float mu = stats[k] * invN;
    float var = stats[64 + k] * invN - mu * mu;
    float sc = g[k] * rsqrtf(var + EPS);
    float sh = be[k] - mu * sc;
    float wv = w[k * 64 + n];
    float wf = sc * wv;
    unsigned short h, l;
    split2bf(wf, h, l);
    wfh[n * 64 + k] = h; wfl[n * 64 + k] = l;
    red[k] = sh * wv; __syncthreads();
    for (int o = 32; o; o >>= 1) {
        if (k < o) red[k] += red[k + o];
        __syncthreads();
    }
    if (k == 0) bias2[n] = bias[n] + red[0];
}

// ---------------------------------------------------------------- ec2 weight prep: W0-W1 and W1, transposed bf16 hi/lo
__global__ void k_wprep2(const float* __restrict__ w,   // c2w [128][128]
        unsigned short* __restrict__ wdh, unsigned short* __restrict__ wdl,
        unsigned short* __restrict__ w1h, unsigned short* __restrict__ w1l) {
    int i = blockIdx.x * 256 + threadIdx.x;  // 64*128
    if (i >= 64 * 128) return;
    int k = i >> 7, n = i & 127;
    float w0 = w[k * 128 + n];
    float w1 = w[(64 + k) * 128 + n];
    float wd = w0 - w1;
    unsigned short h, l;
    split2bf(wd, h, l); wdh[n * 64 + k] = h; wdl[n * 64 + k] = l;
    split2bf(w1, h, l); w1h[n * 64 + k] = h; w1l[n * 64 + k] = l;
}

// ---------------------------------------------------------------- kNN on pos (D=3)
__global__ __launch_bounds__(256) void k_knn1(const float* __restrict__ pos,
                                              int* __restrict__ idx1) {
    __shared__ float4 qt[2048];   // all q staged once (32 KB)
    int b = blockIdx.x >> 5;
    int p0 = (blockIdx.x & 31) << 6;
    const float* posb = pos + (size_t)b * P * 3;
#pragma unroll
    for (int t = 0; t < 8; ++t) {
        int q = (t << 8) + threadIdx.x;
        float qx = posb[q * 3 + 0], qy = posb[q * 3 + 1], qz = posb[q * 3 + 2];
        qt[q] = make_float4(qx, qy, qz, qx * qx + qy * qy + qz * qz);
    }
    __syncthreads();
    int pl = threadIdx.x >> 2, sub = threadIdx.x & 3;
    int p = p0 + pl;
    float4 me = qt[p];
    float x = me.x, y = me.y, z = me.z, sqp = me.w;
    float bd[KNN]; int bi[KNN];
#pragma unroll
    for (int i = 0; i < KNN; ++i) { bd[i] = INFINITY; bi[i] = 0; }
    for (int j0 = 0; j0 < 512; j0 += 8) {
        float4 v[8];
#pragma unroll
        for (int u = 0; u < 8; ++u) v[u] = qt[((j0 + u) << 2) | sub];
#pragma unroll
        for (int u = 0; u < 8; ++u) {
            float dot = x * v[u].x + y * v[u].y + z * v[u].z;
            float d2 = sqp + v[u].w - 2.f * dot;
            if (d2 < bd[KNN - 1]) ins5(d2, ((j0 + u) << 2) | sub, bd, bi);
        }
    }
    // butterfly merge across the 4 subs; snapshot-then-insert
#pragma unroll
    for (int w = 1; w <= 2; w <<= 1) {
        float od[KNN]; int oi[KNN];
#pragma unroll
        for (int i = 0; i < KNN; ++i) {
            od[i] = __shfl_xor(bd[i], w, 64);
            oi[i] = __shfl_xor(bi[i], w, 64);
        }
#pragma unroll
        for (int i = 0; i < KNN; ++i) ins5t(od[i], oi[i], bd, bi);
    }
    if (sub == 0) {
        size_t o = ((size_t)b * P + p) * KNN;
#pragma unroll
        for (int i = 0; i < KNN; ++i) idx1[o + i] = bi[i];
    }
}

// ---------------------------------------------------------------- edgeconv1 layer0: e[6] @ w[6,64]; bf16 hi/lo out + partials
__global__ __launch_bounds__(256) void k_ec1_l0(const float* __restrict__ pos,
        const int* __restrict__ idx1, const float* __restrict__ w,
        const float* __restrict__ bias, unsigned short* __restrict__ zh,
        unsigned short* __restrict__ zl, float* __restrict__ part) {
    __shared__ float elds[256][6];
    __shared__ float red[256];
    int tid = threadIdx.x;
    int base = blockIdx.x * 256;
    {
        int e = base + tid;
        int bp = e / KNN;
        int bb = bp >> 11;
        int q = idx1[e];
        const float* pi = pos + (size_t)bp * 3;
        const float* pj = pos + ((size_t)(bb << 11) + q) * 3;
        float x0 = pi[0], x1v = pi[1], x2v = pi[2];
        elds[tid][0] = x0; elds[tid][1] = x1v; elds[tid][2] = x2v;
        elds[tid][3] = pj[0] - x0; elds[tid][4] = pj[1] - x1v; elds[tid][5] = pj[2] - x2v;
    }
    int c = tid & 63, lane = tid >> 6;
    float wr[6];
#pragma unroll
    for (int d = 0; d < 6; ++d) wr[d] = w[d * 64 + c];
    float bc = bias[c];
    __syncthreads();
    float s1 = 0.f, s2 = 0.f;
    for (int i = 0; i < 64; ++i) {
        int e = lane + (i << 2);
        float acc = bc;
#pragma unroll
        for (int d = 0; d < 6; ++d) acc = fmaf(elds[e][d], wr[d], acc);
        acc = fmaxf(acc, 0.f);
        unsigned short h, l;
        split2bf(acc, h, l);
        zh[(size_t)(base + e) * 64 + c] = h;
        zl[(size_t)(base + e) * 64 + c] = l;
        s1 += acc; s2 = fmaf(acc, acc, s2);
    }
    red[tid] = s1; __syncthreads();
    if (tid < 64) part[(size_t)blockIdx.x * 128 + tid] =
        red[tid] + red[tid + 64] + red[tid + 128] + red[tid + 192];
    __syncthreads();
    red[tid] = s2; __syncthreads();
    if (tid < 64) part[(size_t)blockIdx.x * 128 + 64 + tid] =
        red[tid] + red[tid + 64] + red[tid + 128] + red[tid + 192];
}

// ---------------------------------------------------------------- 64->64 layer (BN folded into weights; direct-frag MFMA)
__global__ __launch_bounds__(128) void k_lin64m(
        const unsigned short* __restrict__ zinh, const unsigned short* __restrict__ zinl,
        const unsigned short* __restrict__ wfh, const unsigned short* __restrict__ wfl,
        const float* __restrict__ bias2, unsigned short* __restrict__ zouth,
        unsigned short* __restrict__ zoutl, float* __restrict__ part) {
    __shared__ float red[2 * 64 * 2];
    int tid = threadIdx.x;
    int wv = tid >> 6, lane = tid & 63;
    int l15 = lane & 15, quad = lane >> 4;
    int row0 = blockIdx.x * 128 + wv * 64;
    f32x4 acc[4][4];
#pragma unroll
    for (int i = 0; i < 4; ++i)
#pragma unroll
        for (int j = 0; j < 4; ++j) acc[i][j] = (f32x4)0.f;

#pragma unroll
    for (int kc = 0; kc < 2; ++kc) {
        bf16x8 afh[4], afl[4], bfh[4], bfl[4];
#pragma unroll
        for (int i = 0; i < 4; ++i) {
            size_t o = (size_t)(row0 + i * 16 + l15) * 64 + kc * 32 + quad * 8;
            afh[i] = *(const bf16x8*)&zinh[o];
            afl[i] = *(const bf16x8*)&zinl[o];
        }
#pragma unroll
        for (int j = 0; j < 4; ++j) {
            size_t wo = (size_t)(j * 16 + l15) * 64 + kc * 32 + quad * 8;
            bfh[j] = *(const bf16x8*)&wfh[wo];
            bfl[j] = *(const bf16x8*)&wfl[wo];
        }
#pragma unroll
        for (int i = 0; i < 4; ++i)
#pragma unroll
            for (int j = 0; j < 4; ++j) {
                acc[i][j] = __builtin_amdgcn_mfma_f32_16x16x32_bf16(afh[i], bfh[j], acc[i][j], 0, 0, 0);
                acc[i][j] = __builtin_amdgcn_mfma_f32_16x16x32_bf16(afh[i], bfl[j], acc[i][j], 0, 0, 0);
                acc[i][j] = __builtin_amdgcn_mfma_f32_16x16x32_bf16(afl[i], bfh[j], acc[i][j], 0, 0, 0);
            }
    }
    // epilogue: bias + ReLU, bf16 split store, per-col stats
#pragma unroll
    for (int j = 0; j < 4; ++j) {
        int colL = j * 16 + l15;
        float bl = bias2[colL];
        float s1 = 0.f, s2 = 0.f;
#pragma unroll
        for (int i = 0; i < 4; ++i) {
            int row = row0 + i * 16 + quad * 4;
#pragma unroll
            for (int r = 0; r < 4; ++r) {
                float v = fmaxf(acc[i][j][r] + bl, 0.f);
                unsigned short h, l;
                split2bf(v, h, l);
                zouth[(size_t)(row + r) * 64 + colL] = h;
                zoutl[(size_t)(row + r) * 64 + colL] = l;
                s1 += v; s2 = fmaf(v, v, s2);
            }
        }
        s1 += __shfl_xor(s1, 16, 64); s1 += __shfl_xor(s1, 32, 64);
        s2 += __shfl_xor(s2, 16, 64); s2 += __shfl_xor(s2, 32, 64);
        if (quad == 0) {
            red[(wv * 64 + colL) * 2 + 0] = s1;
            red[(wv * 64 + colL) * 2 + 1] = s2;
        }
    }
    __syncthreads();
    if (tid < 64) {
        part[(size_t)blockIdx.x * 128 + tid] =
            red[tid * 2] + red[(64 + tid) * 2];
        part[(size_t)blockIdx.x * 128 + 64 + tid] =
            red[tid * 2 + 1] + red[(64 + tid) * 2 + 1];
    }
}

// ---------------------------------------------------------------- ec1 finalize: BN + max over k -> x1 bf16 hi/lo (fused xsplit), sq norms
// NOTE: x1h/x1l MUST NOT alias z2h/z2l (R5 bug: in-place overwrite raced
// with other blocks' reads of z2 rows). x1 pair has a dedicated allocation.
__global__ __launch_bounds__(256) void k_ec1_fin(const unsigned short* __restrict__ z2h,
        const unsigned short* __restrict__ z2l,
        const float* __restrict__ statsIn, const float* __restrict__ g,
        const float* __restrict__ be, unsigned short* __restrict__ x1h,
        unsigned short* __restrict__ x1l, float* __restrict__ sq2) {
    int tid = threadIdx.x;
    int o = blockIdx.x * 256 + tid;
    int c = o & 63; int bp = o >> 6;
    float mu = statsIn[c] * (1.f / E);
    float var = statsIn[64 + c] * (1.f / E) - mu * mu;
    float sc = g[c] * rsqrtf(var + EPS);
    float sh = be[c] - mu * sc;
    float m = -INFINITY;
#pragma unroll
    for (int j = 0; j < KNN; ++j) {
        size_t zo = ((size_t)bp * KNN + j) * 64 + c;
        float v = bf2f(z2h[zo]) + bf2f(z2l[zo]);
        m = fmaxf(m, fmaf(v, sc, sh));
    }
    unsigned short h, l;
    split2bf(m, h, l);
    x1h[o] = h; x1l[o] = l;
    float ss = m * m;
#pragma unroll
    for (int off = 32; off; off >>= 1) ss += __shfl_down(ss, off, 64);
    if (c == 0) sq2[bp] = ss;
}

// ---------------------------------------------------------------- kNN2 partial
// R19: swapped-operand Gram -> C[q][p] with p=lane&15: lane owns full p-rows,
// top-5 scan on MFMA accumulator registers; no LDS key tile.
// R20: spill disaster. R21: 2 sequential p-passes -> doubled loads, 175us.
// R22: q-frags shared across both p-tiles -> 91us. R24: QC2 8 regressed
// (p-frag refetch + cand traffic doubled). R25 post-mortem: moving sq/q
// loads per-j put them on the critical path (103us, VALU 58%, 4 waves/SIMD
// grid cap can't hide L2 latency). R26: manual 2-deep software pipeline —
// issue j+1's q-frags+sq4 before computing j's MFMAs+scan. Named A/B reg
// sets (rule #20: no runtime indexing). MFMA order per acc unchanged ->
// bitwise-identical idx2.
__global__ __launch_bounds__(128) void k_knn2(const unsigned short* __restrict__ x1h,
        const unsigned short* __restrict__ x1l, const float* __restrict__ sq2,
        float* __restrict__ cd, int* __restrict__ ci) {
    int tid = threadIdx.x;
    int wv = tid >> 6, lane = tid & 63;
    int l15 = lane & 15, quad = lane >> 4;
    int qc = blockIdx.x & (QC2 - 1);
    int pt = blockIdx.x >> QC2_SHIFT;         // 16*32 ptiles of 64 rows
    int b = pt >> 5;
    int pw = ((pt & 31) << 6) + wv * 32;      // wave p base within batch
    const size_t xbase = (size_t)b * P * 64;
    int qlo = qc * (P / QC2);                 // 512-q chunk

    // B operand: p-row fragments for both 16-row tiles (held whole kernel)
    bf16x8 ph[2][2], pl_[2][2];               // [i][kc]
#pragma unroll
    for (int i = 0; i < 2; ++i)
#pragma unroll
        for (int kc = 0; kc < 2; ++kc) {
            size_t o = xbase + (size_t)(pw + i * 16 + l15) * 64 + kc * 32 + quad * 8;
            ph[i][kc] = *(const bf16x8*)&x1h[o];
            pl_[i][kc] = *(const bf16x8*)&x1l[o];
        }
    // per-lane top-5 for p-rows l15 (0) and 16+l15 (1)
    float bd0[KNN], bd1[KNN]; int bi0[KNN], bi1[KNN];
#pragma unroll
    for (int i = 0; i < KNN; ++i) {
        bd0[i] = INFINITY; bi0[i] = 0;
        bd1[i] = INFINITY; bi1[i] = 0;
    }

    auto loadQ = [&](int q0, int j, bf16x8* qh, bf16x8* ql, f32x4& sq) {
#pragma unroll
        for (int kc = 0; kc < 2; ++kc) {
            size_t o = xbase + (size_t)(q0 + j * 16 + l15) * 64 + kc * 32 + quad * 8;
            qh[kc] = *(const bf16x8*)&x1h[o];
            ql[kc] = *(const bf16x8*)&x1l[o];
        }
        sq = *(const f32x4*)&sq2[b * P + q0 + j * 16 + (quad << 2)];
    };
    auto procQ = [&](int q0, int j, const bf16x8* qh, const bf16x8* ql,
                     f32x4 sq) {
        f32x4 a0 = (f32x4)0.f, a1 = (f32x4)0.f;
#pragma unroll
        for (int kc = 0; kc < 2; ++kc) {
            a0 = __builtin_amdgcn_mfma_f32_16x16x32_bf16(qh[kc], ph[0][kc], a0, 0, 0, 0);
            a0 = __builtin_amdgcn_mfma_f32_16x16x32_bf16(qh[kc], pl_[0][kc], a0, 0, 0, 0);
            a0 = __builtin_amdgcn_mfma_f32_16x16x32_bf16(ql[kc], ph[0][kc], a0, 0, 0, 0);
            a1 = __builtin_amdgcn_mfma_f32_16x16x32_bf16(qh[kc], ph[1][kc], a1, 0, 0, 0);
            a1 = __builtin_amdgcn_mfma_f32_16x16x32_bf16(qh[kc], pl_[1][kc], a1, 0, 0, 0);
            a1 = __builtin_amdgcn_mfma_f32_16x16x32_bf16(ql[kc], ph[1][kc], a1, 0, 0, 0);
        }
        int qb = q0 + j * 16 + (quad << 2);
#pragma unroll
        for (int r = 0; r < 4; ++r) {
            float d0 = fmaf(a0[r], -2.f, sq[r]);
            if (d0 < bd0[KNN - 1]) ins5(d0, qb + r, bd0, bi0);
            float d1 = fmaf(a1[r], -2.f, sq[r]);
            if (d1 < bd1[KNN - 1]) ins5(d1, qb + r, bd1, bi1);
        }
    };

#pragma unroll 1
    for (int t = 0; t < (P / QC2) / 128; ++t) {
        int q0 = qlo + (t << 7);
        bf16x8 qhA[2], qlA[2], qhB[2], qlB[2];
        f32x4 sqA, sqB;
        loadQ(q0, 0, qhA, qlA, sqA);
#pragma unroll 1
        for (int jj = 0; jj < 8; jj += 2) {
            loadQ(q0, jj + 1, qhB, qlB, sqB);   // prefetch odd
            procQ(q0, jj, qhA, qlA, sqA);
            if (jj < 6) loadQ(q0, jj + 2, qhA, qlA, sqA);   // prefetch next even
            procQ(q0, jj + 1, qhB, qlB, sqB);
        }
    }
    // merge across the 4 quads sharing l15 (disjoint q mod 16 -> clean ties)
    merge_xor(16, bd0, bi0); merge_xor(16, bd1, bi1);
    merge_xor(32, bd0, bi0); merge_xor(32, bd1, bi1);
    if (quad == 0) {
        size_t o0 = (((size_t)b * P + pw + l15) * QC2 + qc) * KNN;
        size_t o1 = (((size_t)b * P + pw + 16 + l15) * QC2 + qc) * KNN;
#pragma unroll
        for (int k = 0; k < KNN; ++k) {
            cd[o0 + k] = bd0[k]; ci[o0 + k] = bi0[k];
            cd[o1 + k] = bd1[k]; ci[o1 + k] = bi1[k];
        }
    }
}

// ---------------------------------------------------------------- kNN2 merge (QC2 sorted chunks of 5 -> 5)
__global__ __launch_bounds__(256) void k_knn2m(const float* __restrict__ cd,
        const int* __restrict__ ci, int* __restrict__ idx2) {
    int bp = blockIdx.x * 256 + threadIdx.x;
    float bd[KNN]; int bi[KNN];
#pragma unroll
    for (int i = 0; i < KNN; ++i) { bd[i] = INFINITY; bi[i] = 0; }
    size_t o = (size_t)bp * QC2 * KNN;
    for (int t = 0; t < QC2 * KNN; ++t) {
        float d2 = cd[o + t]; int qi = ci[o + t];
        if (d2 < bd[KNN - 1]) ins5(d2, qi, bd, bi);
    }
#pragma unroll
    for (int i = 0; i < KNN; ++i) idx2[bp * KNN + i] = bi[i];
}

// ---------------------------------------------------------------- edgeconv2 (direct-fragment split-bf16 MFMA)
__global__ __launch_bounds__(256) void k_ec2m(
        const unsigned short* __restrict__ x1h, const unsigned short* __restrict__ x1l,
        const int* __restrict__ idx2,
        const unsigned short* __restrict__ wdh, const unsigned short* __restrict__ wdl,
        const unsigned short* __restrict__ w1h, const unsigned short* __restrict__ w1l,
        const float* __restrict__ bias, float* __restrict__ zout,
        float* __restrict__ stats) {
    __shared__ float red[2 * 128 * 2];
    int tid = threadIdx.x;
    int base = blockIdx.x * 128;            // first edge
    int bb = base / (P * KNN);              // batch (blocks never straddle: 10240%128==0)
    int wv = tid >> 6, lane = tid & 63;
    int wm = wv >> 1, wn = wv & 1;
    int l15 = lane & 15, quad = lane >> 4;
    // per-lane A rows for this wave's 4 row-tiles
    int rI[4], rJ[4];
#pragma unroll
    for (int i = 0; i < 4; ++i) {
        int e = base + wm * 64 + i * 16 + l15;
        rI[i] = e / KNN;
        rJ[i] = (bb << 11) + idx2[e];
    }
    f32x4 acc[4][4];
#pragma unroll
    for (int i = 0; i < 4; ++i)
#pragma unroll
        for (int j = 0; j < 4; ++j) acc[i][j] = (f32x4)0.f;

#pragma unroll
    for (int s = 0; s < 2; ++s) {
        const unsigned short* bh_ = s ? w1h : wdh;
        const unsigned short* bl_ = s ? w1l : wdl;
#pragma unroll
        for (int kc = 0; kc < 2; ++kc) {
            bf16x8 afh[4], afl[4], bfh[4], bfl[4];
#pragma unroll
            for (int i = 0; i < 4; ++i) {
                int row = s ? rJ[i] : rI[i];
                size_t o = (size_t)row * 64 + kc * 32 + quad * 8;
                afh[i] = *(const bf16x8*)&x1h[o];
                afl[i] = *(const bf16x8*)&x1l[o];
            }
#pragma unroll
            for (int j = 0; j < 4; ++j) {
                size_t wo = (size_t)(wn * 64 + j * 16 + l15) * 64 + kc * 32 + quad * 8;
                bfh[j] = *(const bf16x8*)&bh_[wo];
                bfl[j] = *(const bf16x8*)&bl_[wo];
            }
#pragma unroll
            for (int i = 0; i < 4; ++i)
#pragma unroll
                for (int j = 0; j < 4; ++j) {
                    acc[i][j] = __builtin_amdgcn_mfma_f32_16x16x32_bf16(afh[i], bfh[j], acc[i][j], 0, 0, 0);
                    acc[i][j] = __builtin_amdgcn_mfma_f32_16x16x32_bf16(afh[i], bfl[j], acc[i][j], 0, 0, 0);
                    acc[i][j] = __builtin_amdgcn_mfma_f32_16x16x32_bf16(afl[i], bfh[j], acc[i][j], 0, 0, 0);
                }
        }
    }
    // epilogue: bias + ReLU, write z, per-col stats
#pragma unroll
    for (int j = 0; j < 4; ++j) {
        int colL = wn * 64 + j * 16 + l15;
        float bl = bias[colL];
        float s1 = 0.f, s2 = 0.f;
#pragma unroll
        for (int i = 0; i < 4; ++i) {
            int row = wm * 64 + i * 16 + quad * 4;
#pragma unroll
            for (int r = 0; r < 4; ++r) {
                float v = fmaxf(acc[i][j][r] + bl, 0.f);
                zout[(size_t)(base + row + r) * 128 + colL] = v;
                s1 += v; s2 = fmaf(v, v, s2);
            }
        }
        s1 += __shfl_xor(s1, 16, 64); s1 += __shfl_xor(s1, 32, 64);
        s2 += __shfl_xor(s2, 16, 64); s2 += __shfl_xor(s2, 32, 64);
        if (quad == 0) {
            red[(wm * 128 + colL) * 2 + 0] = s1;
            red[(wm * 128 + colL) * 2 + 1] = s2;
        }
    }
    __syncthreads();
    if (tid < 128) {
        atomicAdd(&stats[tid], red[tid * 2] + red[(128 + tid) * 2]);
        atomicAdd(&stats[128 + tid], red[tid * 2 + 1] + red[(128 + tid) * 2 + 1]);
    }
}

// ---------------------------------------------------------------- ec2 finalize: BN + max over k -> x2 bf16 hi/lo (fused xsplit)
// safe: z3 lives in zA, x2 pair lives in zB — disjoint buffers.
__global__ __launch_bounds__(256) void k_ec2_fin(const float* __restrict__ z3,
        const float* __restrict__ stats, const float* __restrict__ g,
        const float* __restrict__ be, unsigned short* __restrict__ x2h,
        unsigned short* __restrict__ x2l) {
    int o = blockIdx.x * 256 + threadIdx.x;
    int c = o & 127; int bp = o >> 7;
    float mu = stats[c] * (1.f / E);
    float var = stats[128 + c] * (1.f / E) - mu * mu;
    float sc = g[c] * rsqrtf(var + EPS);
    float sh = be[c] - mu * sc;
    float m = -INFINITY;
#pragma unroll
    for (int j = 0; j < KNN; ++j)
        m = fmaxf(m, fmaf(z3[((size_t)bp * KNN + j) * 128 + c], sc, sh));
    unsigned short h, l;
    split2bf(m, h, l);
    x2h[o] = h; x2l[o] = l;
}

// ---------------------------------------------------------------- l1 (LDS-staged split-bf16 MFMA, m97-style 2-phase)
// R18: coalesced global_load_lds staging + ds_read_b128 frags fixed the
// latency-bound direct-gather version (108 -> out of top-5).
__device__ __forceinline__ void gl16(unsigned short* lds, const unsigned short* g) {
    __builtin_amdgcn_global_load_lds(
        (const __attribute__((address_space(1))) unsigned int*)g,
        (__attribute__((address_space(3))) unsigned int*)lds, 16, 0, 0);
}

__global__ __launch_bounds__(256) void k_l1m(
        const unsigned short* __restrict__ x1h, const unsigned short* __restrict__ x1l,
        const unsigned short* __restrict__ x2h, const unsigned short* __restrict__ x2l,
        const unsigned short* __restrict__ wth, const unsigned short* __restrict__ wtl,
        const float* __restrict__ bias, float* __restrict__ stats,
        float* __restrict__ pmax, float* __restrict__ pmin) {
    __shared__ unsigned short Ah[128 * 32], Al[128 * 32];   // [row][k] bf16, 8 KB each
    __shared__ unsigned short Bh[128 * 32], Bl[128 * 32];   // [col][k] bf16
    __shared__ float red[2 * 128 * 4];
    int tid = threadIdx.x;
    int brow = blockIdx.x & 255;
    int bcol = blockIdx.x >> 8;
    int row0 = brow << 7, col0 = bcol << 7;
    int wv = tid >> 6, lane = tid & 63;
    int wm = wv >> 1, wn = wv & 1;
    int l15 = lane & 15, quad = lane >> 4;
    int rloc = wv * 16 + (lane >> 2);      // staging row for call 0 (+64 for call 1)
    int ch8 = (lane & 3) * 8;              // staging k-chunk (ushorts, 16 B)
    f32x4 acc[4][4];
#pragma unroll
    for (int i = 0; i < 4; ++i)
#pragma unroll
        for (int j = 0; j < 4; ++j) acc[i][j] = (f32x4)0.f;

#pragma unroll
    for (int t = 0; t < 6; ++t) {
        int k0 = t * 32;
        const unsigned short* ah = (k0 < 64) ? x1h : x2h;
        const unsigned short* al = (k0 < 64) ? x1l : x2l;
        int astr = (k0 < 64) ? 64 : 128;
        int aoff = (k0 < 64) ? k0 : (k0 - 64);
        // stage: 32 KB/step, 8 x 16B global_load_lds per thread, 1 KB/wave/call
#pragma unroll
        for (int c = 0; c < 2; ++c) {
            int rl = c * 64 + rloc;
            size_t ao = (size_t)(row0 + rl) * astr + aoff + ch8;
            size_t bo = (size_t)(col0 + rl) * 192 + k0 + ch8;
            int lb = (c * 64 + wv * 16) * 32;   // wave-uniform LDS base (ushorts)
            gl16(&Ah[lb], &ah[ao]);
            gl16(&Al[lb], &al[ao]);
            gl16(&Bh[lb], &wth[bo]);
            gl16(&Bl[lb], &wtl[bo]);
        }
        __syncthreads();    // compiler drains vmcnt before s_barrier
        bf16x8 afh[4], afl[4], bfh[4], bfl[4];
#pragma unroll
        for (int i = 0; i < 4; ++i) {
            int o = (wm * 64 + i * 16 + l15) * 32 + quad * 8;
            afh[i] = *(const bf16x8*)&Ah[o];
            afl[i] = *(const bf16x8*)&Al[o];
        }
#pragma unroll
        for (int j = 0; j < 4; ++j) {
            int o = (wn * 64 + j * 16 + l15) * 32 + quad * 8;
            bfh[j] = *(const bf16x8*)&Bh[o];
            bfl[j] = *(const bf16x8*)&Bl[o];
        }
#pragma unroll
        for (int i = 0; i < 4; ++i)
#pragma unroll
            for (int j = 0; j < 4; ++j) {
                acc[i][j] = __builtin_amdgcn_mfma_f32_16x16x32_bf16(afh[i], bfh[j], acc[i][j], 0, 0, 0);
                acc[i][j] = __builtin_amdgcn_mfma_f32_16x16x32_bf16(afh[i], bfl[j], acc[i][j], 0, 0, 0);
                acc[i][j] = __builtin_amdgcn_mfma_f32_16x16x32_bf16(afl[i], bfh[j], acc[i][j], 0, 0, 0);
            }
        __syncthreads();    // protect LDS re-stage of step t+1
    }
    // epilogue: bias + ReLU, per-col sum/sumsq/max/min (h never materialized)
#pragma unroll
    for (int j = 0; j < 4; ++j) {
        int colL = wn * 64 + j * 16 + l15;
        float bl = bias[col0 + colL];
        float s1 = 0.f, s2 = 0.f, mx = 0.f, mn = INFINITY;
#pragma unroll
        for (int i = 0; i < 4; ++i)
#pragma unroll
            for (int r = 0; r < 4; ++r) {
                float v = fmaxf(acc[i][j][r] + bl, 0.f);
                s1 += v; s2 = fmaf(v, v, s2);
                mx = fmaxf(mx, v); mn = fminf(mn, v);
            }
        s1 += __shfl_xor(s1, 16, 64); s1 += __shfl_xor(s1, 32, 64);
        s2 += __shfl_xor(s2, 16, 64); s2 += __shfl_xor(s2, 32, 64);
        mx = fmaxf(mx, __shfl_xor(mx, 16, 64)); mx = fmaxf(mx, __shfl_xor(mx, 32, 64));
        mn = fminf(mn, __shfl_xor(mn, 16, 64)); mn = fminf(mn, __shfl_xor(mn, 32, 64));
        if (quad == 0) {
            float* rp = &red[(wm * 128 + colL) * 4];
            rp[0] = s1; rp[1] = s2; rp[2] = mx; rp[3] = mn;
        }
    }
    __syncthreads();
    if (tid < 128) {
        const float* r0 = &red[tid * 4];
        const float* r1 = &red[(128 + tid) * 4];
        int bb = row0 >> 11;
        atomicAdd(&stats[col0 + tid], r0[0] + r1[0]);
        atomicAdd(&stats[1024 + col0 + tid], r0[1] + r1[1]);
        atomicMax((unsigned int*)&pmax[bb * 1024 + col0 + tid],
                  __float_as_uint(fmaxf(r0[2], r1[2])));
        atomicMin((unsigned int*)&pmin[bb * 1024 + col0 + tid],
                  __float_as_uint(fminf(r0[3], r1[3])));
    }
}

// ---------------------------------------------------------------- pooled p = BN(max or min)
__global__ void k_pool(const float* __restrict__ stats, const float* __restrict__ g,
                       const float* __restrict__ be, const float* __restrict__ pmax,
                       const float* __restrict__ pmin, float* __restrict__ p) {
    int o = blockIdx.x * 256 + threadIdx.x;   // 16384
    int c = o & 1023;
    float mu = stats[c] * (1.f / BP);
    float var = stats[1024 + c] * (1.f / BP) - mu * mu;
    float sc = g[c] * rsqrtf(var + EPS);
    float sh = be[c] - mu * sc;
    float v = (sc >= 0.f) ? pmax[o] : pmin[o];
    p[o] = fmaf(v, sc, sh);
}

// ---------------------------------------------------------------- head
__global__ __launch_bounds__(256) void k_m1(const float* __restrict__ p,
        const float* __restrict__ w, const float* __restrict__ bias,
        float* __restrict__ t1, float* __restrict__ stats) {
    int o = blockIdx.x * 256 + threadIdx.x;   // 8192
    int c = o & 511, b = o >> 9;
    const float* pr = p + (b << 10);
    float acc = bias[c];
    for (int k = 0; k < 1024; ++k) acc = fmaf(pr[k], w[k * 512 + c], acc);
    acc = fmaxf(acc, 0.f);
    t1[o] = acc;
    atomicAdd(&stats[c], acc);
    atomicAdd(&stats[512 + c], acc * acc);
}

__global__ __launch_bounds__(256) void k_m2(const float* __restrict__ t1,
        const float* __restrict__ stats5, const float* __restrict__ g,
        const float* __restrict__ be, const float* __restrict__ w,
        const float* __restrict__ bias, float* __restrict__ t2,
        float* __restrict__ stats6) {
    __shared__ float scl[512], shf[512];
    int tid = threadIdx.x;
    for (int t = tid; t < 512; t += 256) {
        float mu = stats5[t] * (1.f / 16.f);
        float var = stats5[512 + t] * (1.f / 16.f) - mu * mu;
        float sc = g[t] * rsqrtf(var + EPS);
        scl[t] = sc; shf[t] = be[t] - mu * sc;
    }
    __syncthreads();
    int o = blockIdx.x * 256 + tid;   // 4096
    int c = o & 255, b = o >> 8;
    const float* tr = t1 + (b << 9);
    float acc = bias[c];
    for (int k = 0; k < 512; ++k) {
        float u = fmaf(tr[k], scl[k], shf[k]);
        acc = fmaf(u, w[k * 256 + c], acc);
    }
    acc = fmaxf(acc, 0.f);
    t2[o] = acc;
    atomicAdd(&stats6[c], acc);
    atomicAdd(&stats6[256 + c], acc * acc);
}

__global__ __launch_bounds__(256) void k_m3(const float* __restrict__ t2,
        const float* __restrict__ stats6, const float* __restrict__ g,
        const float* __restrict__ be, const float* __restrict__ w,
        const float* __restrict__ bias, float* __restrict__ out) {
    __shared__ float scl[256], shf[256];
    int tid = threadIdx.x;
    {
        float mu = stats6[tid] * (1.f / 16.f);
        float var = stats6[256 + tid] * (1.f / 16.f) - mu * mu;
        float sc = g[tid] * rsqrtf(var + EPS);
        scl[tid] = sc; shf[tid] = be[tid] - mu * sc;
    }
    __syncthreads();
    if (tid < 32) {
        int c = tid & 1, b = tid >> 1;
        const float* tr = t2 + (b << 8);
        float acc = bias[c];
        for (int k = 0; k < 256; ++k) {
            float u = fmaf(tr[k], scl[k], shf[k]);
            acc = fmaf(u, w[k * 2 + c], acc);
        }
        out[tid] = acc;
    }
}

// ================================================================ launch
extern "C" void kernel_launch(void* const* d_in, const int* in_sizes, int n_in,
                              void* d_out, int out_size, void* d_ws, size_t ws_size,
                              hipStream_t stream) {
    const float* pos  = (const float*)d_in[0];
    const float* c1w0 = (const float*)d_in[1];
    const float* c1b0 = (const float*)d_in[2];
    const float* c1g0 = (const float*)d_in[3];
    const float* c1e0 = (const float*)d_in[4];
    const float* c1w1 = (const float*)d_in[5];
    const float* c1b1 = (const float*)d_in[6];
    const float* c1g1 = (const float*)d_in[7];
    const float* c1e1 = (const float*)d_in[8];
    const float* c1w2 = (const float*)d_in[9];
    const float* c1b2 = (const float*)d_in[10];
    const float* c1g2 = (const float*)d_in[11];
    const float* c1e2 = (const float*)d_in[12];
    const float* c2w  = (const float*)d_in[13];
    const float* c2b  = (const float*)d_in[14];
    const float* c2g  = (const float*)d_in[15];
    const float* c2e  = (const float*)d_in[16];
    const float* l1w  = (const float*)d_in[17];
    const float* l1b  = (const float*)d_in[18];
    const float* l1g  = (const float*)d_in[19];
    const float* l1e  = (const float*)d_in[20];
    const float* m1w  = (const float*)d_in[21];
    const float* m1b  = (const float*)d_in[22];
    const float* m1g  = (const float*)d_in[23];
    const float* m1e  = (const float*)d_in[24];
    const float* m2w  = (const float*)d_in[25];
    const float* m2b  = (const float*)d_in[26];
    const float* m2g  = (const float*)d_in[27];
    const float* m2e  = (const float*)d_in[28];
    const float* m3w  = (const float*)d_in[29];
    const float* m3b  = (const float*)d_in[30];
    float* out = (float*)d_out;

    char* ws = (char*)d_ws;
    size_t off = 0;
    auto alloc = [&](size_t bytes) {
        size_t r = off; off = (off + bytes + 255) & ~(size_t)255; return r;
    };
    float* stats = (float*)(ws + alloc(ST_TOTAL * 4));
    float* pmax  = (float*)(ws + alloc(16 * 1024 * 4));
    float* pmin  = (float*)(ws + alloc(16 * 1024 * 4));
    float* pbuf  = (float*)(ws + alloc(16 * 1024 * 4));
    float* t1    = (float*)(ws + alloc(16 * 512 * 4));
    float* t2    = (float*)(ws + alloc(16 * 256 * 4));
    float* sq2   = (float*)(ws + alloc((size_t)BP * 4));
    float* part  = (float*)(ws + alloc((size_t)(E / 64) * 128 * 4));  // up to 2560 blocks x 128
    unsigned short* wthL = (unsigned short*)(ws + alloc((size_t)192 * 1024 * 2));
    unsigned short* wtlL = (unsigned short*)(ws + alloc((size_t)192 * 1024 * 2));
    unsigned short* wdh  = (unsigned short*)(ws + alloc((size_t)128 * 64 * 2));
    unsigned short* wdl  = (unsigned short*)(ws + alloc((size_t)128 * 64 * 2));
    unsigned short* w1h  = (unsigned short*)(ws + alloc((size_t)128 * 64 * 2));
    unsigned short* w1l  = (unsigned short*)(ws + alloc((size_t)128 * 64 * 2));
    unsigned short* wf1h = (unsigned short*)(ws + alloc((size_t)64 * 64 * 2));
    unsigned short* wf1l = (unsigned short*)(ws + alloc((size_t)64 * 64 * 2));
    unsigned short* wf2h = (unsigned short*)(ws + alloc((size_t)64 * 64 * 2));
    unsigned short* wf2l = (unsigned short*)(ws + alloc((size_t)64 * 64 * 2));
    float* bias2a = (float*)(ws + alloc(64 * 4));
    float* bias2b = (float*)(ws + alloc(64 * 4));
    int*   idx1  = (int*)  (ws + alloc((size_t)E * 4));
    int*   idx2  = (int*)  (ws + alloc((size_t)E * 4));
    // dedicated x1 bf16 pair (R6 fix: must NOT alias z2 — ec1_fin reads z2
    // and writes x1 in the same kernel; aliasing raced across blocks)
    unsigned short* x1h = (unsigned short*)(ws + alloc((size_t)BP * 64 * 2));
    unsigned short* x1l = (unsigned short*)(ws + alloc((size_t)BP * 64 * 2));
    float* zA    = (float*)(ws + alloc((size_t)E * 128 * 4)); // hosts z0/z1 bf16 pairs, later z3 fp32
    float* zB    = (float*)(ws + alloc((size_t)E * 64 * 4));  // hosts z2 bf16 pair, later knn2 scratch
    // zA aliases: z0h/z0l (21MB each) then z1h/z1l; all dead before z3 (ec2 out) overwrites
    unsigned short* z0h = (unsigned short*)zA;
    unsigned short* z0l = z0h + (size_t)E * 64;
    unsigned short* z1h = z0l + (size_t)E * 64;
    unsigned short* z1l = z1h + (size_t)E * 64;
    // zB aliases: z2h/z2l (dead after ec1_fin completes), then knn2 scratch:
    // cand 5.2MB + x2 pair 16.8MB = 22 < 41.9MB
    unsigned short* z2h = (unsigned short*)zB;
    unsigned short* z2l = z2h + (size_t)E * 64;
    float* cand_d = (float*)zB;
    int*   cand_i = (int*)(cand_d + (size_t)BP * QC2 * KNN);
    unsigned short* x2h = (unsigned short*)(cand_i + (size_t)BP * QC2 * KNN);
    unsigned short* x2l = x2h + (size_t)BP * 128;

    (void)in_sizes; (void)n_in; (void)out_size; (void)ws_size;

    k_init<<<64, 256, 0, stream>>>(stats, pmax, pmin);
    k_wsplit<<<(192 * 1024 + 255) / 256, 256, 0, stream>>>(l1w, wthL, wtlL, 192, 1024);
    k_wprep2<<<(64 * 128 + 255) / 256, 256, 0, stream>>>(c2w, wdh, wdl, w1h, w1l);
    k_knn1<<<B * 32, 256, 0, stream>>>(pos, idx1);
    k_ec1_l0<<<E / 256, 256, 0, stream>>>(pos, idx1, c1w0, c1b0, z0h, z0l, part);
    k_redstat<<<128, 256, 0, stream>>>(part, stats + ST0, E / 256);
    k_wfold<<<64, 64, 0, stream>>>(stats + ST0, c1g0, c1e0, c1w1, c1b1,
                                   wf1h, wf1l, bias2a, 1.f / E);
    k_lin64m<<<E / 128, 128, 0, stream>>>(z0h, z0l, wf1h, wf1l, bias2a,
                                          z1h, z1l, part);
    k_redstat<<<128, 256, 0, stream>>>(part, stats + ST1, E / 128);
    k_wfold<<<64, 64, 0, stream>>>(stats + ST1, c1g1, c1e1, c1w2, c1b2,
                                   wf2h, wf2l, bias2b, 1.f / E);
    k_lin64m<<<E / 128, 128, 0, stream>>>(z1h, z1l, wf2h, wf2l, bias2b,
                                          z2h, z2l, part);
    k_redstat<<<128, 256, 0, stream>>>(part, stats + ST2, E / 128);
    k_ec1_fin<<<BP * 64 / 256, 256, 0, stream>>>(z2h, z2l, stats + ST2, c1g2, c1e2,
                                                 x1h, x1l, sq2);
    k_knn2<<<B * 32 * QC2, 128, 0, stream>>>(x1h, x1l, sq2, cand_d, cand_i);
    k_knn2m<<<BP / 256, 256, 0, stream>>>(cand_d, cand_i, idx2);
    k_ec2m<<<E / 128, 256, 0, stream>>>(x1h, x1l, idx2, wdh, wdl, w1h, w1l,
                                        c2b, zA, stats + ST3);
    k_ec2_fin<<<BP * 128 / 256, 256, 0, stream>>>(zA, stats + ST3, c2g, c2e,
                                                  x2h, x2l);
    k_l1m<<<256 * 8, 256, 0, stream>>>(x1h, x1l, x2h, x2l, wthL, wtlL, l1b,
                                       stats + ST4, pmax, pmin);
    k_pool<<<64, 256, 0, stream>>>(stats + ST4, l1g, l1e, pmax, pmin, pbuf);
    k_m1<<<32, 256, 0, stream>>>(pbuf, m1w, m1b, t1, stats + ST5);
    k_m2<<<16, 256, 0, stream>>>(t1, stats + ST5, m1g, m1e, m2w, m2b, t2, stats + ST6);
    k_m3<<<1, 256, 0, stream>>>(t2, stats + ST6, m2g, m2e, m3w, m3b, out);
}

// Round 10
// 554.503 us; speedup vs baseline: 1.0500x; 1.0014x over previous
//
#include <hip/hip_runtime.h>
#include <cmath>

constexpr int B = 16, P = 2048, KNN = 5;
constexpr int BP = B * P;           // 32768
constexpr int E = BP * KNN;         // 163840
constexpr float EPS = 1e-5f;
constexpr int QC2 = 4;              // q-chunks for knn2 (8 doubled p-frag refetch + cand traffic)
constexpr int QC2_SHIFT = 2;
static_assert(QC2 == (1 << QC2_SHIFT), "QC2 pow2");

// stats layout (floats): per stage [sum[C] | sumsq[C]]
constexpr int ST0 = 0;        // 64ch -> 128
constexpr int ST1 = 128;      // 64ch
constexpr int ST2 = 256;      // 64ch
constexpr int ST3 = 384;      // 128ch -> 256
constexpr int ST4 = 640;      // 1024ch -> 2048
constexpr int ST5 = 2688;     // 512ch -> 1024
constexpr int ST6 = 3712;     // 256ch -> 512
constexpr int ST_TOTAL = 4224;

typedef __attribute__((ext_vector_type(8))) short bf16x8;
typedef __attribute__((ext_vector_type(4))) float f32x4;

__device__ inline unsigned short f2bf(float x) {
    unsigned u = __float_as_uint(x);
    unsigned r = (u + 0x7FFFu + ((u >> 16) & 1u)) >> 16;
    return (unsigned short)r;
}
__device__ inline float bf2f(unsigned short h) {
    return __uint_as_float(((unsigned)h) << 16);
}
// split x into hi (bf16) and lo (bf16 of residual): x ~= hi + lo, err ~2^-18 rel
__device__ inline void split2bf(float x, unsigned short& h, unsigned short& l) {
    unsigned short hh = f2bf(x);
    h = hh;
    l = f2bf(x - bf2f(hh));
}

// branch-free sorted-5 insertion (ascending); constant indices -> stays in VGPRs.
__device__ inline void ins5(float d, int qi, float bd[KNN], int bi[KNN]) {
    bool c0 = d < bd[0], c1 = d < bd[1], c2 = d < bd[2], c3 = d < bd[3], c4 = d < bd[4];
    bd[4] = c3 ? bd[3] : (c4 ? d : bd[4]);  bi[4] = c3 ? bi[3] : (c4 ? qi : bi[4]);
    bd[3] = c2 ? bd[2] : (c3 ? d : bd[3]);  bi[3] = c2 ? bi[2] : (c3 ? qi : bi[3]);
    bd[2] = c1 ? bd[1] : (c2 ? d : bd[2]);  bi[2] = c1 ? bi[1] : (c2 ? qi : bi[2]);
    bd[1] = c0 ? bd[0] : (c1 ? d : bd[1]);  bi[1] = c0 ? bi[0] : (c1 ? qi : bi[1]);
    bd[0] = c0 ? d : bd[0];                 bi[0] = c0 ? qi : bi[0];
}
// insertion with lexicographic (d, qi) tie-break: keep lower q on exact fp tie
__device__ inline void ins5t(float d, int qi, float bd[KNN], int bi[KNN]) {
    bool c0 = (d < bd[0]) || (d == bd[0] && qi < bi[0]);
    bool c1 = (d < bd[1]) || (d == bd[1] && qi < bi[1]);
    bool c2 = (d < bd[2]) || (d == bd[2] && qi < bi[2]);
    bool c3 = (d < bd[3]) || (d == bd[3] && qi < bi[3]);
    bool c4 = (d < bd[4]) || (d == bd[4] && qi < bi[4]);
    bd[4] = c3 ? bd[3] : (c4 ? d : bd[4]);  bi[4] = c3 ? bi[3] : (c4 ? qi : bi[4]);
    bd[3] = c2 ? bd[2] : (c3 ? d : bd[3]);  bi[3] = c2 ? bi[2] : (c3 ? qi : bi[3]);
    bd[2] = c1 ? bd[1] : (c2 ? d : bd[2]);  bi[2] = c1 ? bi[1] : (c2 ? qi : bi[2]);
    bd[1] = c0 ? bd[0] : (c1 ? d : bd[1]);  bi[1] = c0 ? bi[0] : (c1 ? qi : bi[1]);
    bd[0] = c0 ? d : bd[0];                 bi[0] = c0 ? qi : bi[0];
}
// butterfly-merge helper: pull partner's sorted-5 and insert with tie-break
__device__ inline void merge_xor(int w, float bd[KNN], int bi[KNN]) {
    float od[KNN]; int oi[KNN];
#pragma unroll
    for (int k = 0; k < KNN; ++k) {
        od[k] = __shfl_xor(bd[k], w, 64);
        oi[k] = __shfl_xor(bi[k], w, 64);
    }
#pragma unroll
    for (int k = 0; k < KNN; ++k) ins5t(od[k], oi[k], bd, bi);
}

// ---------------------------------------------------------------- init
__global__ void k_init(float* __restrict__ stats, float* __restrict__ pmax,
                       float* __restrict__ pmin) {
    int i = blockIdx.x * 256 + threadIdx.x;   // grid covers 16384
    if (i < ST_TOTAL) stats[i] = 0.f;
    if (i < B * 1024) { pmax[i] = 0.f; pmin[i] = INFINITY; }
}

// ---------------------------------------------------------------- deterministic partial reducer
__global__ __launch_bounds__(256) void k_redstat(const float* __restrict__ part,
        float* __restrict__ stats, int nblk) {
    __shared__ float r[256];
    int slot = blockIdx.x;
    float s = 0.f;
    for (int i = threadIdx.x; i < nblk; i += 256)
        s += part[(size_t)i * 128 + slot];
    r[threadIdx.x] = s; __syncthreads();
    for (int o = 128; o; o >>= 1) {
        if (threadIdx.x < o) r[threadIdx.x] += r[threadIdx.x + o];
        __syncthreads();
    }
    if (threadIdx.x == 0) stats[slot] = r[0];
}

// ---------------------------------------------------------------- weight pre-split: w[K][N] fp32 -> wt{h,l}[N][K] bf16
__global__ void k_wsplit(const float* __restrict__ w, unsigned short* __restrict__ th,
                         unsigned short* __restrict__ tl, int K, int N) {
    int i = blockIdx.x * 256 + threadIdx.x;
    if (i >= K * N) return;
    int k = i / N, n = i - k * N;          // read coalesced over n
    float f = w[i];
    unsigned short h = f2bf(f);
    th[(size_t)n * K + k] = h;
    tl[(size_t)n * K + k] = f2bf(f - bf2f(h));
}

// ---------------------------------------------------------------- BN-fold: wf[n][k] = scl[k]*w[k][n]; bias2 = bias + shf.w
__global__ __launch_bounds__(64) void k_wfold(const float* __restrict__ stats,
        const float* __restrict__ g, const float* __restrict__ be,
        const float* __restrict__ w, const float* __restrict__ bias,
        unsigned short* __restrict__ wfh, unsigned short* __restrict__ wfl,
        float* __restrict__ bias2, float invN) {
    __shared__ float red[64];
    int n = blockIdx.x, k = threadIdx.x;
    float mu = stats[k] * invN;
    float var = stats[64 + k] * invN - mu * mu;
    float sc = g[k] * rsqrtf(var + EPS);
    float sh = be[k] - mu * sc;
    float wv = w[k * 64 + n];
    float wf = sc * wv;
    unsigned short h, l;
    split2bf(wf, h, l);
    wfh[n * 64 + k] = h; wfl[n * 64 + k] = l;
    red[k] = sh * wv; __syncthreads();
    for (int o = 32; o; o >>= 1) {
        if (k < o) red[k] += red[k + o];
        __syncthreads();
    }
    if (k == 0) bias2[n] = bias[n] + red[0];
}

// ---------------------------------------------------------------- ec2 weight prep: W0-W1 and W1, transposed bf16 hi/lo
__global__ void k_wprep2(const float* __restrict__ w,   // c2w [128][128]
        unsigned short* __restrict__ wdh, unsigned short* __restrict__ wdl,
        unsigned short* __restrict__ w1h, unsigned short* __restrict__ w1l) {
    int i = blockIdx.x * 256 + threadIdx.x;  // 64*128
    if (i >= 64 * 128) return;
    int k = i >> 7, n = i & 127;
    float w0 = w[k * 128 + n];
    float w1 = w[(64 + k) * 128 + n];
    float wd = w0 - w1;
    unsigned short h, l;
    split2bf(wd, h, l); wdh[n * 64 + k] = h; wdl[n * 64 + k] = l;
    split2bf(w1, h, l); w1h[n * 64 + k] = h; w1l[n * 64 + k] = l;
}

// ---------------------------------------------------------------- kNN on pos (D=3)
__global__ __launch_bounds__(256) void k_knn1(const float* __restrict__ pos,
                                              int* __restrict__ idx1) {
    __shared__ float4 qt[2048];   // all q staged once (32 KB)
    int b = blockIdx.x >> 5;
    int p0 = (blockIdx.x & 31) << 6;
    const float* posb = pos + (size_t)b * P * 3;
#pragma unroll
    for (int t = 0; t < 8; ++t) {
        int q = (t << 8) + threadIdx.x;
        float qx = posb[q * 3 + 0], qy = posb[q * 3 + 1], qz = posb[q * 3 + 2];
        qt[q] = make_float4(qx, qy, qz, qx * qx + qy * qy + qz * qz);
    }
    __syncthreads();
    int pl = threadIdx.x >> 2, sub = threadIdx.x & 3;
    int p = p0 + pl;
    float4 me = qt[p];
    float x = me.x, y = me.y, z = me.z, sqp = me.w;
    float bd[KNN]; int bi[KNN];
#pragma unroll
    for (int i = 0; i < KNN; ++i) { bd[i] = INFINITY; bi[i] = 0; }
    for (int j0 = 0; j0 < 512; j0 += 8) {
        float4 v[8];
#pragma unroll
        for (int u = 0; u < 8; ++u) v[u] = qt[((j0 + u) << 2) | sub];
#pragma unroll
        for (int u = 0; u < 8; ++u) {
            float dot = x * v[u].x + y * v[u].y + z * v[u].z;
            float d2 = sqp + v[u].w - 2.f * dot;
            if (d2 < bd[KNN - 1]) ins5(d2, ((j0 + u) << 2) | sub, bd, bi);
        }
    }
    // butterfly merge across the 4 subs; snapshot-then-insert
#pragma unroll
    for (int w = 1; w <= 2; w <<= 1) {
        float od[KNN]; int oi[KNN];
#pragma unroll
        for (int i = 0; i < KNN; ++i) {
            od[i] = __shfl_xor(bd[i], w, 64);
            oi[i] = __shfl_xor(bi[i], w, 64);
        }
#pragma unroll
        for (int i = 0; i < KNN; ++i) ins5t(od[i], oi[i], bd, bi);
    }
    if (sub == 0) {
        size_t o = ((size_t)b * P + p) * KNN;
#pragma unroll
        for (int i = 0; i < KNN; ++i) idx1[o + i] = bi[i];
    }
}

// ---------------------------------------------------------------- edgeconv1 layer0: e[6] @ w[6,64]; bf16 hi/lo out + partials
__global__ __launch_bounds__(256) void k_ec1_l0(const float* __restrict__ pos,
        const int* __restrict__ idx1, const float* __restrict__ w,
        const float* __restrict__ bias, unsigned short* __restrict__ zh,
        unsigned short* __restrict__ zl, float* __restrict__ part) {
    __shared__ float elds[256][6];
    __shared__ float red[256];
    int tid = threadIdx.x;
    int base = blockIdx.x * 256;
    {
        int e = base + tid;
        int bp = e / KNN;
        int bb = bp >> 11;
        int q = idx1[e];
        const float* pi = pos + (size_t)bp * 3;
        const float* pj = pos + ((size_t)(bb << 11) + q) * 3;
        float x0 = pi[0], x1v = pi[1], x2v = pi[2];
        elds[tid][0] = x0; elds[tid][1] = x1v; elds[tid][2] = x2v;
        elds[tid][3] = pj[0] - x0; elds[tid][4] = pj[1] - x1v; elds[tid][5] = pj[2] - x2v;
    }
    int c = tid & 63, lane = tid >> 6;
    float wr[6];
#pragma unroll
    for (int d = 0; d < 6; ++d) wr[d] = w[d * 64 + c];
    float bc = bias[c];
    __syncthreads();
    float s1 = 0.f, s2 = 0.f;
    for (int i = 0; i < 64; ++i) {
        int e = lane + (i << 2);
        float acc = bc;
#pragma unroll
        for (int d = 0; d < 6; ++d) acc = fmaf(elds[e][d], wr[d], acc);
        acc = fmaxf(acc, 0.f);
        unsigned short h, l;
        split2bf(acc, h, l);
        zh[(size_t)(base + e) * 64 + c] = h;
        zl[(size_t)(base + e) * 64 + c] = l;
        s1 += acc; s2 = fmaf(acc, acc, s2);
    }
    red[tid] = s1; __syncthreads();
    if (tid < 64) part[(size_t)blockIdx.x * 128 + tid] =
        red[tid] + red[tid + 64] + red[tid + 128] + red[tid + 192];
    __syncthreads();
    red[tid] = s2; __syncthreads();
    if (tid < 64) part[(size_t)blockIdx.x * 128 + 64 + tid] =
        red[tid] + red[tid + 64] + red[tid + 128] + red[tid + 192];
}

// ---------------------------------------------------------------- gl16: coalesced global->LDS (wave-uniform LDS base + lane*16)
__device__ __forceinline__ void gl16(unsigned short* lds, const unsigned short* g) {
    __builtin_amdgcn_global_load_lds(
        (const __attribute__((address_space(1))) unsigned int*)g,
        (__attribute__((address_space(3))) unsigned int*)lds, 16, 0, 0);
}

// ---------------------------------------------------------------- 64->64 layer (BN folded into weights)
// R27: direct-fragment gathers (16 cache lines/inst, 2-wave blocks) had the
// same latency-bound signature R0's counters proved for k_l1m. Fix is the
// same m97 structure: coalesced global_load_lds staging of the CONTIGUOUS
// 128-row A tile + the 8KB B tile into [128][32]-per-kc LDS tiles (l1m's
// verified conflict-free layout), ds_read_b128 fragments. MFMA operand
// values and order bitwise-identical to the direct version.
__global__ __launch_bounds__(128) void k_lin64m(
        const unsigned short* __restrict__ zinh, const unsigned short* __restrict__ zinl,
        const unsigned short* __restrict__ wfh, const unsigned short* __restrict__ wfl,
        const float* __restrict__ bias2, unsigned short* __restrict__ zouth,
        unsigned short* __restrict__ zoutl, float* __restrict__ part) {
    __shared__ unsigned short Ah[128 * 32], Al[128 * 32];   // [row][k32] per kc, 8 KB each
    __shared__ unsigned short Bh[64 * 32], Bl[64 * 32];     // [col][k32] per kc, 4 KB each
    __shared__ float red[2 * 64 * 2];
    int tid = threadIdx.x;
    int wv = tid >> 6, lane = tid & 63;
    int l15 = lane & 15, quad = lane >> 4;
    int row0g = blockIdx.x * 128;          // block row base (contiguous in memory)
    int row0 = row0g + wv * 64;            // per-wave row base
    int rloc = lane >> 2;                  // row within 16-row staging segment
    int ch8 = (lane & 3) * 8;              // k-chunk (shorts, 16 B)
    f32x4 acc[4][4];
#pragma unroll
    for (int i = 0; i < 4; ++i)
#pragma unroll
        for (int j = 0; j < 4; ++j) acc[i][j] = (f32x4)0.f;

#pragma unroll
    for (int kc = 0; kc < 2; ++kc) {
        // stage A [128][32] (8 segs of 16 rows; waves interleave) + B [64][32]
#pragma unroll
        for (int s = 0; s < 4; ++s) {
            int seg = s * 2 + wv;          // 0..7
            size_t ago = (size_t)(row0g + seg * 16 + rloc) * 64 + kc * 32 + ch8;
            int lb = seg * 16 * 32;        // wave-uniform LDS base (shorts)
            gl16(&Ah[lb], &zinh[ago]);
            gl16(&Al[lb], &zinl[ago]);
        }
#pragma unroll
        for (int s = 0; s < 2; ++s) {
            int seg = s * 2 + wv;          // 0..3
            size_t bgo = (size_t)(seg * 16 + rloc) * 64 + kc * 32 + ch8;
            int lb = seg * 16 * 32;
            gl16(&Bh[lb], &wfh[bgo]);
            gl16(&Bl[lb], &wfl[bgo]);
        }
        __syncthreads();    // compiler drains vmcnt before s_barrier
        bf16x8 afh[4], afl[4], bfh[4], bfl[4];
#pragma unroll
        for (int i = 0; i < 4; ++i) {
            int o = (wv * 64 + i * 16 + l15) * 32 + quad * 8;
            afh[i] = *(const bf16x8*)&Ah[o];
            afl[i] = *(const bf16x8*)&Al[o];
        }
#pragma unroll
        for (int j = 0; j < 4; ++j) {
            int o = (j * 16 + l15) * 32 + quad * 8;
            bfh[j] = *(const bf16x8*)&Bh[o];
            bfl[j] = *(const bf16x8*)&Bl[o];
        }
#pragma unroll
        for (int i = 0; i < 4; ++i)
#pragma unroll
            for (int j = 0; j < 4; ++j) {
                acc[i][j] = __builtin_amdgcn_mfma_f32_16x16x32_bf16(afh[i], bfh[j], acc[i][j], 0, 0, 0);
                acc[i][j] = __builtin_amdgcn_mfma_f32_16x16x32_bf16(afh[i], bfl[j], acc[i][j], 0, 0, 0);
                acc[i][j] = __builtin_amdgcn_mfma_f32_16x16x32_bf16(afl[i], bfh[j], acc[i][j], 0, 0, 0);
            }
        __syncthreads();    // protect LDS re-stage of kc=1
    }
    // epilogue: bias + ReLU, bf16 split store, per-col stats
#pragma unroll
    for (int j = 0; j < 4; ++j) {
        int colL = j * 16 + l15;
        float bl = bias2[colL];
        float s1 = 0.f, s2 = 0.f;
#pragma unroll
        for (int i = 0; i < 4; ++i) {
            int row = row0 + i * 16 + quad * 4;
#pragma unroll
            for (int r = 0; r < 4; ++r) {
                float v = fmaxf(acc[i][j][r] + bl, 0.f);
                unsigned short h, l;
                split2bf(v, h, l);
                zouth[(size_t)(row + r) * 64 + colL] = h;
                zoutl[(size_t)(row + r) * 64 + colL] = l;
                s1 += v; s2 = fmaf(v, v, s2);
            }
        }
        s1 += __shfl_xor(s1, 16, 64); s1 += __shfl_xor(s1, 32, 64);
        s2 += __shfl_xor(s2, 16, 64); s2 += __shfl_xor(s2, 32, 64);
        if (quad == 0) {
            red[(wv * 64 + colL) * 2 + 0] = s1;
            red[(wv * 64 + colL) * 2 + 1] = s2;
        }
    }
    __syncthreads();
    if (tid < 64) {
        part[(size_t)blockIdx.x * 128 + tid] =
            red[tid * 2] + red[(64 + tid) * 2];
        part[(size_t)blockIdx.x * 128 + 64 + tid] =
            red[tid * 2 + 1] + red[(64 + tid) * 2 + 1];
    }
}

// ---------------------------------------------------------------- ec1 finalize: BN + max over k -> x1 bf16 hi/lo (fused xsplit), sq norms
// NOTE: x1h/x1l MUST NOT alias z2h/z2l (R5 bug: in-place overwrite raced
// with other blocks' reads of z2 rows). x1 pair has a dedicated allocation.
__global__ __launch_bounds__(256) void k_ec1_fin(const unsigned short* __restrict__ z2h,
        const unsigned short* __restrict__ z2l,
        const float* __restrict__ statsIn, const float* __restrict__ g,
        const float* __restrict__ be, unsigned short* __restrict__ x1h,
        unsigned short* __restrict__ x1l, float* __restrict__ sq2) {
    int tid = threadIdx.x;
    int o = blockIdx.x * 256 + tid;
    int c = o & 63; int bp = o >> 6;
    float mu = statsIn[c] * (1.f / E);
    float var = statsIn[64 + c] * (1.f / E) - mu * mu;
    float sc = g[c] * rsqrtf(var + EPS);
    float sh = be[c] - mu * sc;
    float m = -INFINITY;
#pragma unroll
    for (int j = 0; j < KNN; ++j) {
        size_t zo = ((size_t)bp * KNN + j) * 64 + c;
        float v = bf2f(z2h[zo]) + bf2f(z2l[zo]);
        m = fmaxf(m, fmaf(v, sc, sh));
    }
    unsigned short h, l;
    split2bf(m, h, l);
    x1h[o] = h; x1l[o] = l;
    float ss = m * m;
#pragma unroll
    for (int off = 32; off; off >>= 1) ss += __shfl_down(ss, off, 64);
    if (c == 0) sq2[bp] = ss;
}

// ---------------------------------------------------------------- kNN2 partial
// R19: swapped-operand Gram -> C[q][p] with p=lane&15: lane owns full p-rows,
// top-5 scan on MFMA accumulator registers; no LDS key tile.
// R22: q-frags shared across both p-tiles. R26: 2-deep j software pipeline
// (issue j+1 loads before j's MFMAs+scan) -> 103->88us. Named A/B reg sets
// (rule #20). MFMA order per acc unchanged -> bitwise-identical idx2.
__global__ __launch_bounds__(128) void k_knn2(const unsigned short* __restrict__ x1h,
        const unsigned short* __restrict__ x1l, const float* __restrict__ sq2,
        float* __restrict__ cd, int* __restrict__ ci) {
    int tid = threadIdx.x;
    int wv = tid >> 6, lane = tid & 63;
    int l15 = lane & 15, quad = lane >> 4;
    int qc = blockIdx.x & (QC2 - 1);
    int pt = blockIdx.x >> QC2_SHIFT;         // 16*32 ptiles of 64 rows
    int b = pt >> 5;
    int pw = ((pt & 31) << 6) + wv * 32;      // wave p base within batch
    const size_t xbase = (size_t)b * P * 64;
    int qlo = qc * (P / QC2);                 // 512-q chunk

    // B operand: p-row fragments for both 16-row tiles (held whole kernel)
    bf16x8 ph[2][2], pl_[2][2];               // [i][kc]
#pragma unroll
    for (int i = 0; i < 2; ++i)
#pragma unroll
        for (int kc = 0; kc < 2; ++kc) {
            size_t o = xbase + (size_t)(pw + i * 16 + l15) * 64 + kc * 32 + quad * 8;
            ph[i][kc] = *(const bf16x8*)&x1h[o];
            pl_[i][kc] = *(const bf16x8*)&x1l[o];
        }
    // per-lane top-5 for p-rows l15 (0) and 16+l15 (1)
    float bd0[KNN], bd1[KNN]; int bi0[KNN], bi1[KNN];
#pragma unroll
    for (int i = 0; i < KNN; ++i) {
        bd0[i] = INFINITY; bi0[i] = 0;
        bd1[i] = INFINITY; bi1[i] = 0;
    }

    auto loadQ = [&](int q0, int j, bf16x8* qh, bf16x8* ql, f32x4& sq) {
#pragma unroll
        for (int kc = 0; kc < 2; ++kc) {
            size_t o = xbase + (size_t)(q0 + j * 16 + l15) * 64 + kc * 32 + quad * 8;
            qh[kc] = *(const bf16x8*)&x1h[o];
            ql[kc] = *(const bf16x8*)&x1l[o];
        }
        sq = *(const f32x4*)&sq2[b * P + q0 + j * 16 + (quad << 2)];
    };
    auto procQ = [&](int q0, int j, const bf16x8* qh, const bf16x8* ql,
                     f32x4 sq) {
        f32x4 a0 = (f32x4)0.f, a1 = (f32x4)0.f;
#pragma unroll
        for (int kc = 0; kc < 2; ++kc) {
            a0 = __builtin_amdgcn_mfma_f32_16x16x32_bf16(qh[kc], ph[0][kc], a0, 0, 0, 0);
            a0 = __builtin_amdgcn_mfma_f32_16x16x32_bf16(qh[kc], pl_[0][kc], a0, 0, 0, 0);
            a0 = __builtin_amdgcn_mfma_f32_16x16x32_bf16(ql[kc], ph[0][kc], a0, 0, 0, 0);
            a1 = __builtin_amdgcn_mfma_f32_16x16x32_bf16(qh[kc], ph[1][kc], a1, 0, 0, 0);
            a1 = __builtin_amdgcn_mfma_f32_16x16x32_bf16(qh[kc], pl_[1][kc], a1, 0, 0, 0);
            a1 = __builtin_amdgcn_mfma_f32_16x16x32_bf16(ql[kc], ph[1][kc], a1, 0, 0, 0);
        }
        int qb = q0 + j * 16 + (quad << 2);
#pragma unroll
        for (int r = 0; r < 4; ++r) {
            float d0 = fmaf(a0[r], -2.f, sq[r]);
            if (d0 < bd0[KNN - 1]) ins5(d0, qb + r, bd0, bi0);
            float d1 = fmaf(a1[r], -2.f, sq[r]);
            if (d1 < bd1[KNN - 1]) ins5(d1, qb + r, bd1, bi1);
        }
    };

#pragma unroll 1
    for (int t = 0; t < (P / QC2) / 128; ++t) {
        int q0 = qlo + (t << 7);
        bf16x8 qhA[2], qlA[2], qhB[2], qlB[2];
        f32x4 sqA, sqB;
        loadQ(q0, 0, qhA, qlA, sqA);
#pragma unroll 1
        for (int jj = 0; jj < 8; jj += 2) {
            loadQ(q0, jj + 1, qhB, qlB, sqB);   // prefetch odd
            procQ(q0, jj, qhA, qlA, sqA);
            if (jj < 6) loadQ(q0, jj + 2, qhA, qlA, sqA);   // prefetch next even
            procQ(q0, jj + 1, qhB, qlB, sqB);
        }
    }
    // merge across the 4 quads sharing l15 (disjoint q mod 16 -> clean ties)
    merge_xor(16, bd0, bi0); merge_xor(16, bd1, bi1);
    merge_xor(32, bd0, bi0); merge_xor(32, bd1, bi1);
    if (quad == 0) {
        size_t o0 = (((size_t)b * P + pw + l15) * QC2 + qc) * KNN;
        size_t o1 = (((size_t)b * P + pw + 16 + l15) * QC2 + qc) * KNN;
#pragma unroll
        for (int k = 0; k < KNN; ++k) {
            cd[o0 + k] = bd0[k]; ci[o0 + k] = bi0[k];
            cd[o1 + k] = bd1[k]; ci[o1 + k] = bi1[k];
        }
    }
}

// ---------------------------------------------------------------- kNN2 merge (QC2 sorted chunks of 5 -> 5)
__global__ __launch_bounds__(256) void k_knn2m(const float* __restrict__ cd,
        const int* __restrict__ ci, int* __restrict__ idx2) {
    int bp = blockIdx.x * 256 + threadIdx.x;
    float bd[KNN]; int bi[KNN];
#pragma unroll
    for (int i = 0; i < KNN; ++i) { bd[i] = INFINITY; bi[i] = 0; }
    size_t o = (size_t)bp * QC2 * KNN;
    for (int t = 0; t < QC2 * KNN; ++t) {
        float d2 = cd[o + t]; int qi = ci[o + t];
        if (d2 < bd[KNN - 1]) ins5(d2, qi, bd, bi);
    }
#pragma unroll
    for (int i = 0; i < KNN; ++i) idx2[bp * KNN + i] = bi[i];
}

// ---------------------------------------------------------------- edgeconv2 (direct-fragment split-bf16 MFMA)
__global__ __launch_bounds__(256) void k_ec2m(
        const unsigned short* __restrict__ x1h, const unsigned short* __restrict__ x1l,
        const int* __restrict__ idx2,
        const unsigned short* __restrict__ wdh, const unsigned short* __restrict__ wdl,
        const unsigned short* __restrict__ w1h, const unsigned short* __restrict__ w1l,
        const float* __restrict__ bias, float* __restrict__ zout,
        float* __restrict__ stats) {
    __shared__ float red[2 * 128 * 2];
    int tid = threadIdx.x;
    int base = blockIdx.x * 128;            // first edge
    int bb = base / (P * KNN);              // batch (blocks never straddle: 10240%128==0)
    int wv = tid >> 6, lane = tid & 63;
    int wm = wv >> 1, wn = wv & 1;
    int l15 = lane & 15, quad = lane >> 4;
    // per-lane A rows for this wave's 4 row-tiles
    int rI[4], rJ[4];
#pragma unroll
    for (int i = 0; i < 4; ++i) {
        int e = base + wm * 64 + i * 16 + l15;
        rI[i] = e / KNN;
        rJ[i] = (bb << 11) + idx2[e];
    }
    f32x4 acc[4][4];
#pragma unroll
    for (int i = 0; i < 4; ++i)
#pragma unroll
        for (int j = 0; j < 4; ++j) acc[i][j] = (f32x4)0.f;

#pragma unroll
    for (int s = 0; s < 2; ++s) {
        const unsigned short* bh_ = s ? w1h : wdh;
        const unsigned short* bl_ = s ? w1l : wdl;
#pragma unroll
        for (int kc = 0; kc < 2; ++kc) {
            bf16x8 afh[4], afl[4], bfh[4], bfl[4];
#pragma unroll
            for (int i = 0; i < 4; ++i) {
                int row = s ? rJ[i] : rI[i];
                size_t o = (size_t)row * 64 + kc * 32 + quad * 8;
                afh[i] = *(const bf16x8*)&x1h[o];
                afl[i] = *(const bf16x8*)&x1l[o];
            }
#pragma unroll
            for (int j = 0; j < 4; ++j) {
                size_t wo = (size_t)(wn * 64 + j * 16 + l15) * 64 + kc * 32 + quad * 8;
                bfh[j] = *(const bf16x8*)&bh_[wo];
                bfl[j] = *(const bf16x8*)&bl_[wo];
            }
#pragma unroll
            for (int i = 0; i < 4; ++i)
#pragma unroll
                for (int j = 0; j < 4; ++j) {
                    acc[i][j] = __builtin_amdgcn_mfma_f32_16x16x32_bf16(afh[i], bfh[j], acc[i][j], 0, 0, 0);
                    acc[i][j] = __builtin_amdgcn_mfma_f32_16x16x32_bf16(afh[i], bfl[j], acc[i][j], 0, 0, 0);
                    acc[i][j] = __builtin_amdgcn_mfma_f32_16x16x32_bf16(afl[i], bfh[j], acc[i][j], 0, 0, 0);
                }
        }
    }
    // epilogue: bias + ReLU, write z, per-col stats
#pragma unroll
    for (int j = 0; j < 4; ++j) {
        int colL = wn * 64 + j * 16 + l15;
        float bl = bias[colL];
        float s1 = 0.f, s2 = 0.f;
#pragma unroll
        for (int i = 0; i < 4; ++i) {
            int row = wm * 64 + i * 16 + quad * 4;
#pragma unroll
            for (int r = 0; r < 4; ++r) {
                float v = fmaxf(acc[i][j][r] + bl, 0.f);
                zout[(size_t)(base + row + r) * 128 + colL] = v;
                s1 += v; s2 = fmaf(v, v, s2);
            }
        }
        s1 += __shfl_xor(s1, 16, 64); s1 += __shfl_xor(s1, 32, 64);
        s2 += __shfl_xor(s2, 16, 64); s2 += __shfl_xor(s2, 32, 64);
        if (quad == 0) {
            red[(wm * 128 + colL) * 2 + 0] = s1;
            red[(wm * 128 + colL) * 2 + 1] = s2;
        }
    }
    __syncthreads();
    if (tid < 128) {
        atomicAdd(&stats[tid], red[tid * 2] + red[(128 + tid) * 2]);
        atomicAdd(&stats[128 + tid], red[tid * 2 + 1] + red[(128 + tid) * 2 + 1]);
    }
}

// ---------------------------------------------------------------- ec2 finalize: BN + max over k -> x2 bf16 hi/lo (fused xsplit)
// safe: z3 lives in zA, x2 pair lives in zB — disjoint buffers.
__global__ __launch_bounds__(256) void k_ec2_fin(const float* __restrict__ z3,
        const float* __restrict__ stats, const float* __restrict__ g,
        const float* __restrict__ be, unsigned short* __restrict__ x2h,
        unsigned short* __restrict__ x2l) {
    int o = blockIdx.x * 256 + threadIdx.x;
    int c = o & 127; int bp = o >> 7;
    float mu = stats[c] * (1.f / E);
    float var = stats[128 + c] * (1.f / E) - mu * mu;
    float sc = g[c] * rsqrtf(var + EPS);
    float sh = be[c] - mu * sc;
    float m = -INFINITY;
#pragma unroll
    for (int j = 0; j < KNN; ++j)
        m = fmaxf(m, fmaf(z3[((size_t)bp * KNN + j) * 128 + c], sc, sh));
    unsigned short h, l;
    split2bf(m, h, l);
    x2h[o] = h; x2l[o] = l;
}

// ---------------------------------------------------------------- l1 (LDS-staged split-bf16 MFMA, m97-style 2-phase)
// R18: coalesced global_load_lds staging + ds_read_b128 frags fixed the
// latency-bound direct-gather version (108 -> out of top-5).
__global__ __launch_bounds__(256) void k_l1m(
        const unsigned short* __restrict__ x1h, const unsigned short* __restrict__ x1l,
        const unsigned short* __restrict__ x2h, const unsigned short* __restrict__ x2l,
        const unsigned short* __restrict__ wth, const unsigned short* __restrict__ wtl,
        const float* __restrict__ bias, float* __restrict__ stats,
        float* __restrict__ pmax, float* __restrict__ pmin) {
    __shared__ unsigned short Ah[128 * 32], Al[128 * 32];   // [row][k] bf16, 8 KB each
    __shared__ unsigned short Bh[128 * 32], Bl[128 * 32];   // [col][k] bf16
    __shared__ float red[2 * 128 * 4];
    int tid = threadIdx.x;
    int brow = blockIdx.x & 255;
    int bcol = blockIdx.x >> 8;
    int row0 = brow << 7, col0 = bcol << 7;
    int wv = tid >> 6, lane = tid & 63;
    int wm = wv >> 1, wn = wv & 1;
    int l15 = lane & 15, quad = lane >> 4;
    int rloc = wv * 16 + (lane >> 2);      // staging row for call 0 (+64 for call 1)
    int ch8 = (lane & 3) * 8;              // staging k-chunk (ushorts, 16 B)
    f32x4 acc[4][4];
#pragma unroll
    for (int i = 0; i < 4; ++i)
#pragma unroll
        for (int j = 0; j < 4; ++j) acc[i][j] = (f32x4)0.f;

#pragma unroll
    for (int t = 0; t < 6; ++t) {
        int k0 = t * 32;
        const unsigned short* ah = (k0 < 64) ? x1h : x2h;
        const unsigned short* al = (k0 < 64) ? x1l : x2l;
        int astr = (k0 < 64) ? 64 : 128;
        int aoff = (k0 < 64) ? k0 : (k0 - 64);
        // stage: 32 KB/step, 8 x 16B global_load_lds per thread, 1 KB/wave/call
#pragma unroll
        for (int c = 0; c < 2; ++c) {
            int rl = c * 64 + rloc;
            size_t ao = (size_t)(row0 + rl) * astr + aoff + ch8;
            size_t bo = (size_t)(col0 + rl) * 192 + k0 + ch8;
            int lb = (c * 64 + wv * 16) * 32;   // wave-uniform LDS base (ushorts)
            gl16(&Ah[lb], &ah[ao]);
            gl16(&Al[lb], &al[ao]);
            gl16(&Bh[lb], &wth[bo]);
            gl16(&Bl[lb], &wtl[bo]);
        }
        __syncthreads();    // compiler drains vmcnt before s_barrier
        bf16x8 afh[4], afl[4], bfh[4], bfl[4];
#pragma unroll
        for (int i = 0; i < 4; ++i) {
            int o = (wm * 64 + i * 16 + l15) * 32 + quad * 8;
            afh[i] = *(const bf16x8*)&Ah[o];
            afl[i] = *(const bf16x8*)&Al[o];
        }
#pragma unroll
        for (int j = 0; j < 4; ++j) {
            int o = (wn * 64 + j * 16 + l15) * 32 + quad * 8;
            bfh[j] = *(const bf16x8*)&Bh[o];
            bfl[j] = *(const bf16x8*)&Bl[o];
        }
#pragma unroll
        for (int i = 0; i < 4; ++i)
#pragma unroll
            for (int j = 0; j < 4; ++j) {
                acc[i][j] = __builtin_amdgcn_mfma_f32_16x16x32_bf16(afh[i], bfh[j], acc[i][j], 0, 0, 0);
                acc[i][j] = __builtin_amdgcn_mfma_f32_16x16x32_bf16(afh[i], bfl[j], acc[i][j], 0, 0, 0);
                acc[i][j] = __builtin_amdgcn_mfma_f32_16x16x32_bf16(afl[i], bfh[j], acc[i][j], 0, 0, 0);
            }
        __syncthreads();    // protect LDS re-stage of step t+1
    }
    // epilogue: bias + ReLU, per-col sum/sumsq/max/min (h never materialized)
#pragma unroll
    for (int j = 0; j < 4; ++j) {
        int colL = wn * 64 + j * 16 + l15;
        float bl = bias[col0 + colL];
        float s1 = 0.f, s2 = 0.f, mx = 0.f, mn = INFINITY;
#pragma unroll
        for (int i = 0; i < 4; ++i)
#pragma unroll
            for (int r = 0; r < 4; ++r) {
                float v = fmaxf(acc[i][j][r] + bl, 0.f);
                s1 += v; s2 = fmaf(v, v, s2);
                mx = fmaxf(mx, v); mn = fminf(mn, v);
            }
        s1 += __shfl_xor(s1, 16, 64); s1 += __shfl_xor(s1, 32, 64);
        s2 += __shfl_xor(s2, 16, 64); s2 += __shfl_xor(s2, 32, 64);
        mx = fmaxf(mx, __shfl_xor(mx, 16, 64)); mx = fmaxf(mx, __shfl_xor(mx, 32, 64));
        mn = fminf(mn, __shfl_xor(mn, 16, 64)); mn = fminf(mn, __shfl_xor(mn, 32, 64));
        if (quad == 0) {
            float* rp = &red[(wm * 128 + colL) * 4];
            rp[0] = s1; rp[1] = s2; rp[2] = mx; rp[3] = mn;
        }
    }
    __syncthreads();
    if (tid < 128) {
        const float* r0 = &red[tid * 4];
        const float* r1 = &red[(128 + tid) * 4];
        int bb = row0 >> 11;
        atomicAdd(&stats[col0 + tid], r0[0] + r1[0]);
        atomicAdd(&stats[1024 + col0 + tid], r0[1] + r1[1]);
        atomicMax((unsigned int*)&pmax[bb * 1024 + col0 + tid],
                  __float_as_uint(fmaxf(r0[2], r1[2])));
        atomicMin((unsigned int*)&pmin[bb * 1024 + col0 + tid],
                  __float_as_uint(fminf(r0[3], r1[3])));
    }
}

// ---------------------------------------------------------------- pooled p = BN(max or min)
__global__ void k_pool(const float* __restrict__ stats, const float* __restrict__ g,
                       const float* __restrict__ be, const float* __restrict__ pmax,
                       const float* __restrict__ pmin, float* __restrict__ p) {
    int o = blockIdx.x * 256 + threadIdx.x;   // 16384
    int c = o & 1023;
    float mu = stats[c] * (1.f / BP);
    float var = stats[1024 + c] * (1.f / BP) - mu * mu;
    float sc = g[c] * rsqrtf(var + EPS);
    float sh = be[c] - mu * sc;
    float v = (sc >= 0.f) ? pmax[o] : pmin[o];
    p[o] = fmaf(v, sc, sh);
}

// ---------------------------------------------------------------- head
__global__ __launch_bounds__(256) void k_m1(const float* __restrict__ p,
        const float* __restrict__ w, const float* __restrict__ bias,
        float* __restrict__ t1, float* __restrict__ stats) {
    int o = blockIdx.x * 256 + threadIdx.x;   // 8192
    int c = o & 511, b = o >> 9;
    const float* pr = p + (b << 10);
    float acc = bias[c];
    for (int k = 0; k < 1024; ++k) acc = fmaf(pr[k], w[k * 512 + c], acc);
    acc = fmaxf(acc, 0.f);
    t1[o] = acc;
    atomicAdd(&stats[c], acc);
    atomicAdd(&stats[512 + c], acc * acc);
}

__global__ __launch_bounds__(256) void k_m2(const float* __restrict__ t1,
        const float* __restrict__ stats5, const float* __restrict__ g,
        const float* __restrict__ be, const float* __restrict__ w,
        const float* __restrict__ bias, float* __restrict__ t2,
        float* __restrict__ stats6) {
    __shared__ float scl[512], shf[512];
    int tid = threadIdx.x;
    for (int t = tid; t < 512; t += 256) {
        float mu = stats5[t] * (1.f / 16.f);
        float var = stats5[512 + t] * (1.f / 16.f) - mu * mu;
        float sc = g[t] * rsqrtf(var + EPS);
        scl[t] = sc; shf[t] = be[t] - mu * sc;
    }
    __syncthreads();
    int o = blockIdx.x * 256 + tid;   // 4096
    int c = o & 255, b = o >> 8;
    const float* tr = t1 + (b << 9);
    float acc = bias[c];
    for (int k = 0; k < 512; ++k) {
        float u = fmaf(tr[k], scl[k], shf[k]);
        acc = fmaf(u, w[k * 256 + c], acc);
    }
    acc = fmaxf(acc, 0.f);
    t2[o] = acc;
    atomicAdd(&stats6[c], acc);
    atomicAdd(&stats6[256 + c], acc * acc);
}

__global__ __launch_bounds__(256) void k_m3(const float* __restrict__ t2,
        const float* __restrict__ stats6, const float* __restrict__ g,
        const float* __restrict__ be, const float* __restrict__ w,
        const float* __restrict__ bias, float* __restrict__ out) {
    __shared__ float scl[256], shf[256];
    int tid = threadIdx.x;
    {
        float mu = stats6[tid] * (1.f / 16.f);
        float var = stats6[256 + tid] * (1.f / 16.f) - mu * mu;
        float sc = g[tid] * rsqrtf(var + EPS);
        scl[tid] = sc; shf[tid] = be[tid] - mu * sc;
    }
    __syncthreads();
    if (tid < 32) {
        int c = tid & 1, b = tid >> 1;
        const float* tr = t2 + (b << 8);
        float acc = bias[c];
        for (int k = 0; k < 256; ++k) {
            float u = fmaf(tr[k], scl[k], shf[k]);
            acc = fmaf(u, w[k * 2 + c], acc);
        }
        out[tid] = acc;
    }
}

// ================================================================ launch
extern "C" void kernel_launch(void* const* d_in, const int* in_sizes, int n_in,
                              void* d_out, int out_size, void* d_ws, size_t ws_size,
                              hipStream_t stream) {
    const float* pos  = (const float*)d_in[0];
    const float* c1w0 = (const float*)d_in[1];
    const float* c1b0 = (const float*)d_in[2];
    const float* c1g0 = (const float*)d_in[3];
    const float* c1e0 = (const float*)d_in[4];
    const float* c1w1 = (const float*)d_in[5];
    const float* c1b1 = (const float*)d_in[6];
    const float* c1g1 = (const float*)d_in[7];
    const float* c1e1 = (const float*)d_in[8];
    const float* c1w2 = (const float*)d_in[9];
    const float* c1b2 = (const float*)d_in[10];
    const float* c1g2 = (const float*)d_in[11];
    const float* c1e2 = (const float*)d_in[12];
    const float* c2w  = (const float*)d_in[13];
    const float* c2b  = (const float*)d_in[14];
    const float* c2g  = (const float*)d_in[15];
    const float* c2e  = (const float*)d_in[16];
    const float* l1w  = (const float*)d_in[17];
    const float* l1b  = (const float*)d_in[18];
    const float* l1g  = (const float*)d_in[19];
    const float* l1e  = (const float*)d_in[20];
    const float* m1w  = (const float*)d_in[21];
    const float* m1b  = (const float*)d_in[22];
    const float* m1g  = (const float*)d_in[23];
    const float* m1e  = (const float*)d_in[24];
    const float* m2w  = (const float*)d_in[25];
    const float* m2b  = (const float*)d_in[26];
    const float* m2g  = (const float*)d_in[27];
    const float* m2e  = (const float*)d_in[28];
    const float* m3w  = (const float*)d_in[29];
    const float* m3b  = (const float*)d_in[30];
    float* out = (float*)d_out;

    char* ws = (char*)d_ws;
    size_t off = 0;
    auto alloc = [&](size_t bytes) {
        size_t r = off; off = (off + bytes + 255) & ~(size_t)255; return r;
    };
    float* stats = (float*)(ws + alloc(ST_TOTAL * 4));
    float* pmax  = (float*)(ws + alloc(16 * 1024 * 4));
    float* pmin  = (float*)(ws + alloc(16 * 1024 * 4));
    float* pbuf  = (float*)(ws + alloc(16 * 1024 * 4));
    float* t1    = (float*)(ws + alloc(16 * 512 * 4));
    float* t2    = (float*)(ws + alloc(16 * 256 * 4));
    float* sq2   = (float*)(ws + alloc((size_t)BP * 4));
    float* part  = (float*)(ws + alloc((size_t)(E / 64) * 128 * 4));  // up to 2560 blocks x 128
    unsigned short* wthL = (unsigned short*)(ws + alloc((size_t)192 * 1024 * 2));
    unsigned short* wtlL = (unsigned short*)(ws + alloc((size_t)192 * 1024 * 2));
    unsigned short* wdh  = (unsigned short*)(ws + alloc((size_t)128 * 64 * 2));
    unsigned short* wdl  = (unsigned short*)(ws + alloc((size_t)128 * 64 * 2));
    unsigned short* w1h  = (unsigned short*)(ws + alloc((size_t)128 * 64 * 2));
    unsigned short* w1l  = (unsigned short*)(ws + alloc((size_t)128 * 64 * 2));
    unsigned short* wf1h = (unsigned short*)(ws + alloc((size_t)64 * 64 * 2));
    unsigned short* wf1l = (unsigned short*)(ws + alloc((size_t)64 * 64 * 2));
    unsigned short* wf2h = (unsigned short*)(ws + alloc((size_t)64 * 64 * 2));
    unsigned short* wf2l = (unsigned short*)(ws + alloc((size_t)64 * 64 * 2));
    float* bias2a = (float*)(ws + alloc(64 * 4));
    float* bias2b = (float*)(ws + alloc(64 * 4));
    int*   idx1  = (int*)  (ws + alloc((size_t)E * 4));
    int*   idx2  = (int*)  (ws + alloc((size_t)E * 4));
    // dedicated x1 bf16 pair (R6 fix: must NOT alias z2 — ec1_fin reads z2
    // and writes x1 in the same kernel; aliasing raced across blocks)
    unsigned short* x1h = (unsigned short*)(ws + alloc((size_t)BP * 64 * 2));
    unsigned short* x1l = (unsigned short*)(ws + alloc((size_t)BP * 64 * 2));
    float* zA    = (float*)(ws + alloc((size_t)E * 128 * 4)); // hosts z0/z1 bf16 pairs, later z3 fp32
    float* zB    = (float*)(ws + alloc((size_t)E * 64 * 4));  // hosts z2 bf16 pair, later knn2 scratch
    // zA aliases: z0h/z0l (21MB each) then z1h/z1l; all dead before z3 (ec2 out) overwrites
    unsigned short* z0h = (unsigned short*)zA;
    unsigned short* z0l = z0h + (size_t)E * 64;
    unsigned short* z1h = z0l + (size_t)E * 64;
    unsigned short* z1l = z1h + (size_t)E * 64;
    // zB aliases: z2h/z2l (dead after ec1_fin completes), then knn2 scratch:
    // cand 5.2MB + x2 pair 16.8MB = 22 < 41.9MB
    unsigned short* z2h = (unsigned short*)zB;
    unsigned short* z2l = z2h + (size_t)E * 64;
    float* cand_d = (float*)zB;
    int*   cand_i = (int*)(cand_d + (size_t)BP * QC2 * KNN);
    unsigned short* x2h = (unsigned short*)(cand_i + (size_t)BP * QC2 * KNN);
    unsigned short* x2l = x2h + (size_t)BP * 128;

    (void)in_sizes; (void)n_in; (void)out_size; (void)ws_size;

    k_init<<<64, 256, 0, stream>>>(stats, pmax, pmin);
    k_wsplit<<<(192 * 1024 + 255) / 256, 256, 0, stream>>>(l1w, wthL, wtlL, 192, 1024);
    k_wprep2<<<(64 * 128 + 255) / 256, 256, 0, stream>>>(c2w, wdh, wdl, w1h, w1l);
    k_knn1<<<B * 32, 256, 0, stream>>>(pos, idx1);
    k_ec1_l0<<<E / 256, 256, 0, stream>>>(pos, idx1, c1w0, c1b0, z0h, z0l, part);
    k_redstat<<<128, 256, 0, stream>>>(part, stats + ST0, E / 256);
    k_wfold<<<64, 64, 0, stream>>>(stats + ST0, c1g0, c1e0, c1w1, c1b1,
                                   wf1h, wf1l, bias2a, 1.f / E);
    k_lin64m<<<E / 128, 128, 0, stream>>>(z0h, z0l, wf1h, wf1l, bias2a,
                                          z1h, z1l, part);
    k_redstat<<<128, 256, 0, stream>>>(part, stats + ST1, E / 128);
    k_wfold<<<64, 64, 0, stream>>>(stats + ST1, c1g1, c1e1, c1w2, c1b2,
                                   wf2h, wf2l, bias2b, 1.f / E);
    k_lin64m<<<E / 128, 128, 0, stream>>>(z1h, z1l, wf2h, wf2l, bias2b,
                                          z2h, z2l, part);
    k_redstat<<<128, 256, 0, stream>>>(part, stats + ST2, E / 128);
    k_ec1_fin<<<BP * 64 / 256, 256, 0, stream>>>(z2h, z2l, stats + ST2, c1g2, c1e2,
                                                 x1h, x1l, sq2);
    k_knn2<<<B * 32 * QC2, 128, 0, stream>>>(x1h, x1l, sq2, cand_d, cand_i);
    k_knn2m<<<BP / 256, 256, 0, stream>>>(cand_d, cand_i, idx2);
    k_ec2m<<<E / 128, 256, 0, stream>>>(x1h, x1l, idx2, wdh, wdl, w1h, w1l,
                                        c2b, zA, stats + ST3);
    k_ec2_fin<<<BP * 128 / 256, 256, 0, stream>>>(zA, stats + ST3, c2g, c2e,
                                                  x2h, x2l);
    k_l1m<<<256 * 8, 256, 0, stream>>>(x1h, x1l, x2h, x2l, wthL, wtlL, l1b,
                                       stats + ST4, pmax, pmin);
    k_pool<<<64, 256, 0, stream>>>(stats + ST4, l1g, l1e, pmax, pmin, pbuf);
    k_m1<<<32, 256, 0, stream>>>(pbuf, m1w, m1b, t1, stats + ST5);
    k_m2<<<16, 256, 0, stream>>>(t1, stats + ST5, m1g, m1e, m2w, m2b, t2, stats + ST6);
    k_m3<<<1, 256, 0, stream>>>(t2, stats + ST6, m2g, m2e, m3w, m3b, out);
}

// Round 11
// 550.766 us; speedup vs baseline: 1.0572x; 1.0068x over previous
//
#include <hip/hip_runtime.h>
#include <cmath>

constexpr int B = 16, P = 2048, KNN = 5;
constexpr int BP = B * P;           // 32768
constexpr int E = BP * KNN;         // 163840
constexpr float EPS = 1e-5f;
constexpr int QC2 = 4;              // q-chunks for knn2 (8 doubled p-frag refetch + cand traffic)
constexpr int QC2_SHIFT = 2;
static_assert(QC2 == (1 << QC2_SHIFT), "QC2 pow2");

// stats layout (floats): per stage [sum[C] | sumsq[C]]
constexpr int ST0 = 0;        // 64ch -> 128
constexpr int ST1 = 128;      // 64ch
constexpr int ST2 = 256;      // 64ch
constexpr int ST3 = 384;      // 128ch -> 256
constexpr int ST4 = 640;      // 1024ch -> 2048
constexpr int ST5 = 2688;     // 512ch -> 1024
constexpr int ST6 = 3712;     // 256ch -> 512
constexpr int ST_TOTAL = 4224;

typedef __attribute__((ext_vector_type(8))) short bf16x8;
typedef __attribute__((ext_vector_type(4))) float f32x4;

__device__ inline unsigned short f2bf(float x) {
    unsigned u = __float_as_uint(x);
    unsigned r = (u + 0x7FFFu + ((u >> 16) & 1u)) >> 16;
    return (unsigned short)r;
}
__device__ inline float bf2f(unsigned short h) {
    return __uint_as_float(((unsigned)h) << 16);
}
// split x into hi (bf16) and lo (bf16 of residual): x ~= hi + lo, err ~2^-18 rel
__device__ inline void split2bf(float x, unsigned short& h, unsigned short& l) {
    unsigned short hh = f2bf(x);
    h = hh;
    l = f2bf(x - bf2f(hh));
}

// branch-free sorted-5 insertion (ascending); constant indices -> stays in VGPRs.
__device__ inline void ins5(float d, int qi, float bd[KNN], int bi[KNN]) {
    bool c0 = d < bd[0], c1 = d < bd[1], c2 = d < bd[2], c3 = d < bd[3], c4 = d < bd[4];
    bd[4] = c3 ? bd[3] : (c4 ? d : bd[4]);  bi[4] = c3 ? bi[3] : (c4 ? qi : bi[4]);
    bd[3] = c2 ? bd[2] : (c3 ? d : bd[3]);  bi[3] = c2 ? bi[2] : (c3 ? qi : bi[3]);
    bd[2] = c1 ? bd[1] : (c2 ? d : bd[2]);  bi[2] = c1 ? bi[1] : (c2 ? qi : bi[2]);
    bd[1] = c0 ? bd[0] : (c1 ? d : bd[1]);  bi[1] = c0 ? bi[0] : (c1 ? qi : bi[1]);
    bd[0] = c0 ? d : bd[0];                 bi[0] = c0 ? qi : bi[0];
}
// insertion with lexicographic (d, qi) tie-break: keep lower q on exact fp tie
__device__ inline void ins5t(float d, int qi, float bd[KNN], int bi[KNN]) {
    bool c0 = (d < bd[0]) || (d == bd[0] && qi < bi[0]);
    bool c1 = (d < bd[1]) || (d == bd[1] && qi < bi[1]);
    bool c2 = (d < bd[2]) || (d == bd[2] && qi < bi[2]);
    bool c3 = (d < bd[3]) || (d == bd[3] && qi < bi[3]);
    bool c4 = (d < bd[4]) || (d == bd[4] && qi < bi[4]);
    bd[4] = c3 ? bd[3] : (c4 ? d : bd[4]);  bi[4] = c3 ? bi[3] : (c4 ? qi : bi[4]);
    bd[3] = c2 ? bd[2] : (c3 ? d : bd[3]);  bi[3] = c2 ? bi[2] : (c3 ? qi : bi[3]);
    bd[2] = c1 ? bd[1] : (c2 ? d : bd[2]);  bi[2] = c1 ? bi[1] : (c2 ? qi : bi[2]);
    bd[1] = c0 ? bd[0] : (c1 ? d : bd[1]);  bi[1] = c0 ? bi[0] : (c1 ? qi : bi[1]);
    bd[0] = c0 ? d : bd[0];                 bi[0] = c0 ? qi : bi[0];
}
// butterfly-merge helper: pull partner's sorted-5 and insert with tie-break
__device__ inline void merge_xor(int w, float bd[KNN], int bi[KNN]) {
    float od[KNN]; int oi[KNN];
#pragma unroll
    for (int k = 0; k < KNN; ++k) {
        od[k] = __shfl_xor(bd[k], w, 64);
        oi[k] = __shfl_xor(bi[k], w, 64);
    }
#pragma unroll
    for (int k = 0; k < KNN; ++k) ins5t(od[k], oi[k], bd, bi);
}

// ---------------------------------------------------------------- init
__global__ void k_init(float* __restrict__ stats, float* __restrict__ pmax,
                       float* __restrict__ pmin) {
    int i = blockIdx.x * 256 + threadIdx.x;   // grid covers 16384
    if (i < ST_TOTAL) stats[i] = 0.f;
    if (i < B * 1024) { pmax[i] = 0.f; pmin[i] = INFINITY; }
}

// ---------------------------------------------------------------- deterministic partial reducer
__global__ __launch_bounds__(256) void k_redstat(const float* __restrict__ part,
        float* __restrict__ stats, int nblk) {
    __shared__ float r[256];
    int slot = blockIdx.x;
    float s = 0.f;
    for (int i = threadIdx.x; i < nblk; i += 256)
        s += part[(size_t)i * 128 + slot];
    r[threadIdx.x] = s; __syncthreads();
    for (int o = 128; o; o >>= 1) {
        if (threadIdx.x < o) r[threadIdx.x] += r[threadIdx.x + o];
        __syncthreads();
    }
    if (threadIdx.x == 0) stats[slot] = r[0];
}

// ---------------------------------------------------------------- weight pre-split: w[K][N] fp32 -> wt{h,l}[N][K] bf16
__global__ void k_wsplit(const float* __restrict__ w, unsigned short* __restrict__ th,
                         unsigned short* __restrict__ tl, int K, int N) {
    int i = blockIdx.x * 256 + threadIdx.x;
    if (i >= K * N) return;
    int k = i / N, n = i - k * N;          // read coalesced over n
    float f = w[i];
    unsigned short h = f2bf(f);
    th[(size_t)n * K + k] = h;
    tl[(size_t)n * K + k] = f2bf(f - bf2f(h));
}

// ---------------------------------------------------------------- BN-fold: wf[n][k] = scl[k]*w[k][n]; bias2 = bias + shf.w
__global__ __launch_bounds__(64) void k_wfold(const float* __restrict__ stats,
        const float* __restrict__ g, const float* __restrict__ be,
        const float* __restrict__ w, const float* __restrict__ bias,
        unsigned short* __restrict__ wfh, unsigned short* __restrict__ wfl,
        float* __restrict__ bias2, float invN) {
    __shared__ float red[64];
    int n = blockIdx.x, k = threadIdx.x;
    float mu = stats[k] * invN;
    float var = stats[64 + k] * invN - mu * mu;
    float sc = g[k] * rsqrtf(var + EPS);
    float sh = be[k] - mu * sc;
    float wv = w[k * 64 + n];
    float wf = sc * wv;
    unsigned short h, l;
    split2bf(wf, h, l);
    wfh[n * 64 + k] = h; wfl[n * 64 + k] = l;
    red[k] = sh * wv; __syncthreads();
    for (int o = 32; o; o >>= 1) {
        if (k < o) red[k] += red[k + o];
        __syncthreads();
    }
    if (k == 0) bias2[n] = bias[n] + red[0];
}

// ---------------------------------------------------------------- ec2 weight prep: W0-W1 and W1, transposed bf16 hi/lo
__global__ void k_wprep2(const float* __restrict__ w,   // c2w [128][128]
        unsigned short* __restrict__ wdh, unsigned short* __restrict__ wdl,
        unsigned short* __restrict__ w1h, unsigned short* __restrict__ w1l) {
    int i = blockIdx.x * 256 + threadIdx.x;  // 64*128
    if (i >= 64 * 128) return;
    int k = i >> 7, n = i & 127;
    float w0 = w[k * 128 + n];
    float w1 = w[(64 + k) * 128 + n];
    float wd = w0 - w1;
    unsigned short h, l;
    split2bf(wd, h, l); wdh[n * 64 + k] = h; wdl[n * 64 + k] = l;
    split2bf(w1, h, l); w1h[n * 64 + k] = h; w1l[n * 64 + k] = l;
}

// ---------------------------------------------------------------- kNN on pos (D=3)
__global__ __launch_bounds__(256) void k_knn1(const float* __restrict__ pos,
                                              int* __restrict__ idx1) {
    __shared__ float4 qt[2048];   // all q staged once (32 KB)
    int b = blockIdx.x >> 5;
    int p0 = (blockIdx.x & 31) << 6;
    const float* posb = pos + (size_t)b * P * 3;
#pragma unroll
    for (int t = 0; t < 8; ++t) {
        int q = (t << 8) + threadIdx.x;
        float qx = posb[q * 3 + 0], qy = posb[q * 3 + 1], qz = posb[q * 3 + 2];
        qt[q] = make_float4(qx, qy, qz, qx * qx + qy * qy + qz * qz);
    }
    __syncthreads();
    int pl = threadIdx.x >> 2, sub = threadIdx.x & 3;
    int p = p0 + pl;
    float4 me = qt[p];
    float x = me.x, y = me.y, z = me.z, sqp = me.w;
    float bd[KNN]; int bi[KNN];
#pragma unroll
    for (int i = 0; i < KNN; ++i) { bd[i] = INFINITY; bi[i] = 0; }
    for (int j0 = 0; j0 < 512; j0 += 8) {
        float4 v[8];
#pragma unroll
        for (int u = 0; u < 8; ++u) v[u] = qt[((j0 + u) << 2) | sub];
#pragma unroll
        for (int u = 0; u < 8; ++u) {
            float dot = x * v[u].x + y * v[u].y + z * v[u].z;
            float d2 = sqp + v[u].w - 2.f * dot;
            if (d2 < bd[KNN - 1]) ins5(d2, ((j0 + u) << 2) | sub, bd, bi);
        }
    }
    // butterfly merge across the 4 subs; snapshot-then-insert
#pragma unroll
    for (int w = 1; w <= 2; w <<= 1) {
        float od[KNN]; int oi[KNN];
#pragma unroll
        for (int i = 0; i < KNN; ++i) {
            od[i] = __shfl_xor(bd[i], w, 64);
            oi[i] = __shfl_xor(bi[i], w, 64);
        }
#pragma unroll
        for (int i = 0; i < KNN; ++i) ins5t(od[i], oi[i], bd, bi);
    }
    if (sub == 0) {
        size_t o = ((size_t)b * P + p) * KNN;
#pragma unroll
        for (int i = 0; i < KNN; ++i) idx1[o + i] = bi[i];
    }
}

// ---------------------------------------------------------------- edgeconv1 layer0: e[6] @ w[6,64]; bf16 hi/lo out + partials
__global__ __launch_bounds__(256) void k_ec1_l0(const float* __restrict__ pos,
        const int* __restrict__ idx1, const float* __restrict__ w,
        const float* __restrict__ bias, unsigned short* __restrict__ zh,
        unsigned short* __restrict__ zl, float* __restrict__ part) {
    __shared__ float elds[256][6];
    __shared__ float red[256];
    int tid = threadIdx.x;
    int base = blockIdx.x * 256;
    {
        int e = base + tid;
        int bp = e / KNN;
        int bb = bp >> 11;
        int q = idx1[e];
        const float* pi = pos + (size_t)bp * 3;
        const float* pj = pos + ((size_t)(bb << 11) + q) * 3;
        float x0 = pi[0], x1v = pi[1], x2v = pi[2];
        elds[tid][0] = x0; elds[tid][1] = x1v; elds[tid][2] = x2v;
        elds[tid][3] = pj[0] - x0; elds[tid][4] = pj[1] - x1v; elds[tid][5] = pj[2] - x2v;
    }
    int c = tid & 63, lane = tid >> 6;
    float wr[6];
#pragma unroll
    for (int d = 0; d < 6; ++d) wr[d] = w[d * 64 + c];
    float bc = bias[c];
    __syncthreads();
    float s1 = 0.f, s2 = 0.f;
    for (int i = 0; i < 64; ++i) {
        int e = lane + (i << 2);
        float acc = bc;
#pragma unroll
        for (int d = 0; d < 6; ++d) acc = fmaf(elds[e][d], wr[d], acc);
        acc = fmaxf(acc, 0.f);
        unsigned short h, l;
        split2bf(acc, h, l);
        zh[(size_t)(base + e) * 64 + c] = h;
        zl[(size_t)(base + e) * 64 + c] = l;
        s1 += acc; s2 = fmaf(acc, acc, s2);
    }
    red[tid] = s1; __syncthreads();
    if (tid < 64) part[(size_t)blockIdx.x * 128 + tid] =
        red[tid] + red[tid + 64] + red[tid + 128] + red[tid + 192];
    __syncthreads();
    red[tid] = s2; __syncthreads();
    if (tid < 64) part[(size_t)blockIdx.x * 128 + 64 + tid] =
        red[tid] + red[tid + 64] + red[tid + 128] + red[tid + 192];
}

// ---------------------------------------------------------------- gl16: coalesced global->LDS (wave-uniform LDS base + lane*16)
__device__ __forceinline__ void gl16(unsigned short* lds, const unsigned short* g) {
    __builtin_amdgcn_global_load_lds(
        (const __attribute__((address_space(1))) unsigned int*)g,
        (__attribute__((address_space(3))) unsigned int*)lds, 16, 0, 0);
}

// ---------------------------------------------------------------- 64->64 layer (BN folded into weights; m97-style LDS staging)
__global__ __launch_bounds__(128) void k_lin64m(
        const unsigned short* __restrict__ zinh, const unsigned short* __restrict__ zinl,
        const unsigned short* __restrict__ wfh, const unsigned short* __restrict__ wfl,
        const float* __restrict__ bias2, unsigned short* __restrict__ zouth,
        unsigned short* __restrict__ zoutl, float* __restrict__ part) {
    __shared__ unsigned short Ah[128 * 32], Al[128 * 32];   // [row][k32] per kc, 8 KB each
    __shared__ unsigned short Bh[64 * 32], Bl[64 * 32];     // [col][k32] per kc, 4 KB each
    __shared__ float red[2 * 64 * 2];
    int tid = threadIdx.x;
    int wv = tid >> 6, lane = tid & 63;
    int l15 = lane & 15, quad = lane >> 4;
    int row0g = blockIdx.x * 128;          // block row base (contiguous in memory)
    int row0 = row0g + wv * 64;            // per-wave row base
    int rloc = lane >> 2;                  // row within 16-row staging segment
    int ch8 = (lane & 3) * 8;              // k-chunk (shorts, 16 B)
    f32x4 acc[4][4];
#pragma unroll
    for (int i = 0; i < 4; ++i)
#pragma unroll
        for (int j = 0; j < 4; ++j) acc[i][j] = (f32x4)0.f;

#pragma unroll
    for (int kc = 0; kc < 2; ++kc) {
        // stage A [128][32] (8 segs of 16 rows; waves interleave) + B [64][32]
#pragma unroll
        for (int s = 0; s < 4; ++s) {
            int seg = s * 2 + wv;          // 0..7
            size_t ago = (size_t)(row0g + seg * 16 + rloc) * 64 + kc * 32 + ch8;
            int lb = seg * 16 * 32;        // wave-uniform LDS base (shorts)
            gl16(&Ah[lb], &zinh[ago]);
            gl16(&Al[lb], &zinl[ago]);
        }
#pragma unroll
        for (int s = 0; s < 2; ++s) {
            int seg = s * 2 + wv;          // 0..3
            size_t bgo = (size_t)(seg * 16 + rloc) * 64 + kc * 32 + ch8;
            int lb = seg * 16 * 32;
            gl16(&Bh[lb], &wfh[bgo]);
            gl16(&Bl[lb], &wfl[bgo]);
        }
        __syncthreads();    // compiler drains vmcnt before s_barrier
        bf16x8 afh[4], afl[4], bfh[4], bfl[4];
#pragma unroll
        for (int i = 0; i < 4; ++i) {
            int o = (wv * 64 + i * 16 + l15) * 32 + quad * 8;
            afh[i] = *(const bf16x8*)&Ah[o];
            afl[i] = *(const bf16x8*)&Al[o];
        }
#pragma unroll
        for (int j = 0; j < 4; ++j) {
            int o = (j * 16 + l15) * 32 + quad * 8;
            bfh[j] = *(const bf16x8*)&Bh[o];
            bfl[j] = *(const bf16x8*)&Bl[o];
        }
#pragma unroll
        for (int i = 0; i < 4; ++i)
#pragma unroll
            for (int j = 0; j < 4; ++j) {
                acc[i][j] = __builtin_amdgcn_mfma_f32_16x16x32_bf16(afh[i], bfh[j], acc[i][j], 0, 0, 0);
                acc[i][j] = __builtin_amdgcn_mfma_f32_16x16x32_bf16(afh[i], bfl[j], acc[i][j], 0, 0, 0);
                acc[i][j] = __builtin_amdgcn_mfma_f32_16x16x32_bf16(afl[i], bfh[j], acc[i][j], 0, 0, 0);
            }
        __syncthreads();    // protect LDS re-stage of kc=1
    }
    // epilogue: bias + ReLU, bf16 split store, per-col stats
#pragma unroll
    for (int j = 0; j < 4; ++j) {
        int colL = j * 16 + l15;
        float bl = bias2[colL];
        float s1 = 0.f, s2 = 0.f;
#pragma unroll
        for (int i = 0; i < 4; ++i) {
            int row = row0 + i * 16 + quad * 4;
#pragma unroll
            for (int r = 0; r < 4; ++r) {
                float v = fmaxf(acc[i][j][r] + bl, 0.f);
                unsigned short h, l;
                split2bf(v, h, l);
                zouth[(size_t)(row + r) * 64 + colL] = h;
                zoutl[(size_t)(row + r) * 64 + colL] = l;
                s1 += v; s2 = fmaf(v, v, s2);
            }
        }
        s1 += __shfl_xor(s1, 16, 64); s1 += __shfl_xor(s1, 32, 64);
        s2 += __shfl_xor(s2, 16, 64); s2 += __shfl_xor(s2, 32, 64);
        if (quad == 0) {
            red[(wv * 64 + colL) * 2 + 0] = s1;
            red[(wv * 64 + colL) * 2 + 1] = s2;
        }
    }
    __syncthreads();
    if (tid < 64) {
        part[(size_t)blockIdx.x * 128 + tid] =
            red[tid * 2] + red[(64 + tid) * 2];
        part[(size_t)blockIdx.x * 128 + 64 + tid] =
            red[tid * 2 + 1] + red[(64 + tid) * 2 + 1];
    }
}

// ---------------------------------------------------------------- ec1 finalize: BN + max over k -> x1 bf16 hi/lo (fused xsplit), sq norms
// NOTE: x1h/x1l MUST NOT alias z2h/z2l (R5 bug: in-place overwrite raced
// with other blocks' reads of z2 rows). x1 pair has a dedicated allocation.
__global__ __launch_bounds__(256) void k_ec1_fin(const unsigned short* __restrict__ z2h,
        const unsigned short* __restrict__ z2l,
        const float* __restrict__ statsIn, const float* __restrict__ g,
        const float* __restrict__ be, unsigned short* __restrict__ x1h,
        unsigned short* __restrict__ x1l, float* __restrict__ sq2) {
    int tid = threadIdx.x;
    int o = blockIdx.x * 256 + tid;
    int c = o & 63; int bp = o >> 6;
    float mu = statsIn[c] * (1.f / E);
    float var = statsIn[64 + c] * (1.f / E) - mu * mu;
    float sc = g[c] * rsqrtf(var + EPS);
    float sh = be[c] - mu * sc;
    float m = -INFINITY;
#pragma unroll
    for (int j = 0; j < KNN; ++j) {
        size_t zo = ((size_t)bp * KNN + j) * 64 + c;
        float v = bf2f(z2h[zo]) + bf2f(z2l[zo]);
        m = fmaxf(m, fmaf(v, sc, sh));
    }
    unsigned short h, l;
    split2bf(m, h, l);
    x1h[o] = h; x1l[o] = l;
    float ss = m * m;
#pragma unroll
    for (int off = 32; off; off >>= 1) ss += __shfl_down(ss, off, 64);
    if (c == 0) sq2[bp] = ss;
}

// ---------------------------------------------------------------- kNN2 partial
// R19: swapped-operand Gram -> C[q][p] with p=lane&15: lane owns full p-rows,
// top-5 scan on MFMA accumulator registers; no LDS key tile.
// R22: q-frags shared across both p-tiles. R26: 2-deep j load pipeline
// (103->88us). R28: the scan stalled on each j's 6-deep serial MFMA chain;
// split procQ into mfmaQ/scanQ and issue j+1's chain BEFORE scanning j —
// chain latency hides under the previous scan's VALU. Per-acc MFMA order
// and scan order unchanged -> bitwise-identical idx2.
__global__ __launch_bounds__(128) void k_knn2(const unsigned short* __restrict__ x1h,
        const unsigned short* __restrict__ x1l, const float* __restrict__ sq2,
        float* __restrict__ cd, int* __restrict__ ci) {
    int tid = threadIdx.x;
    int wv = tid >> 6, lane = tid & 63;
    int l15 = lane & 15, quad = lane >> 4;
    int qc = blockIdx.x & (QC2 - 1);
    int pt = blockIdx.x >> QC2_SHIFT;         // 16*32 ptiles of 64 rows
    int b = pt >> 5;
    int pw = ((pt & 31) << 6) + wv * 32;      // wave p base within batch
    const size_t xbase = (size_t)b * P * 64;
    int qlo = qc * (P / QC2);                 // 512-q chunk

    // B operand: p-row fragments for both 16-row tiles (held whole kernel)
    bf16x8 ph[2][2], pl_[2][2];               // [i][kc]
#pragma unroll
    for (int i = 0; i < 2; ++i)
#pragma unroll
        for (int kc = 0; kc < 2; ++kc) {
            size_t o = xbase + (size_t)(pw + i * 16 + l15) * 64 + kc * 32 + quad * 8;
            ph[i][kc] = *(const bf16x8*)&x1h[o];
            pl_[i][kc] = *(const bf16x8*)&x1l[o];
        }
    // per-lane top-5 for p-rows l15 (0) and 16+l15 (1)
    float bd0[KNN], bd1[KNN]; int bi0[KNN], bi1[KNN];
#pragma unroll
    for (int i = 0; i < KNN; ++i) {
        bd0[i] = INFINITY; bi0[i] = 0;
        bd1[i] = INFINITY; bi1[i] = 0;
    }

    auto loadQ = [&](int q0, int j, bf16x8* qh, bf16x8* ql, f32x4& sq) {
#pragma unroll
        for (int kc = 0; kc < 2; ++kc) {
            size_t o = xbase + (size_t)(q0 + j * 16 + l15) * 64 + kc * 32 + quad * 8;
            qh[kc] = *(const bf16x8*)&x1h[o];
            ql[kc] = *(const bf16x8*)&x1l[o];
        }
        sq = *(const f32x4*)&sq2[b * P + q0 + j * 16 + (quad << 2)];
    };
    auto mfmaQ = [&](const bf16x8* qh, const bf16x8* ql, f32x4& a0, f32x4& a1) {
        a0 = (f32x4)0.f; a1 = (f32x4)0.f;
#pragma unroll
        for (int kc = 0; kc < 2; ++kc) {
            a0 = __builtin_amdgcn_mfma_f32_16x16x32_bf16(qh[kc], ph[0][kc], a0, 0, 0, 0);
            a0 = __builtin_amdgcn_mfma_f32_16x16x32_bf16(qh[kc], pl_[0][kc], a0, 0, 0, 0);
            a0 = __builtin_amdgcn_mfma_f32_16x16x32_bf16(ql[kc], ph[0][kc], a0, 0, 0, 0);
            a1 = __builtin_amdgcn_mfma_f32_16x16x32_bf16(qh[kc], ph[1][kc], a1, 0, 0, 0);
            a1 = __builtin_amdgcn_mfma_f32_16x16x32_bf16(qh[kc], pl_[1][kc], a1, 0, 0, 0);
            a1 = __builtin_amdgcn_mfma_f32_16x16x32_bf16(ql[kc], ph[1][kc], a1, 0, 0, 0);
        }
    };
    auto scanQ = [&](int q0, int j, f32x4 a0, f32x4 a1, f32x4 sq) {
        int qb = q0 + j * 16 + (quad << 2);
#pragma unroll
        for (int r = 0; r < 4; ++r) {
            float d0 = fmaf(a0[r], -2.f, sq[r]);
            if (d0 < bd0[KNN - 1]) ins5(d0, qb + r, bd0, bi0);
            float d1 = fmaf(a1[r], -2.f, sq[r]);
            if (d1 < bd1[KNN - 1]) ins5(d1, qb + r, bd1, bi1);
        }
    };

#pragma unroll 1
    for (int t = 0; t < (P / QC2) / 128; ++t) {
        int q0 = qlo + (t << 7);
        bf16x8 qhA[2], qlA[2], qhB[2], qlB[2];
        f32x4 sqA, sqB, a0A, a1A, a0B, a1B;
        loadQ(q0, 0, qhA, qlA, sqA);
        mfmaQ(qhA, qlA, a0A, a1A);            // chain 0 in flight
#pragma unroll 1
        for (int jj = 0; jj < 8; jj += 2) {
            loadQ(q0, jj + 1, qhB, qlB, sqB);
            mfmaQ(qhB, qlB, a0B, a1B);        // chain j+1 issues before scan j
            scanQ(q0, jj, a0A, a1A, sqA);     // runs while chain j+1 in flight
            if (jj < 6) {
                loadQ(q0, jj + 2, qhA, qlA, sqA);
                mfmaQ(qhA, qlA, a0A, a1A);    // chain j+2 issues before scan j+1
            }
            scanQ(q0, jj + 1, a0B, a1B, sqB);
        }
    }
    // merge across the 4 quads sharing l15 (disjoint q mod 16 -> clean ties)
    merge_xor(16, bd0, bi0); merge_xor(16, bd1, bi1);
    merge_xor(32, bd0, bi0); merge_xor(32, bd1, bi1);
    if (quad == 0) {
        size_t o0 = (((size_t)b * P + pw + l15) * QC2 + qc) * KNN;
        size_t o1 = (((size_t)b * P + pw + 16 + l15) * QC2 + qc) * KNN;
#pragma unroll
        for (int k = 0; k < KNN; ++k) {
            cd[o0 + k] = bd0[k]; ci[o0 + k] = bi0[k];
            cd[o1 + k] = bd1[k]; ci[o1 + k] = bi1[k];
        }
    }
}

// ---------------------------------------------------------------- kNN2 merge (QC2 sorted chunks of 5 -> 5)
__global__ __launch_bounds__(256) void k_knn2m(const float* __restrict__ cd,
        const int* __restrict__ ci, int* __restrict__ idx2) {
    int bp = blockIdx.x * 256 + threadIdx.x;
    float bd[KNN]; int bi[KNN];
#pragma unroll
    for (int i = 0; i < KNN; ++i) { bd[i] = INFINITY; bi[i] = 0; }
    size_t o = (size_t)bp * QC2 * KNN;
    for (int t = 0; t < QC2 * KNN; ++t) {
        float d2 = cd[o + t]; int qi = ci[o + t];
        if (d2 < bd[KNN - 1]) ins5(d2, qi, bd, bi);
    }
#pragma unroll
    for (int i = 0; i < KNN; ++i) idx2[bp * KNN + i] = bi[i];
}

// ---------------------------------------------------------------- edgeconv2 (direct-fragment split-bf16 MFMA)
__global__ __launch_bounds__(256) void k_ec2m(
        const unsigned short* __restrict__ x1h, const unsigned short* __restrict__ x1l,
        const int* __restrict__ idx2,
        const unsigned short* __restrict__ wdh, const unsigned short* __restrict__ wdl,
        const unsigned short* __restrict__ w1h, const unsigned short* __restrict__ w1l,
        const float* __restrict__ bias, float* __restrict__ zout,
        float* __restrict__ stats) {
    __shared__ float red[2 * 128 * 2];
    int tid = threadIdx.x;
    int base = blockIdx.x * 128;            // first edge
    int bb = base / (P * KNN);              // batch (blocks never straddle: 10240%128==0)
    int wv = tid >> 6, lane = tid & 63;
    int wm = wv >> 1, wn = wv & 1;
    int l15 = lane & 15, quad = lane >> 4;
    // per-lane A rows for this wave's 4 row-tiles
    int rI[4], rJ[4];
#pragma unroll
    for (int i = 0; i < 4; ++i) {
        int e = base + wm * 64 + i * 16 + l15;
        rI[i] = e / KNN;
        rJ[i] = (bb << 11) + idx2[e];
    }
    f32x4 acc[4][4];
#pragma unroll
    for (int i = 0; i < 4; ++i)
#pragma unroll
        for (int j = 0; j < 4; ++j) acc[i][j] = (f32x4)0.f;

#pragma unroll
    for (int s = 0; s < 2; ++s) {
        const unsigned short* bh_ = s ? w1h : wdh;
        const unsigned short* bl_ = s ? w1l : wdl;
#pragma unroll
        for (int kc = 0; kc < 2; ++kc) {
            bf16x8 afh[4], afl[4], bfh[4], bfl[4];
#pragma unroll
            for (int i = 0; i < 4; ++i) {
                int row = s ? rJ[i] : rI[i];
                size_t o = (size_t)row * 64 + kc * 32 + quad * 8;
                afh[i] = *(const bf16x8*)&x1h[o];
                afl[i] = *(const bf16x8*)&x1l[o];
            }
#pragma unroll
            for (int j = 0; j < 4; ++j) {
                size_t wo = (size_t)(wn * 64 + j * 16 + l15) * 64 + kc * 32 + quad * 8;
                bfh[j] = *(const bf16x8*)&bh_[wo];
                bfl[j] = *(const bf16x8*)&bl_[wo];
            }
#pragma unroll
            for (int i = 0; i < 4; ++i)
#pragma unroll
                for (int j = 0; j < 4; ++j) {
                    acc[i][j] = __builtin_amdgcn_mfma_f32_16x16x32_bf16(afh[i], bfh[j], acc[i][j], 0, 0, 0);
                    acc[i][j] = __builtin_amdgcn_mfma_f32_16x16x32_bf16(afh[i], bfl[j], acc[i][j], 0, 0, 0);
                    acc[i][j] = __builtin_amdgcn_mfma_f32_16x16x32_bf16(afl[i], bfh[j], acc[i][j], 0, 0, 0);
                }
        }
    }
    // epilogue: bias + ReLU, write z, per-col stats
#pragma unroll
    for (int j = 0; j < 4; ++j) {
        int colL = wn * 64 + j * 16 + l15;
        float bl = bias[colL];
        float s1 = 0.f, s2 = 0.f;
#pragma unroll
        for (int i = 0; i < 4; ++i) {
            int row = wm * 64 + i * 16 + quad * 4;
#pragma unroll
            for (int r = 0; r < 4; ++r) {
                float v = fmaxf(acc[i][j][r] + bl, 0.f);
                zout[(size_t)(base + row + r) * 128 + colL] = v;
                s1 += v; s2 = fmaf(v, v, s2);
            }
        }
        s1 += __shfl_xor(s1, 16, 64); s1 += __shfl_xor(s1, 32, 64);
        s2 += __shfl_xor(s2, 16, 64); s2 += __shfl_xor(s2, 32, 64);
        if (quad == 0) {
            red[(wm * 128 + colL) * 2 + 0] = s1;
            red[(wm * 128 + colL) * 2 + 1] = s2;
        }
    }
    __syncthreads();
    if (tid < 128) {
        atomicAdd(&stats[tid], red[tid * 2] + red[(128 + tid) * 2]);
        atomicAdd(&stats[128 + tid], red[tid * 2 + 1] + red[(128 + tid) * 2 + 1]);
    }
}

// ---------------------------------------------------------------- ec2 finalize: BN + max over k -> x2 bf16 hi/lo (fused xsplit)
// safe: z3 lives in zA, x2 pair lives in zB — disjoint buffers.
__global__ __launch_bounds__(256) void k_ec2_fin(const float* __restrict__ z3,
        const float* __restrict__ stats, const float* __restrict__ g,
        const float* __restrict__ be, unsigned short* __restrict__ x2h,
        unsigned short* __restrict__ x2l) {
    int o = blockIdx.x * 256 + threadIdx.x;
    int c = o & 127; int bp = o >> 7;
    float mu = stats[c] * (1.f / E);
    float var = stats[128 + c] * (1.f / E) - mu * mu;
    float sc = g[c] * rsqrtf(var + EPS);
    float sh = be[c] - mu * sc;
    float m = -INFINITY;
#pragma unroll
    for (int j = 0; j < KNN; ++j)
        m = fmaxf(m, fmaf(z3[((size_t)bp * KNN + j) * 128 + c], sc, sh));
    unsigned short h, l;
    split2bf(m, h, l);
    x2h[o] = h; x2l[o] = l;
}

// ---------------------------------------------------------------- l1 (LDS-staged split-bf16 MFMA, m97-style 2-phase)
__global__ __launch_bounds__(256) void k_l1m(
        const unsigned short* __restrict__ x1h, const unsigned short* __restrict__ x1l,
        const unsigned short* __restrict__ x2h, const unsigned short* __restrict__ x2l,
        const unsigned short* __restrict__ wth, const unsigned short* __restrict__ wtl,
        const float* __restrict__ bias, float* __restrict__ stats,
        float* __restrict__ pmax, float* __restrict__ pmin) {
    __shared__ unsigned short Ah[128 * 32], Al[128 * 32];   // [row][k] bf16, 8 KB each
    __shared__ unsigned short Bh[128 * 32], Bl[128 * 32];   // [col][k] bf16
    __shared__ float red[2 * 128 * 4];
    int tid = threadIdx.x;
    int brow = blockIdx.x & 255;
    int bcol = blockIdx.x >> 8;
    int row0 = brow << 7, col0 = bcol << 7;
    int wv = tid >> 6, lane = tid & 63;
    int wm = wv >> 1, wn = wv & 1;
    int l15 = lane & 15, quad = lane >> 4;
    int rloc = wv * 16 + (lane >> 2);      // staging row for call 0 (+64 for call 1)
    int ch8 = (lane & 3) * 8;              // staging k-chunk (ushorts, 16 B)
    f32x4 acc[4][4];
#pragma unroll
    for (int i = 0; i < 4; ++i)
#pragma unroll
        for (int j = 0; j < 4; ++j) acc[i][j] = (f32x4)0.f;

#pragma unroll
    for (int t = 0; t < 6; ++t) {
        int k0 = t * 32;
        const unsigned short* ah = (k0 < 64) ? x1h : x2h;
        const unsigned short* al = (k0 < 64) ? x1l : x2l;
        int astr = (k0 < 64) ? 64 : 128;
        int aoff = (k0 < 64) ? k0 : (k0 - 64);
        // stage: 32 KB/step, 8 x 16B global_load_lds per thread, 1 KB/wave/call
#pragma unroll
        for (int c = 0; c < 2; ++c) {
            int rl = c * 64 + rloc;
            size_t ao = (size_t)(row0 + rl) * astr + aoff + ch8;
            size_t bo = (size_t)(col0 + rl) * 192 + k0 + ch8;
            int lb = (c * 64 + wv * 16) * 32;   // wave-uniform LDS base (ushorts)
            gl16(&Ah[lb], &ah[ao]);
            gl16(&Al[lb], &al[ao]);
            gl16(&Bh[lb], &wth[bo]);
            gl16(&Bl[lb], &wtl[bo]);
        }
        __syncthreads();    // compiler drains vmcnt before s_barrier
        bf16x8 afh[4], afl[4], bfh[4], bfl[4];
#pragma unroll
        for (int i = 0; i < 4; ++i) {
            int o = (wm * 64 + i * 16 + l15) * 32 + quad * 8;
            afh[i] = *(const bf16x8*)&Ah[o];
            afl[i] = *(const bf16x8*)&Al[o];
        }
#pragma unroll
        for (int j = 0; j < 4; ++j) {
            int o = (wn * 64 + j * 16 + l15) * 32 + quad * 8;
            bfh[j] = *(const bf16x8*)&Bh[o];
            bfl[j] = *(const bf16x8*)&Bl[o];
        }
#pragma unroll
        for (int i = 0; i < 4; ++i)
#pragma unroll
            for (int j = 0; j < 4; ++j) {
                acc[i][j] = __builtin_amdgcn_mfma_f32_16x16x32_bf16(afh[i], bfh[j], acc[i][j], 0, 0, 0);
                acc[i][j] = __builtin_amdgcn_mfma_f32_16x16x32_bf16(afh[i], bfl[j], acc[i][j], 0, 0, 0);
                acc[i][j] = __builtin_amdgcn_mfma_f32_16x16x32_bf16(afl[i], bfh[j], acc[i][j], 0, 0, 0);
            }
        __syncthreads();    // protect LDS re-stage of step t+1
    }
    // epilogue: bias + ReLU, per-col sum/sumsq/max/min (h never materialized)
#pragma unroll
    for (int j = 0; j < 4; ++j) {
        int colL = wn * 64 + j * 16 + l15;
        float bl = bias[col0 + colL];
        float s1 = 0.f, s2 = 0.f, mx = 0.f, mn = INFINITY;
#pragma unroll
        for (int i = 0; i < 4; ++i)
#pragma unroll
            for (int r = 0; r < 4; ++r) {
                float v = fmaxf(acc[i][j][r] + bl, 0.f);
                s1 += v; s2 = fmaf(v, v, s2);
                mx = fmaxf(mx, v); mn = fminf(mn, v);
            }
        s1 += __shfl_xor(s1, 16, 64); s1 += __shfl_xor(s1, 32, 64);
        s2 += __shfl_xor(s2, 16, 64); s2 += __shfl_xor(s2, 32, 64);
        mx = fmaxf(mx, __shfl_xor(mx, 16, 64)); mx = fmaxf(mx, __shfl_xor(mx, 32, 64));
        mn = fminf(mn, __shfl_xor(mn, 16, 64)); mn = fminf(mn, __shfl_xor(mn, 32, 64));
        if (quad == 0) {
            float* rp = &red[(wm * 128 + colL) * 4];
            rp[0] = s1; rp[1] = s2; rp[2] = mx; rp[3] = mn;
        }
    }
    __syncthreads();
    if (tid < 128) {
        const float* r0 = &red[tid * 4];
        const float* r1 = &red[(128 + tid) * 4];
        int bb = row0 >> 11;
        atomicAdd(&stats[col0 + tid], r0[0] + r1[0]);
        atomicAdd(&stats[1024 + col0 + tid], r0[1] + r1[1]);
        atomicMax((unsigned int*)&pmax[bb * 1024 + col0 + tid],
                  __float_as_uint(fmaxf(r0[2], r1[2])));
        atomicMin((unsigned int*)&pmin[bb * 1024 + col0 + tid],
                  __float_as_uint(fminf(r0[3], r1[3])));
    }
}

// ---------------------------------------------------------------- pooled p = BN(max or min)
__global__ void k_pool(const float* __restrict__ stats, const float* __restrict__ g,
                       const float* __restrict__ be, const float* __restrict__ pmax,
                       const float* __restrict__ pmin, float* __restrict__ p) {
    int o = blockIdx.x * 256 + threadIdx.x;   // 16384
    int c = o & 1023;
    float mu = stats[c] * (1.f / BP);
    float var = stats[1024 + c] * (1.f / BP) - mu * mu;
    float sc = g[c] * rsqrtf(var + EPS);
    float sh = be[c] - mu * sc;
    float v = (sc >= 0.f) ? pmax[o] : pmin[o];
    p[o] = fmaf(v, sc, sh);
}

// ---------------------------------------------------------------- head
__global__ __launch_bounds__(256) void k_m1(const float* __restrict__ p,
        const float* __restrict__ w, const float* __restrict__ bias,
        float* __restrict__ t1, float* __restrict__ stats) {
    int o = blockIdx.x * 256 + threadIdx.x;   // 8192
    int c = o & 511, b = o >> 9;
    const float* pr = p + (b << 10);
    float acc = bias[c];
    for (int k = 0; k < 1024; ++k) acc = fmaf(pr[k], w[k * 512 + c], acc);
    acc = fmaxf(acc, 0.f);
    t1[o] = acc;
    atomicAdd(&stats[c], acc);
    atomicAdd(&stats[512 + c], acc * acc);
}

__global__ __launch_bounds__(256) void k_m2(const float* __restrict__ t1,
        const float* __restrict__ stats5, const float* __restrict__ g,
        const float* __restrict__ be, const float* __restrict__ w,
        const float* __restrict__ bias, float* __restrict__ t2,
        float* __restrict__ stats6) {
    __shared__ float scl[512], shf[512];
    int tid = threadIdx.x;
    for (int t = tid; t < 512; t += 256) {
        float mu = stats5[t] * (1.f / 16.f);
        float var = stats5[512 + t] * (1.f / 16.f) - mu * mu;
        float sc = g[t] * rsqrtf(var + EPS);
        scl[t] = sc; shf[t] = be[t] - mu * sc;
    }
    __syncthreads();
    int o = blockIdx.x * 256 + tid;   // 4096
    int c = o & 255, b = o >> 8;
    const float* tr = t1 + (b << 9);
    float acc = bias[c];
    for (int k = 0; k < 512; ++k) {
        float u = fmaf(tr[k], scl[k], shf[k]);
        acc = fmaf(u, w[k * 256 + c], acc);
    }
    acc = fmaxf(acc, 0.f);
    t2[o] = acc;
    atomicAdd(&stats6[c], acc);
    atomicAdd(&stats6[256 + c], acc * acc);
}

__global__ __launch_bounds__(256) void k_m3(const float* __restrict__ t2,
        const float* __restrict__ stats6, const float* __restrict__ g,
        const float* __restrict__ be, const float* __restrict__ w,
        const float* __restrict__ bias, float* __restrict__ out) {
    __shared__ float scl[256], shf[256];
    int tid = threadIdx.x;
    {
        float mu = stats6[tid] * (1.f / 16.f);
        float var = stats6[256 + tid] * (1.f / 16.f) - mu * mu;
        float sc = g[tid] * rsqrtf(var + EPS);
        scl[tid] = sc; shf[tid] = be[tid] - mu * sc;
    }
    __syncthreads();
    if (tid < 32) {
        int c = tid & 1, b = tid >> 1;
        const float* tr = t2 + (b << 8);
        float acc = bias[c];
        for (int k = 0; k < 256; ++k) {
            float u = fmaf(tr[k], scl[k], shf[k]);
            acc = fmaf(u, w[k * 2 + c], acc);
        }
        out[tid] = acc;
    }
}

// ================================================================ launch
extern "C" void kernel_launch(void* const* d_in, const int* in_sizes, int n_in,
                              void* d_out, int out_size, void* d_ws, size_t ws_size,
                              hipStream_t stream) {
    const float* pos  = (const float*)d_in[0];
    const float* c1w0 = (const float*)d_in[1];
    const float* c1b0 = (const float*)d_in[2];
    const float* c1g0 = (const float*)d_in[3];
    const float* c1e0 = (const float*)d_in[4];
    const float* c1w1 = (const float*)d_in[5];
    const float* c1b1 = (const float*)d_in[6];
    const float* c1g1 = (const float*)d_in[7];
    const float* c1e1 = (const float*)d_in[8];
    const float* c1w2 = (const float*)d_in[9];
    const float* c1b2 = (const float*)d_in[10];
    const float* c1g2 = (const float*)d_in[11];
    const float* c1e2 = (const float*)d_in[12];
    const float* c2w  = (const float*)d_in[13];
    const float* c2b  = (const float*)d_in[14];
    const float* c2g  = (const float*)d_in[15];
    const float* c2e  = (const float*)d_in[16];
    const float* l1w  = (const float*)d_in[17];
    const float* l1b  = (const float*)d_in[18];
    const float* l1g  = (const float*)d_in[19];
    const float* l1e  = (const float*)d_in[20];
    const float* m1w  = (const float*)d_in[21];
    const float* m1b  = (const float*)d_in[22];
    const float* m1g  = (const float*)d_in[23];
    const float* m1e  = (const float*)d_in[24];
    const float* m2w  = (const float*)d_in[25];
    const float* m2b  = (const float*)d_in[26];
    const float* m2g  = (const float*)d_in[27];
    const float* m2e  = (const float*)d_in[28];
    const float* m3w  = (const float*)d_in[29];
    const float* m3b  = (const float*)d_in[30];
    float* out = (float*)d_out;

    char* ws = (char*)d_ws;
    size_t off = 0;
    auto alloc = [&](size_t bytes) {
        size_t r = off; off = (off + bytes + 255) & ~(size_t)255; return r;
    };
    float* stats = (float*)(ws + alloc(ST_TOTAL * 4));
    float* pmax  = (float*)(ws + alloc(16 * 1024 * 4));
    float* pmin  = (float*)(ws + alloc(16 * 1024 * 4));
    float* pbuf  = (float*)(ws + alloc(16 * 1024 * 4));
    float* t1    = (float*)(ws + alloc(16 * 512 * 4));
    float* t2    = (float*)(ws + alloc(16 * 256 * 4));
    float* sq2   = (float*)(ws + alloc((size_t)BP * 4));
    float* part  = (float*)(ws + alloc((size_t)(E / 64) * 128 * 4));  // up to 2560 blocks x 128
    unsigned short* wthL = (unsigned short*)(ws + alloc((size_t)192 * 1024 * 2));
    unsigned short* wtlL = (unsigned short*)(ws + alloc((size_t)192 * 1024 * 2));
    unsigned short* wdh  = (unsigned short*)(ws + alloc((size_t)128 * 64 * 2));
    unsigned short* wdl  = (unsigned short*)(ws + alloc((size_t)128 * 64 * 2));
    unsigned short* w1h  = (unsigned short*)(ws + alloc((size_t)128 * 64 * 2));
    unsigned short* w1l  = (unsigned short*)(ws + alloc((size_t)128 * 64 * 2));
    unsigned short* wf1h = (unsigned short*)(ws + alloc((size_t)64 * 64 * 2));
    unsigned short* wf1l = (unsigned short*)(ws + alloc((size_t)64 * 64 * 2));
    unsigned short* wf2h = (unsigned short*)(ws + alloc((size_t)64 * 64 * 2));
    unsigned short* wf2l = (unsigned short*)(ws + alloc((size_t)64 * 64 * 2));
    float* bias2a = (float*)(ws + alloc(64 * 4));
    float* bias2b = (float*)(ws + alloc(64 * 4));
    int*   idx1  = (int*)  (ws + alloc((size_t)E * 4));
    int*   idx2  = (int*)  (ws + alloc((size_t)E * 4));
    // dedicated x1 bf16 pair (R6 fix: must NOT alias z2 — ec1_fin reads z2
    // and writes x1 in the same kernel; aliasing raced across blocks)
    unsigned short* x1h = (unsigned short*)(ws + alloc((size_t)BP * 64 * 2));
    unsigned short* x1l = (unsigned short*)(ws + alloc((size_t)BP * 64 * 2));
    float* zA    = (float*)(ws + alloc((size_t)E * 128 * 4)); // hosts z0/z1 bf16 pairs, later z3 fp32
    float* zB    = (float*)(ws + alloc((size_t)E * 64 * 4));  // hosts z2 bf16 pair, later knn2 scratch
    // zA aliases: z0h/z0l (21MB each) then z1h/z1l; all dead before z3 (ec2 out) overwrites
    unsigned short* z0h = (unsigned short*)zA;
    unsigned short* z0l = z0h + (size_t)E * 64;
    unsigned short* z1h = z0l + (size_t)E * 64;
    unsigned short* z1l = z1h + (size_t)E * 64;
    // zB aliases: z2h/z2l (dead after ec1_fin completes), then knn2 scratch:
    // cand 5.2MB + x2 pair 16.8MB = 22 < 41.9MB
    unsigned short* z2h = (unsigned short*)zB;
    unsigned short* z2l = z2h + (size_t)E * 64;
    float* cand_d = (float*)zB;
    int*   cand_i = (int*)(cand_d + (size_t)BP * QC2 * KNN);
    unsigned short* x2h = (unsigned short*)(cand_i + (size_t)BP * QC2 * KNN);
    unsigned short* x2l = x2h + (size_t)BP * 128;

    (void)in_sizes; (void)n_in; (void)out_size; (void)ws_size;

    k_init<<<64, 256, 0, stream>>>(stats, pmax, pmin);
    k_wsplit<<<(192 * 1024 + 255) / 256, 256, 0, stream>>>(l1w, wthL, wtlL, 192, 1024);
    k_wprep2<<<(64 * 128 + 255) / 256, 256, 0, stream>>>(c2w, wdh, wdl, w1h, w1l);
    k_knn1<<<B * 32, 256, 0, stream>>>(pos, idx1);
    k_ec1_l0<<<E / 256, 256, 0, stream>>>(pos, idx1, c1w0, c1b0, z0h, z0l, part);
    k_redstat<<<128, 256, 0, stream>>>(part, stats + ST0, E / 256);
    k_wfold<<<64, 64, 0, stream>>>(stats + ST0, c1g0, c1e0, c1w1, c1b1,
                                   wf1h, wf1l, bias2a, 1.f / E);
    k_lin64m<<<E / 128, 128, 0, stream>>>(z0h, z0l, wf1h, wf1l, bias2a,
                                          z1h, z1l, part);
    k_redstat<<<128, 256, 0, stream>>>(part, stats + ST1, E / 128);
    k_wfold<<<64, 64, 0, stream>>>(stats + ST1, c1g1, c1e1, c1w2, c1b2,
                                   wf2h, wf2l, bias2b, 1.f / E);
    k_lin64m<<<E / 128, 128, 0, stream>>>(z1h, z1l, wf2h, wf2l, bias2b,
                                          z2h, z2l, part);
    k_redstat<<<128, 256, 0, stream>>>(part, stats + ST2, E / 128);
    k_ec1_fin<<<BP * 64 / 256, 256, 0, stream>>>(z2h, z2l, stats + ST2, c1g2, c1e2,
                                                 x1h, x1l, sq2);
    k_knn2<<<B * 32 * QC2, 128, 0, stream>>>(x1h, x1l, sq2, cand_d, cand_i);
    k_knn2m<<<BP / 256, 256, 0, stream>>>(cand_d, cand_i, idx2);
    k_ec2m<<<E / 128, 256, 0, stream>>>(x1h, x1l, idx2, wdh, wdl, w1h, w1l,
                                        c2b, zA, stats + ST3);
    k_ec2_fin<<<BP * 128 / 256, 256, 0, stream>>>(zA, stats + ST3, c2g, c2e,
                                                  x2h, x2l);
    k_l1m<<<256 * 8, 256, 0, stream>>>(x1h, x1l, x2h, x2l, wthL, wtlL, l1b,
                                       stats + ST4, pmax, pmin);
    k_pool<<<64, 256, 0, stream>>>(stats + ST4, l1g, l1e, pmax, pmin, pbuf);
    k_m1<<<32, 256, 0, stream>>>(pbuf, m1w, m1b, t1, stats + ST5);
    k_m2<<<16, 256, 0, stream>>>(t1, stats + ST5, m1g, m1e, m2w, m2b, t2, stats + ST6);
    k_m3<<<1, 256, 0, stream>>>(t2, stats + ST6, m2g, m2e, m3w, m3b, out);
}